// Round 3
// baseline (759.194 us; speedup 1.0000x reference)
//
#include <hip/hip_runtime.h>

// ---------------------------------------------------------------------------
// MLA forward (B=1, S=2048, HID=2048, NH=32, DQK=192(128+64 rope), DV=128)
// Round 2: fix round-1 regression — __launch_bounds__(256,4) capped VGPRs at
// 64 and spilled the prefetch registers to scratch (WRITE_SIZE 16->356 MB).
// Keep prefetch + softmax restructure, drop the min-waves bound.
// ---------------------------------------------------------------------------

typedef __bf16 bf16x8 __attribute__((ext_vector_type(8)));
typedef float  f32x4  __attribute__((ext_vector_type(4)));

#define GLOAD16(g, l)                                                          \
  __builtin_amdgcn_global_load_lds(                                            \
      (const __attribute__((address_space(1))) unsigned int*)(g),              \
      (__attribute__((address_space(3))) unsigned int*)(l), 16, 0, 0)

__device__ __forceinline__ unsigned short f2b(float f) {
  unsigned u = __builtin_bit_cast(unsigned, f);
  u += 0x7fffu + ((u >> 16) & 1u);   // round-to-nearest-even
  return (unsigned short)(u >> 16);
}

// ---------------- elementwise cast fp32 -> bf16 (vectorized) ----------------
__global__ __launch_bounds__(256) void castb(const float* __restrict__ s,
                                             unsigned short* __restrict__ d, int n4) {
  int i = blockIdx.x * 256 + threadIdx.x;
  if (i < n4) {
    float4 v = ((const float4*)s)[i];
    ushort4 o;
    o.x = f2b(v.x); o.y = f2b(v.y); o.z = f2b(v.z); o.w = f2b(v.w);
    ((ushort4*)d)[i] = o;
  }
}

// ------------- transpose-cast: src[R][C] f32 -> dst[Cpad][R] bf16 -----------
__global__ __launch_bounds__(256) void tcast(const float* __restrict__ src,
                                             unsigned short* __restrict__ dst,
                                             int R, int C, int Cpad) {
  __shared__ float t[32][33];
  int tx = threadIdx.x, ty = threadIdx.y;
  int r0 = blockIdx.x * 32, c0 = blockIdx.y * 32;
#pragma unroll
  for (int j = 0; j < 4; j++) {
    int c = c0 + tx;
    t[ty + j * 8][tx] = (c < C) ? src[(size_t)(r0 + ty + j * 8) * C + c] : 0.f;
  }
  __syncthreads();
#pragma unroll
  for (int j = 0; j < 4; j++)
    dst[(size_t)(c0 + ty + j * 8) * R + r0 + tx] = f2b(t[tx][ty + j * 8]);
}

// ---------------- RMSNorm row kernel: fp32 in -> bf16 out -------------------
__global__ __launch_bounds__(256) void rmsnorm(const float* __restrict__ x,
                                               const float* __restrict__ w,
                                               unsigned short* __restrict__ o,
                                               int C, int stride) {
  int row = blockIdx.x, tid = threadIdx.x;
  const float* xr = x + (size_t)row * stride;
  float ss = 0.f;
  for (int c = tid; c < C; c += 256) { float v = xr[c]; ss += v * v; }
#pragma unroll
  for (int off = 1; off < 64; off <<= 1) ss += __shfl_xor(ss, off, 64);
  __shared__ float red[4];
  if ((tid & 63) == 0) red[tid >> 6] = ss;
  __syncthreads();
  ss = red[0] + red[1] + red[2] + red[3];
  float r = rsqrtf(ss / C + 1e-6f);
  unsigned short* orow = o + (size_t)row * C;
  for (int c = tid; c < C; c += 256) orow[c] = f2b(xr[c] * r * w[c]);
}

// ------------- q RoPE + cast: q_raw[2048][6144] f32 -> Qb bf16 --------------
__global__ __launch_bounds__(256) void qrope(const float* __restrict__ q,
                                             unsigned short* __restrict__ Qb) {
  int s = blockIdx.x, tid = threadIdx.x;
  const float* qr = q + (size_t)s * 6144;
  unsigned short* ob = Qb + (size_t)s * 6144;
  for (int idx = tid; idx < 6144; idx += 256) {
    int d = idx % 192;
    float v = qr[idx], outv;
    if (d < 128) outv = v;
    else {
      int i = d - 128, ii = i & 31;
      float a = (float)s * exp2f(-(float)ii * 0.4152410118609203f);
      float cs = __cosf(a), sn = __sinf(a);
      if (i < 32) outv = v * cs - qr[idx + 32] * sn;
      else        outv = qr[idx - 32] * sn + v * cs;
    }
    ob[idx] = f2b(outv);
  }
}

// -------- k_rot rope + broadcast into Kb[t][h*192 + 128..192] ---------------
__global__ __launch_bounds__(256) void krot(const float* __restrict__ ckv,
                                            unsigned short* __restrict__ Kb) {
  int t = blockIdx.x, tid = threadIdx.x;
  __shared__ unsigned short rot[64];
  if (tid < 32) {
    float x1 = ckv[(size_t)t * 640 + 512 + tid];
    float x2 = ckv[(size_t)t * 640 + 544 + tid];
    float a = (float)t * exp2f(-(float)tid * 0.4152410118609203f);
    float cs = __cosf(a), sn = __sinf(a);
    rot[tid]      = f2b(x1 * cs - x2 * sn);
    rot[tid + 32] = f2b(x1 * sn + x2 * cs);
  }
  __syncthreads();
  for (int idx = tid; idx < 2048; idx += 256) {
    int h = idx >> 6, d = idx & 63;
    Kb[(size_t)t * 6144 + h * 192 + 128 + d] = rot[d];
  }
}

// -------- k_pass split: kv_raw[t][h*256 + d] -> Kb[t][h*192 + d], d<128 -----
__global__ __launch_bounds__(256) void kvpass(const float* __restrict__ kv,
                                              unsigned short* __restrict__ Kb) {
  int t = blockIdx.x, tid = threadIdx.x;
  for (int idx = tid; idx < 4096; idx += 256) {
    int h = idx >> 7, d = idx & 127;
    Kb[(size_t)t * 6144 + h * 192 + d] = f2b(kv[(size_t)t * 8192 + h * 256 + d]);
  }
}

// -------- V transpose: kv_raw[t][h*256+128+d] -> Vt[h*128+d][t] bf16 --------
__global__ __launch_bounds__(256) void vtrans(const float* __restrict__ kv,
                                              unsigned short* __restrict__ Vt) {
  __shared__ float t[32][33];
  int tx = threadIdx.x, ty = threadIdx.y;
  int t0 = blockIdx.x * 32, d0 = blockIdx.y * 32, h = blockIdx.z;
#pragma unroll
  for (int j = 0; j < 4; j++)
    t[ty + j * 8][tx] = kv[(size_t)(t0 + ty + j * 8) * 8192 + h * 256 + 128 + d0 + tx];
  __syncthreads();
#pragma unroll
  for (int j = 0; j < 4; j++)
    Vt[(size_t)(h * 128 + d0 + ty + j * 8) * 2048 + t0 + tx] = f2b(t[tx][ty + j * 8]);
}

// ---------------------------------------------------------------------------
// GEMM: C[M][N] f32 = A[M][K] bf16 * Bt[N][K] bf16 (unchanged)
// ---------------------------------------------------------------------------
__global__ __launch_bounds__(256) void gemm_bt(const unsigned short* __restrict__ A,
                                               const unsigned short* __restrict__ Bt,
                                               float* __restrict__ C,
                                               int M, int N, int K) {
  __shared__ unsigned short As[4096];
  __shared__ unsigned short Bs[4096];
  const int tid = threadIdx.x;
  const int w = tid >> 6, lane = tid & 63;
  const int lr = lane & 15, lh = lane >> 4;
  const int m0 = blockIdx.y * 128, n0 = blockIdx.x * 128;
  const int wm = w >> 1, wn = w & 1;
  const int srow = lane >> 2;
  const int schunk = (lane & 3) ^ ((lane >> 3) & 3);
  const int swzr = (lr >> 1) & 3;

  f32x4 acc[4][4];
  const f32x4 z = {0.f, 0.f, 0.f, 0.f};
#pragma unroll
  for (int i = 0; i < 4; i++)
#pragma unroll
    for (int j = 0; j < 4; j++) acc[i][j] = z;

  for (int k0 = 0; k0 < K; k0 += 32) {
#pragma unroll
    for (int c = 0; c < 2; c++) {
      GLOAD16(A + (size_t)(m0 + c * 64 + w * 16 + srow) * K + k0 + schunk * 8,
              As + c * 2048 + w * 512);
      GLOAD16(Bt + (size_t)(n0 + c * 64 + w * 16 + srow) * K + k0 + schunk * 8,
              Bs + c * 2048 + w * 512);
    }
    __syncthreads();
    bf16x8 a[4], b[4];
#pragma unroll
    for (int m = 0; m < 4; m++) {
      int row = wm * 64 + m * 16 + lr;
      a[m] = *(const bf16x8*)(As + row * 32 + ((lh ^ swzr) * 8));
    }
#pragma unroll
    for (int n = 0; n < 4; n++) {
      int row = wn * 64 + n * 16 + lr;
      b[n] = *(const bf16x8*)(Bs + row * 32 + ((lh ^ swzr) * 8));
    }
#pragma unroll
    for (int m = 0; m < 4; m++)
#pragma unroll
      for (int n = 0; n < 4; n++)
        acc[m][n] = __builtin_amdgcn_mfma_f32_16x16x32_bf16(a[m], b[n], acc[m][n], 0, 0, 0);
    __syncthreads();
  }
#pragma unroll
  for (int m = 0; m < 4; m++)
#pragma unroll
    for (int n = 0; n < 4; n++)
#pragma unroll
      for (int r = 0; r < 4; r++) {
        int row = m0 + wm * 64 + m * 16 + lh * 4 + r;
        int col = n0 + wn * 64 + n * 16 + lr;
        C[(size_t)row * N + col] = acc[m][n][r];
      }
}

// ---------------------------------------------------------------------------
// Causal MLA attention. NO min-waves bound (round-1's ",4" caused spills).
// reg-prefetch double buffer + per-lane l partials + depth-4 max reduce.
// Grid (S/64, NH). Block 256 = 4 waves, wave w owns q rows [q0+16w, +16).
// ---------------------------------------------------------------------------
__global__ __launch_bounds__(256) void attn(const unsigned short* __restrict__ Qb,
                                            const unsigned short* __restrict__ Kb,
                                            const unsigned short* __restrict__ Vt,
                                            unsigned short* __restrict__ O) {
  __shared__ unsigned short Kl[32 * 200];   // [32 t][192+8 d]
  __shared__ unsigned short Vl[128 * 40];   // [128 d][32+8 t]
  __shared__ unsigned short Pl[4][16 * 40]; // per-wave [16 q][32+8 t]
  const int tid = threadIdx.x;
  const int w = tid >> 6, lane = tid & 63;
  const int lr = lane & 15, lh = lane >> 4;
  const int h = blockIdx.y;
  const int q0 = blockIdx.x * 64;
  const int qw = q0 + w * 16;

  bf16x8 qf[6];
#pragma unroll
  for (int c = 0; c < 6; c++)
    qf[c] = *(const bf16x8*)(Qb + (size_t)(qw + lr) * 6144 + h * 192 + c * 32 + lh * 8);

  int krow[3], kcol[3];
#pragma unroll
  for (int j = 0; j < 3; j++) {
    int c = tid + j * 256;
    krow[j] = c / 24; kcol[j] = c - krow[j] * 24;
  }
  int vd[2], vc[2];
#pragma unroll
  for (int j = 0; j < 2; j++) {
    int c = tid + j * 256;
    vd[j] = c >> 2; vc[j] = c & 3;
  }
  const unsigned short* Kbase = Kb + h * 192;
  const unsigned short* Vbase = Vt + (size_t)h * 128 * 2048;

  int4 kreg[3], vreg[2];
#define ISSUE(T0)                                                              \
  {                                                                            \
    _Pragma("unroll") for (int j = 0; j < 3; j++)                              \
        kreg[j] = *(const int4*)(Kbase + (size_t)((T0) + krow[j]) * 6144 + kcol[j] * 8); \
    _Pragma("unroll") for (int j = 0; j < 2; j++)                              \
        vreg[j] = *(const int4*)(Vbase + (size_t)vd[j] * 2048 + (T0) + vc[j] * 8); \
  }

  f32x4 acc[8];
  const f32x4 z = {0.f, 0.f, 0.f, 0.f};
#pragma unroll
  for (int n = 0; n < 8; n++) acc[n] = z;
  float m[4] = {-1e30f, -1e30f, -1e30f, -1e30f};
  float l[4] = {0.f, 0.f, 0.f, 0.f};
  const float scale = 0.07216878364870322f;  // 192^-0.5

  const int nt = (q0 + 64) >> 5;
  ISSUE(0);
  for (int it = 0; it < nt; ++it) {
    const int t0 = it << 5;
    __syncthreads();
#pragma unroll
    for (int j = 0; j < 3; j++) *(int4*)(Kl + krow[j] * 200 + kcol[j] * 8) = kreg[j];
#pragma unroll
    for (int j = 0; j < 2; j++) *(int4*)(Vl + vd[j] * 40 + vc[j] * 8) = vreg[j];
    if (it + 1 < nt) ISSUE(t0 + 32);   // overlap next loads with compute below
    __syncthreads();
    if (t0 <= qw + 15) {
      f32x4 s0 = z, s1 = z;
#pragma unroll
      for (int c = 0; c < 6; c++) {
        bf16x8 k0 = *(const bf16x8*)(Kl + lr * 200 + c * 32 + lh * 8);
        bf16x8 k1 = *(const bf16x8*)(Kl + (16 + lr) * 200 + c * 32 + lh * 8);
        s0 = __builtin_amdgcn_mfma_f32_16x16x32_bf16(qf[c], k0, s0, 0, 0, 0);
        s1 = __builtin_amdgcn_mfma_f32_16x16x32_bf16(qf[c], k1, s1, 0, 0, 0);
      }
      float a0[4], a1[4], mx4[4];
#pragma unroll
      for (int r = 0; r < 4; r++) {
        const int qrow = qw + lh * 4 + r;
        a0[r] = (t0 + lr > qrow) ? -1e30f : s0[r] * scale;
        a1[r] = (t0 + 16 + lr > qrow) ? -1e30f : s1[r] * scale;
        mx4[r] = fmaxf(a0[r], a1[r]);
      }
#pragma unroll
      for (int off = 1; off < 16; off <<= 1) {
#pragma unroll
        for (int r = 0; r < 4; r++)
          mx4[r] = fmaxf(mx4[r], __shfl_xor(mx4[r], off, 16));
      }
      float ro[4];
#pragma unroll
      for (int r = 0; r < 4; r++) {
        float mn = fmaxf(m[r], mx4[r]);
        ro[r] = __expf(m[r] - mn);
        m[r] = mn;
        float p0 = __expf(a0[r] - mn), p1 = __expf(a1[r] - mn);
        l[r] = l[r] * ro[r] + p0 + p1;
        Pl[w][(lh * 4 + r) * 40 + lr]      = f2b(p0);
        Pl[w][(lh * 4 + r) * 40 + 16 + lr] = f2b(p1);
      }
#pragma unroll
      for (int n = 0; n < 8; n++)
#pragma unroll
        for (int r = 0; r < 4; r++) acc[n][r] *= ro[r];
      bf16x8 pa = *(const bf16x8*)(Pl[w] + lr * 40 + lh * 8);
#pragma unroll
      for (int n = 0; n < 8; n++) {
        bf16x8 vb = *(const bf16x8*)(Vl + (n * 16 + lr) * 40 + lh * 8);
        acc[n] = __builtin_amdgcn_mfma_f32_16x16x32_bf16(pa, vb, acc[n], 0, 0, 0);
      }
    }
  }
#undef ISSUE
#pragma unroll
  for (int off = 1; off < 16; off <<= 1) {
#pragma unroll
    for (int r = 0; r < 4; r++) l[r] += __shfl_xor(l[r], off, 16);
  }
  float inv[4];
#pragma unroll
  for (int r = 0; r < 4; r++) inv[r] = 1.f / l[r];
#pragma unroll
  for (int n = 0; n < 8; n++)
#pragma unroll
    for (int r = 0; r < 4; r++) {
      int q = qw + lh * 4 + r;
      O[(size_t)q * 4096 + h * 128 + n * 16 + lr] = f2b(acc[n][r] * inv[r]);
    }
}

// ---------------------------------------------------------------------------
extern "C" void kernel_launch(void* const* d_in, const int* in_sizes, int n_in,
                              void* d_out, int out_size, void* d_ws, size_t ws_size,
                              hipStream_t stream) {
  const float* hs      = (const float*)d_in[0];
  const float* q_a_w   = (const float*)d_in[1];
  const float* q_a_ln  = (const float*)d_in[2];
  const float* q_b_w   = (const float*)d_in[3];
  const float* kv_a_w  = (const float*)d_in[4];
  const float* kv_a_ln = (const float*)d_in[5];
  const float* kv_b_w  = (const float*)d_in[6];
  const float* o_w     = (const float*)d_in[7];
  float* out = (float*)d_out;

  char* ws = (char*)d_ws;
  size_t off = 0;
  auto alloc = [&](size_t bytes) {
    void* p = ws + off;
    off += (bytes + 255) & ~(size_t)255;
    return p;
  };
  unsigned short* q_a_wT  = (unsigned short*)alloc(1536UL * 2048 * 2);
  unsigned short* q_b_wT  = (unsigned short*)alloc(6144UL * 1536 * 2);
  unsigned short* kv_a_wT = (unsigned short*)alloc(640UL * 2048 * 2);
  unsigned short* kv_b_wT = (unsigned short*)alloc(8192UL * 512 * 2);
  unsigned short* o_wT    = (unsigned short*)alloc(2048UL * 4096 * 2);
  unsigned short* hs_b    = (unsigned short*)alloc(2048UL * 2048 * 2);
  unsigned short* q_a_n   = (unsigned short*)alloc(2048UL * 1536 * 2);
  unsigned short* Qb      = (unsigned short*)alloc(2048UL * 6144 * 2);
  float*          ckv_raw = (float*)alloc(2048UL * 640 * 4);
  unsigned short* ckv_n   = (unsigned short*)alloc(2048UL * 512 * 2);
  unsigned short* Kb      = (unsigned short*)alloc(2048UL * 6144 * 2);
  unsigned short* Vt      = (unsigned short*)alloc(32UL * 128 * 2048 * 2);
  float* big = (float*)alloc(2048UL * 8192 * 4);
  float* q_a_raw = big;
  float* q_raw   = big;
  float* kv_raw  = big;
  unsigned short* attn_out = (unsigned short*)big;
  (void)ws_size; (void)in_sizes; (void)n_in; (void)out_size;

  dim3 b256(256), b328(32, 8);
  castb<<<4096, b256, 0, stream>>>(hs, hs_b, 1048576);
  tcast<<<dim3(64, 48), b328, 0, stream>>>(q_a_w, q_a_wT, 2048, 1536, 1536);
  tcast<<<dim3(48, 192), b328, 0, stream>>>(q_b_w, q_b_wT, 1536, 6144, 6144);
  tcast<<<dim3(64, 20), b328, 0, stream>>>(kv_a_w, kv_a_wT, 2048, 576, 640);
  tcast<<<dim3(16, 256), b328, 0, stream>>>(kv_b_w, kv_b_wT, 512, 8192, 8192);
  tcast<<<dim3(128, 64), b328, 0, stream>>>(o_w, o_wT, 4096, 2048, 2048);
  gemm_bt<<<dim3(12, 16), b256, 0, stream>>>(hs_b, q_a_wT, q_a_raw, 2048, 1536, 2048);
  rmsnorm<<<2048, b256, 0, stream>>>(q_a_raw, q_a_ln, q_a_n, 1536, 1536);
  gemm_bt<<<dim3(48, 16), b256, 0, stream>>>(q_a_n, q_b_wT, q_raw, 2048, 6144, 1536);
  qrope<<<2048, b256, 0, stream>>>(q_raw, Qb);
  gemm_bt<<<dim3(5, 16), b256, 0, stream>>>(hs_b, kv_a_wT, ckv_raw, 2048, 640, 2048);
  rmsnorm<<<2048, b256, 0, stream>>>(ckv_raw, kv_a_ln, ckv_n, 512, 640);
  krot<<<2048, b256, 0, stream>>>(ckv_raw, Kb);
  gemm_bt<<<dim3(64, 16), b256, 0, stream>>>(ckv_n, kv_b_wT, kv_raw, 2048, 8192, 512);
  kvpass<<<2048, b256, 0, stream>>>(kv_raw, Kb);
  vtrans<<<dim3(64, 4, 32), b328, 0, stream>>>(kv_raw, Vt);
  attn<<<dim3(32, 32), b256, 0, stream>>>(Qb, Kb, Vt, attn_out);
  gemm_bt<<<dim3(16, 16), b256, 0, stream>>>(attn_out, o_wT, out, 2048, 2048, 4096);
}

// Round 4
// 581.312 us; speedup vs baseline: 1.3060x; 1.3060x over previous
//
#include <hip/hip_runtime.h>

// ---------------------------------------------------------------------------
// MLA forward (B=1, S=2048, HID=2048, NH=32, DQK=192(128+64 rope), DV=128)
// Round 3: attn staging -> global_load_lds double-buffered LDS (no prefetch
// VGPRs => no spill). K tile XOR-swizzled source+read; V tile linear.
// Reverse q-block dispatch for causal load balance.
// ---------------------------------------------------------------------------

typedef __bf16 bf16x8 __attribute__((ext_vector_type(8)));
typedef float  f32x4  __attribute__((ext_vector_type(4)));

#define GLOAD16(g, l)                                                          \
  __builtin_amdgcn_global_load_lds(                                            \
      (const __attribute__((address_space(1))) unsigned int*)(g),              \
      (__attribute__((address_space(3))) unsigned int*)(l), 16, 0, 0)

__device__ __forceinline__ unsigned short f2b(float f) {
  unsigned u = __builtin_bit_cast(unsigned, f);
  u += 0x7fffu + ((u >> 16) & 1u);   // round-to-nearest-even
  return (unsigned short)(u >> 16);
}

// ---------------- elementwise cast fp32 -> bf16 (vectorized) ----------------
__global__ __launch_bounds__(256) void castb(const float* __restrict__ s,
                                             unsigned short* __restrict__ d, int n4) {
  int i = blockIdx.x * 256 + threadIdx.x;
  if (i < n4) {
    float4 v = ((const float4*)s)[i];
    ushort4 o;
    o.x = f2b(v.x); o.y = f2b(v.y); o.z = f2b(v.z); o.w = f2b(v.w);
    ((ushort4*)d)[i] = o;
  }
}

// ------------- transpose-cast: src[R][C] f32 -> dst[Cpad][R] bf16 -----------
__global__ __launch_bounds__(256) void tcast(const float* __restrict__ src,
                                             unsigned short* __restrict__ dst,
                                             int R, int C, int Cpad) {
  __shared__ float t[32][33];
  int tx = threadIdx.x, ty = threadIdx.y;
  int r0 = blockIdx.x * 32, c0 = blockIdx.y * 32;
#pragma unroll
  for (int j = 0; j < 4; j++) {
    int c = c0 + tx;
    t[ty + j * 8][tx] = (c < C) ? src[(size_t)(r0 + ty + j * 8) * C + c] : 0.f;
  }
  __syncthreads();
#pragma unroll
  for (int j = 0; j < 4; j++)
    dst[(size_t)(c0 + ty + j * 8) * R + r0 + tx] = f2b(t[tx][ty + j * 8]);
}

// ---------------- RMSNorm row kernel: fp32 in -> bf16 out -------------------
__global__ __launch_bounds__(256) void rmsnorm(const float* __restrict__ x,
                                               const float* __restrict__ w,
                                               unsigned short* __restrict__ o,
                                               int C, int stride) {
  int row = blockIdx.x, tid = threadIdx.x;
  const float* xr = x + (size_t)row * stride;
  float ss = 0.f;
  for (int c = tid; c < C; c += 256) { float v = xr[c]; ss += v * v; }
#pragma unroll
  for (int off = 1; off < 64; off <<= 1) ss += __shfl_xor(ss, off, 64);
  __shared__ float red[4];
  if ((tid & 63) == 0) red[tid >> 6] = ss;
  __syncthreads();
  ss = red[0] + red[1] + red[2] + red[3];
  float r = rsqrtf(ss / C + 1e-6f);
  unsigned short* orow = o + (size_t)row * C;
  for (int c = tid; c < C; c += 256) orow[c] = f2b(xr[c] * r * w[c]);
}

// ------------- q RoPE + cast: q_raw[2048][6144] f32 -> Qb bf16 --------------
__global__ __launch_bounds__(256) void qrope(const float* __restrict__ q,
                                             unsigned short* __restrict__ Qb) {
  int s = blockIdx.x, tid = threadIdx.x;
  const float* qr = q + (size_t)s * 6144;
  unsigned short* ob = Qb + (size_t)s * 6144;
  for (int idx = tid; idx < 6144; idx += 256) {
    int d = idx % 192;
    float v = qr[idx], outv;
    if (d < 128) outv = v;
    else {
      int i = d - 128, ii = i & 31;
      float a = (float)s * exp2f(-(float)ii * 0.4152410118609203f);
      float cs = __cosf(a), sn = __sinf(a);
      if (i < 32) outv = v * cs - qr[idx + 32] * sn;
      else        outv = qr[idx - 32] * sn + v * cs;
    }
    ob[idx] = f2b(outv);
  }
}

// -------- k_rot rope + broadcast into Kb[t][h*192 + 128..192] ---------------
__global__ __launch_bounds__(256) void krot(const float* __restrict__ ckv,
                                            unsigned short* __restrict__ Kb) {
  int t = blockIdx.x, tid = threadIdx.x;
  __shared__ unsigned short rot[64];
  if (tid < 32) {
    float x1 = ckv[(size_t)t * 640 + 512 + tid];
    float x2 = ckv[(size_t)t * 640 + 544 + tid];
    float a = (float)t * exp2f(-(float)tid * 0.4152410118609203f);
    float cs = __cosf(a), sn = __sinf(a);
    rot[tid]      = f2b(x1 * cs - x2 * sn);
    rot[tid + 32] = f2b(x1 * sn + x2 * cs);
  }
  __syncthreads();
  for (int idx = tid; idx < 2048; idx += 256) {
    int h = idx >> 6, d = idx & 63;
    Kb[(size_t)t * 6144 + h * 192 + 128 + d] = rot[d];
  }
}

// -------- k_pass split: kv_raw[t][h*256 + d] -> Kb[t][h*192 + d], d<128 -----
__global__ __launch_bounds__(256) void kvpass(const float* __restrict__ kv,
                                              unsigned short* __restrict__ Kb) {
  int t = blockIdx.x, tid = threadIdx.x;
  for (int idx = tid; idx < 4096; idx += 256) {
    int h = idx >> 7, d = idx & 127;
    Kb[(size_t)t * 6144 + h * 192 + d] = f2b(kv[(size_t)t * 8192 + h * 256 + d]);
  }
}

// -------- V transpose: kv_raw[t][h*256+128+d] -> Vt[h*128+d][t] bf16 --------
__global__ __launch_bounds__(256) void vtrans(const float* __restrict__ kv,
                                              unsigned short* __restrict__ Vt) {
  __shared__ float t[32][33];
  int tx = threadIdx.x, ty = threadIdx.y;
  int t0 = blockIdx.x * 32, d0 = blockIdx.y * 32, h = blockIdx.z;
#pragma unroll
  for (int j = 0; j < 4; j++)
    t[ty + j * 8][tx] = kv[(size_t)(t0 + ty + j * 8) * 8192 + h * 256 + 128 + d0 + tx];
  __syncthreads();
#pragma unroll
  for (int j = 0; j < 4; j++)
    Vt[(size_t)(h * 128 + d0 + ty + j * 8) * 2048 + t0 + tx] = f2b(t[tx][ty + j * 8]);
}

// ---------------------------------------------------------------------------
// GEMM: C[M][N] f32 = A[M][K] bf16 * Bt[N][K] bf16 (unchanged)
// ---------------------------------------------------------------------------
__global__ __launch_bounds__(256) void gemm_bt(const unsigned short* __restrict__ A,
                                               const unsigned short* __restrict__ Bt,
                                               float* __restrict__ C,
                                               int M, int N, int K) {
  __shared__ unsigned short As[4096];
  __shared__ unsigned short Bs[4096];
  const int tid = threadIdx.x;
  const int w = tid >> 6, lane = tid & 63;
  const int lr = lane & 15, lh = lane >> 4;
  const int m0 = blockIdx.y * 128, n0 = blockIdx.x * 128;
  const int wm = w >> 1, wn = w & 1;
  const int srow = lane >> 2;
  const int schunk = (lane & 3) ^ ((lane >> 3) & 3);
  const int swzr = (lr >> 1) & 3;

  f32x4 acc[4][4];
  const f32x4 z = {0.f, 0.f, 0.f, 0.f};
#pragma unroll
  for (int i = 0; i < 4; i++)
#pragma unroll
    for (int j = 0; j < 4; j++) acc[i][j] = z;

  for (int k0 = 0; k0 < K; k0 += 32) {
#pragma unroll
    for (int c = 0; c < 2; c++) {
      GLOAD16(A + (size_t)(m0 + c * 64 + w * 16 + srow) * K + k0 + schunk * 8,
              As + c * 2048 + w * 512);
      GLOAD16(Bt + (size_t)(n0 + c * 64 + w * 16 + srow) * K + k0 + schunk * 8,
              Bs + c * 2048 + w * 512);
    }
    __syncthreads();
    bf16x8 a[4], b[4];
#pragma unroll
    for (int m = 0; m < 4; m++) {
      int row = wm * 64 + m * 16 + lr;
      a[m] = *(const bf16x8*)(As + row * 32 + ((lh ^ swzr) * 8));
    }
#pragma unroll
    for (int n = 0; n < 4; n++) {
      int row = wn * 64 + n * 16 + lr;
      b[n] = *(const bf16x8*)(Bs + row * 32 + ((lh ^ swzr) * 8));
    }
#pragma unroll
    for (int m = 0; m < 4; m++)
#pragma unroll
      for (int n = 0; n < 4; n++)
        acc[m][n] = __builtin_amdgcn_mfma_f32_16x16x32_bf16(a[m], b[n], acc[m][n], 0, 0, 0);
    __syncthreads();
  }
#pragma unroll
  for (int m = 0; m < 4; m++)
#pragma unroll
    for (int n = 0; n < 4; n++)
#pragma unroll
      for (int r = 0; r < 4; r++) {
        int row = m0 + wm * 64 + m * 16 + lh * 4 + r;
        int col = n0 + wn * 64 + n * 16 + lr;
        C[(size_t)row * N + col] = acc[m][n][r];
      }
}

// ---------------------------------------------------------------------------
// Causal MLA attention, round-3 structure:
//  - global_load_lds staging into double-buffered LDS (no prefetch VGPRs)
//  - K tile [32][192] linear dest, XOR chunk swizzle (source + read sides)
//  - V tile [128][32] linear (64 B stride = uniform banks, no swizzle)
//  - one __syncthreads per tile; stage of t+1 issued before compute of t
//  - reverse q-block dispatch (heaviest first) for causal load balance
// Grid (S/64, NH). Block 256 = 4 waves, wave w owns q rows [q0+16w, +16).
// ---------------------------------------------------------------------------
__global__ __launch_bounds__(256) void attn(const unsigned short* __restrict__ Qb,
                                            const unsigned short* __restrict__ Kb,
                                            const unsigned short* __restrict__ Vt,
                                            unsigned short* __restrict__ O) {
  __shared__ unsigned short Kl[2][6144];    // [32 t][192 d], chunk-swizzled
  __shared__ unsigned short Vl[2][4096];    // [128 d][32 t], linear
  __shared__ unsigned short Pl[4][16 * 40]; // per-wave [16 q][32+8 t]
  const int tid = threadIdx.x;
  const int w = tid >> 6, lane = tid & 63;
  const int lr = lane & 15, lh = lane >> 4;
  const int h = blockIdx.y;
  const int q0 = (gridDim.x - 1 - blockIdx.x) * 64;  // heavy blocks first
  const int qw = q0 + w * 16;

  bf16x8 qf[6];
#pragma unroll
  for (int c = 0; c < 6; c++)
    qf[c] = *(const bf16x8*)(Qb + (size_t)(qw + lr) * 6144 + h * 192 + c * 32 + lh * 8);

  // --- staging decomposition (pre-swizzled global source, linear LDS dest) ---
  const unsigned short* Kbase = Kb + h * 192;
  const unsigned short* Vbase = Vt + (size_t)h * 128 * 2048;
  size_t kga[3];
#pragma unroll
  for (int j = 0; j < 3; j++) {
    int c = w * 192 + j * 64 + lane;        // chunk 0..767 (16 B each)
    int r = c / 24, p = c - r * 24;         // row 0..31, physical chunk 0..23
    int ch = p ^ (r & 7);                   // logical chunk at this slot
    kga[j] = (size_t)r * 6144 + ch * 8;
  }
  size_t vga[2];
#pragma unroll
  for (int j = 0; j < 2; j++) {
    int c = w * 128 + j * 64 + lane;        // chunk 0..511
    int d = c >> 2, p = c & 3;
    vga[j] = (size_t)d * 2048 + p * 8;
  }

#define STAGE(T0, B)                                                           \
  {                                                                            \
    _Pragma("unroll") for (int j = 0; j < 3; j++)                              \
        GLOAD16(Kbase + (size_t)(T0) * 6144 + kga[j],                          \
                &Kl[B][(w * 192 + j * 64) * 8]);                               \
    _Pragma("unroll") for (int j = 0; j < 2; j++)                              \
        GLOAD16(Vbase + vga[j] + (T0), &Vl[B][(w * 128 + j * 64) * 8]);        \
  }

  f32x4 acc[8];
  const f32x4 z = {0.f, 0.f, 0.f, 0.f};
#pragma unroll
  for (int n = 0; n < 8; n++) acc[n] = z;
  float m[4] = {-1e30f, -1e30f, -1e30f, -1e30f};
  float l[4] = {0.f, 0.f, 0.f, 0.f};
  const float scale = 0.07216878364870322f;  // 192^-0.5
  const int swz = (lr & 7) * 8;              // read-side K swizzle (ushorts)

  const int nt = (q0 + 64) >> 5;
  STAGE(0, 0);
  __syncthreads();                            // drain stage -> buf0 ready
  for (int it = 0; it < nt; ++it) {
    const int t0 = it << 5;
    const int cur = it & 1;
    if (it + 1 < nt) STAGE(t0 + 32, cur ^ 1); // fly under compute below
    if (t0 <= qw + 15) {
      f32x4 s0 = z, s1 = z;
#pragma unroll
      for (int c = 0; c < 6; c++) {
        int col = ((c * 4 + lh) * 8) ^ swz;   // involution of staging swizzle
        bf16x8 k0 = *(const bf16x8*)(&Kl[cur][lr * 192 + col]);
        bf16x8 k1 = *(const bf16x8*)(&Kl[cur][(16 + lr) * 192 + col]);
        s0 = __builtin_amdgcn_mfma_f32_16x16x32_bf16(qf[c], k0, s0, 0, 0, 0);
        s1 = __builtin_amdgcn_mfma_f32_16x16x32_bf16(qf[c], k1, s1, 0, 0, 0);
      }
      float a0[4], a1[4], mx4[4];
#pragma unroll
      for (int r = 0; r < 4; r++) {
        const int qrow = qw + lh * 4 + r;
        a0[r] = (t0 + lr > qrow) ? -1e30f : s0[r] * scale;
        a1[r] = (t0 + 16 + lr > qrow) ? -1e30f : s1[r] * scale;
        mx4[r] = fmaxf(a0[r], a1[r]);
      }
#pragma unroll
      for (int off = 1; off < 16; off <<= 1) {
#pragma unroll
        for (int r = 0; r < 4; r++)
          mx4[r] = fmaxf(mx4[r], __shfl_xor(mx4[r], off, 16));
      }
      float ro[4];
#pragma unroll
      for (int r = 0; r < 4; r++) {
        float mn = fmaxf(m[r], mx4[r]);
        ro[r] = __expf(m[r] - mn);
        m[r] = mn;
        float p0 = __expf(a0[r] - mn), p1 = __expf(a1[r] - mn);
        l[r] = l[r] * ro[r] + p0 + p1;
        Pl[w][(lh * 4 + r) * 40 + lr]      = f2b(p0);
        Pl[w][(lh * 4 + r) * 40 + 16 + lr] = f2b(p1);
      }
#pragma unroll
      for (int n = 0; n < 8; n++)
#pragma unroll
        for (int r = 0; r < 4; r++) acc[n][r] *= ro[r];
      bf16x8 pa = *(const bf16x8*)(Pl[w] + lr * 40 + lh * 8);
#pragma unroll
      for (int n = 0; n < 8; n++) {
        bf16x8 vb = *(const bf16x8*)(&Vl[cur][(n * 16 + lr) * 32 + lh * 8]);
        acc[n] = __builtin_amdgcn_mfma_f32_16x16x32_bf16(pa, vb, acc[n], 0, 0, 0);
      }
    }
    __syncthreads();   // drains stage (vmcnt) + compute reads; buffers flip
  }
#undef STAGE
#pragma unroll
  for (int off = 1; off < 16; off <<= 1) {
#pragma unroll
    for (int r = 0; r < 4; r++) l[r] += __shfl_xor(l[r], off, 16);
  }
  float inv[4];
#pragma unroll
  for (int r = 0; r < 4; r++) inv[r] = 1.f / l[r];
#pragma unroll
  for (int n = 0; n < 8; n++)
#pragma unroll
    for (int r = 0; r < 4; r++) {
      int q = qw + lh * 4 + r;
      O[(size_t)q * 4096 + h * 128 + n * 16 + lr] = f2b(acc[n][r] * inv[r]);
    }
}

// ---------------------------------------------------------------------------
extern "C" void kernel_launch(void* const* d_in, const int* in_sizes, int n_in,
                              void* d_out, int out_size, void* d_ws, size_t ws_size,
                              hipStream_t stream) {
  const float* hs      = (const float*)d_in[0];
  const float* q_a_w   = (const float*)d_in[1];
  const float* q_a_ln  = (const float*)d_in[2];
  const float* q_b_w   = (const float*)d_in[3];
  const float* kv_a_w  = (const float*)d_in[4];
  const float* kv_a_ln = (const float*)d_in[5];
  const float* kv_b_w  = (const float*)d_in[6];
  const float* o_w     = (const float*)d_in[7];
  float* out = (float*)d_out;

  char* ws = (char*)d_ws;
  size_t off = 0;
  auto alloc = [&](size_t bytes) {
    void* p = ws + off;
    off += (bytes + 255) & ~(size_t)255;
    return p;
  };
  unsigned short* q_a_wT  = (unsigned short*)alloc(1536UL * 2048 * 2);
  unsigned short* q_b_wT  = (unsigned short*)alloc(6144UL * 1536 * 2);
  unsigned short* kv_a_wT = (unsigned short*)alloc(640UL * 2048 * 2);
  unsigned short* kv_b_wT = (unsigned short*)alloc(8192UL * 512 * 2);
  unsigned short* o_wT    = (unsigned short*)alloc(2048UL * 4096 * 2);
  unsigned short* hs_b    = (unsigned short*)alloc(2048UL * 2048 * 2);
  unsigned short* q_a_n   = (unsigned short*)alloc(2048UL * 1536 * 2);
  unsigned short* Qb      = (unsigned short*)alloc(2048UL * 6144 * 2);
  float*          ckv_raw = (float*)alloc(2048UL * 640 * 4);
  unsigned short* ckv_n   = (unsigned short*)alloc(2048UL * 512 * 2);
  unsigned short* Kb      = (unsigned short*)alloc(2048UL * 6144 * 2);
  unsigned short* Vt      = (unsigned short*)alloc(32UL * 128 * 2048 * 2);
  float* big = (float*)alloc(2048UL * 8192 * 4);
  float* q_a_raw = big;
  float* q_raw   = big;
  float* kv_raw  = big;
  unsigned short* attn_out = (unsigned short*)big;
  (void)ws_size; (void)in_sizes; (void)n_in; (void)out_size;

  dim3 b256(256), b328(32, 8);
  castb<<<4096, b256, 0, stream>>>(hs, hs_b, 1048576);
  tcast<<<dim3(64, 48), b328, 0, stream>>>(q_a_w, q_a_wT, 2048, 1536, 1536);
  tcast<<<dim3(48, 192), b328, 0, stream>>>(q_b_w, q_b_wT, 1536, 6144, 6144);
  tcast<<<dim3(64, 20), b328, 0, stream>>>(kv_a_w, kv_a_wT, 2048, 576, 640);
  tcast<<<dim3(16, 256), b328, 0, stream>>>(kv_b_w, kv_b_wT, 512, 8192, 8192);
  tcast<<<dim3(128, 64), b328, 0, stream>>>(o_w, o_wT, 4096, 2048, 2048);
  gemm_bt<<<dim3(12, 16), b256, 0, stream>>>(hs_b, q_a_wT, q_a_raw, 2048, 1536, 2048);
  rmsnorm<<<2048, b256, 0, stream>>>(q_a_raw, q_a_ln, q_a_n, 1536, 1536);
  gemm_bt<<<dim3(48, 16), b256, 0, stream>>>(q_a_n, q_b_wT, q_raw, 2048, 6144, 1536);
  qrope<<<2048, b256, 0, stream>>>(q_raw, Qb);
  gemm_bt<<<dim3(5, 16), b256, 0, stream>>>(hs_b, kv_a_wT, ckv_raw, 2048, 640, 2048);
  rmsnorm<<<2048, b256, 0, stream>>>(ckv_raw, kv_a_ln, ckv_n, 512, 640);
  krot<<<2048, b256, 0, stream>>>(ckv_raw, Kb);
  gemm_bt<<<dim3(64, 16), b256, 0, stream>>>(ckv_n, kv_b_wT, kv_raw, 2048, 8192, 512);
  kvpass<<<2048, b256, 0, stream>>>(kv_raw, Kb);
  vtrans<<<dim3(64, 4, 32), b328, 0, stream>>>(kv_raw, Vt);
  attn<<<dim3(32, 32), b256, 0, stream>>>(Qb, Kb, Vt, attn_out);
  gemm_bt<<<dim3(16, 16), b256, 0, stream>>>(attn_out, o_wT, out, 2048, 2048, 4096);
}

// Round 5
// 534.816 us; speedup vs baseline: 1.4195x; 1.0869x over previous
//
#include <hip/hip_runtime.h>

// ---------------------------------------------------------------------------
// MLA forward (B=1, S=2048, HID=2048, NH=32, DQK=192(128+64 rope), DV=128)
// Round 5: attn softmax in-register (swapped QK^T, cvt_pk+bpermute P-relayout,
// T13 defer-rescale, Pl LDS dropped -> 40 KB = 4 blocks/CU). qrope fused into
// q_b GEMM epilogue (template EPI).
// ---------------------------------------------------------------------------

typedef __bf16 bf16x8 __attribute__((ext_vector_type(8)));
typedef float  f32x4  __attribute__((ext_vector_type(4)));
typedef unsigned u32x4 __attribute__((ext_vector_type(4)));

#define GLOAD16(g, l)                                                          \
  __builtin_amdgcn_global_load_lds(                                            \
      (const __attribute__((address_space(1))) unsigned int*)(g),              \
      (__attribute__((address_space(3))) unsigned int*)(l), 16, 0, 0)

__device__ __forceinline__ unsigned short f2b(float f) {
  unsigned u = __builtin_bit_cast(unsigned, f);
  u += 0x7fffu + ((u >> 16) & 1u);   // round-to-nearest-even
  return (unsigned short)(u >> 16);
}

__device__ __forceinline__ unsigned cvtpk(float lo, float hi) {
  unsigned r;
  asm("v_cvt_pk_bf16_f32 %0, %1, %2" : "=v"(r) : "v"(lo), "v"(hi));
  return r;
}

// ---------------- elementwise cast fp32 -> bf16 (vectorized) ----------------
__global__ __launch_bounds__(256) void castb(const float* __restrict__ s,
                                             unsigned short* __restrict__ d, int n4) {
  int i = blockIdx.x * 256 + threadIdx.x;
  if (i < n4) {
    float4 v = ((const float4*)s)[i];
    ushort4 o;
    o.x = f2b(v.x); o.y = f2b(v.y); o.z = f2b(v.z); o.w = f2b(v.w);
    ((ushort4*)d)[i] = o;
  }
}

// ------------- transpose-cast: src[R][C] f32 -> dst[Cpad][R] bf16 -----------
__global__ __launch_bounds__(256) void tcast(const float* __restrict__ src,
                                             unsigned short* __restrict__ dst,
                                             int R, int C, int Cpad) {
  __shared__ float t[32][33];
  int tx = threadIdx.x, ty = threadIdx.y;
  int r0 = blockIdx.x * 32, c0 = blockIdx.y * 32;
#pragma unroll
  for (int j = 0; j < 4; j++) {
    int c = c0 + tx;
    t[ty + j * 8][tx] = (c < C) ? src[(size_t)(r0 + ty + j * 8) * C + c] : 0.f;
  }
  __syncthreads();
#pragma unroll
  for (int j = 0; j < 4; j++)
    dst[(size_t)(c0 + ty + j * 8) * R + r0 + tx] = f2b(t[tx][ty + j * 8]);
}

// ---------------- RMSNorm row kernel: fp32 in -> bf16 out -------------------
__global__ __launch_bounds__(256) void rmsnorm(const float* __restrict__ x,
                                               const float* __restrict__ w,
                                               unsigned short* __restrict__ o,
                                               int C, int stride) {
  int row = blockIdx.x, tid = threadIdx.x;
  const float* xr = x + (size_t)row * stride;
  float ss = 0.f;
  for (int c = tid; c < C; c += 256) { float v = xr[c]; ss += v * v; }
#pragma unroll
  for (int off = 1; off < 64; off <<= 1) ss += __shfl_xor(ss, off, 64);
  __shared__ float red[4];
  if ((tid & 63) == 0) red[tid >> 6] = ss;
  __syncthreads();
  ss = red[0] + red[1] + red[2] + red[3];
  float r = rsqrtf(ss / C + 1e-6f);
  unsigned short* orow = o + (size_t)row * C;
  for (int c = tid; c < C; c += 256) orow[c] = f2b(xr[c] * r * w[c]);
}

// -------- k_rot rope + broadcast into Kb[t][h*192 + 128..192] ---------------
__global__ __launch_bounds__(256) void krot(const float* __restrict__ ckv,
                                            unsigned short* __restrict__ Kb) {
  int t = blockIdx.x, tid = threadIdx.x;
  __shared__ unsigned short rot[64];
  if (tid < 32) {
    float x1 = ckv[(size_t)t * 640 + 512 + tid];
    float x2 = ckv[(size_t)t * 640 + 544 + tid];
    float a = (float)t * exp2f(-(float)tid * 0.4152410118609203f);
    float cs = __cosf(a), sn = __sinf(a);
    rot[tid]      = f2b(x1 * cs - x2 * sn);
    rot[tid + 32] = f2b(x1 * sn + x2 * cs);
  }
  __syncthreads();
  for (int idx = tid; idx < 2048; idx += 256) {
    int h = idx >> 6, d = idx & 63;
    Kb[(size_t)t * 6144 + h * 192 + 128 + d] = rot[d];
  }
}

// -------- k_pass split: kv_raw[t][h*256 + d] -> Kb[t][h*192 + d], d<128 -----
__global__ __launch_bounds__(256) void kvpass(const float* __restrict__ kv,
                                              unsigned short* __restrict__ Kb) {
  int t = blockIdx.x, tid = threadIdx.x;
  for (int idx = tid; idx < 4096; idx += 256) {
    int h = idx >> 7, d = idx & 127;
    Kb[(size_t)t * 6144 + h * 192 + d] = f2b(kv[(size_t)t * 8192 + h * 256 + d]);
  }
}

// -------- V transpose: kv_raw[t][h*256+128+d] -> Vt[h*128+d][t] bf16 --------
__global__ __launch_bounds__(256) void vtrans(const float* __restrict__ kv,
                                              unsigned short* __restrict__ Vt) {
  __shared__ float t[32][33];
  int tx = threadIdx.x, ty = threadIdx.y;
  int t0 = blockIdx.x * 32, d0 = blockIdx.y * 32, h = blockIdx.z;
#pragma unroll
  for (int j = 0; j < 4; j++)
    t[ty + j * 8][tx] = kv[(size_t)(t0 + ty + j * 8) * 8192 + h * 256 + 128 + d0 + tx];
  __syncthreads();
#pragma unroll
  for (int j = 0; j < 4; j++)
    Vt[(size_t)(h * 128 + d0 + ty + j * 8) * 2048 + t0 + tx] = f2b(t[tx][ty + j * 8]);
}

// ---------------------------------------------------------------------------
// GEMM: C[M][N] = A[M][K] bf16 * Bt[N][K] bf16.
// EPI=0: f32 output.  EPI=1: bf16 output with fused q-RoPE (N must be 6144,
// rope cols = col%192 in [128,192), pairs 32 apart -> acc[m][n+-2][r]).
// ---------------------------------------------------------------------------
template <int EPI>
__global__ __launch_bounds__(256) void gemm_bt(const unsigned short* __restrict__ A,
                                               const unsigned short* __restrict__ Bt,
                                               void* __restrict__ Cout,
                                               int M, int N, int K) {
  __shared__ unsigned short As[4096];
  __shared__ unsigned short Bs[4096];
  const int tid = threadIdx.x;
  const int w = tid >> 6, lane = tid & 63;
  const int lr = lane & 15, lh = lane >> 4;
  const int m0 = blockIdx.y * 128, n0 = blockIdx.x * 128;
  const int wm = w >> 1, wn = w & 1;
  const int srow = lane >> 2;
  const int schunk = (lane & 3) ^ ((lane >> 3) & 3);
  const int swzr = (lr >> 1) & 3;

  f32x4 acc[4][4];
  const f32x4 z = {0.f, 0.f, 0.f, 0.f};
#pragma unroll
  for (int i = 0; i < 4; i++)
#pragma unroll
    for (int j = 0; j < 4; j++) acc[i][j] = z;

  for (int k0 = 0; k0 < K; k0 += 32) {
#pragma unroll
    for (int c = 0; c < 2; c++) {
      GLOAD16(A + (size_t)(m0 + c * 64 + w * 16 + srow) * K + k0 + schunk * 8,
              As + c * 2048 + w * 512);
      GLOAD16(Bt + (size_t)(n0 + c * 64 + w * 16 + srow) * K + k0 + schunk * 8,
              Bs + c * 2048 + w * 512);
    }
    __syncthreads();
    bf16x8 a[4], b[4];
#pragma unroll
    for (int m = 0; m < 4; m++) {
      int row = wm * 64 + m * 16 + lr;
      a[m] = *(const bf16x8*)(As + row * 32 + ((lh ^ swzr) * 8));
    }
#pragma unroll
    for (int n = 0; n < 4; n++) {
      int row = wn * 64 + n * 16 + lr;
      b[n] = *(const bf16x8*)(Bs + row * 32 + ((lh ^ swzr) * 8));
    }
#pragma unroll
    for (int m = 0; m < 4; m++)
#pragma unroll
      for (int n = 0; n < 4; n++)
        acc[m][n] = __builtin_amdgcn_mfma_f32_16x16x32_bf16(a[m], b[n], acc[m][n], 0, 0, 0);
    __syncthreads();
  }
  if (EPI == 0) {
    float* C = (float*)Cout;
#pragma unroll
    for (int m = 0; m < 4; m++)
#pragma unroll
      for (int n = 0; n < 4; n++)
#pragma unroll
        for (int r = 0; r < 4; r++) {
          int row = m0 + wm * 64 + m * 16 + lh * 4 + r;
          int col = n0 + wn * 64 + n * 16 + lr;
          C[(size_t)row * N + col] = acc[m][n][r];
        }
  } else {
    unsigned short* C = (unsigned short*)Cout;
#pragma unroll
    for (int m = 0; m < 4; m++)
#pragma unroll
      for (int n = 0; n < 4; n++) {
        int colb = n0 + wn * 64 + n * 16;          // 16-col span, category-uniform
        int sb = colb % 192;
        bool isrope = sb >= 128;
        bool first  = sb < 160;                    // i < 32 half
        int col = colb + lr;
#pragma unroll
        for (int r = 0; r < 4; r++) {
          int row = m0 + wm * 64 + m * 16 + lh * 4 + r;
          float v = acc[m][n][r], o;
          if (!isrope) {
            o = v;
          } else {
            int ii = (col - 128) & 31;
            float ang = (float)row * exp2f(-(float)ii * 0.4152410118609203f);
            float cs = __cosf(ang), sn = __sinf(ang);
            float pa_ = acc[m][(n + 2) & 3][r];    // partner when first
            float pb_ = acc[m][(n + 6) & 3][r];    // partner when !first
            float partner = first ? pa_ : pb_;
            o = first ? (v * cs - partner * sn) : (partner * sn + v * cs);
          }
          C[(size_t)row * N + col] = f2b(o);
        }
      }
  }
}

// ---------------------------------------------------------------------------
// Causal MLA attention, round-5 structure:
//  - global_load_lds double-buffered staging (as round 4)
//  - SWAPPED QK^T: mfma(k, qf) -> S[t][q]; lane owns one q row (q = qw+lr)
//  - in-register softmax: 2-round max reduce, per-lane m/l scalars
//  - T13 defer-rescale (THR=8): skip acc rescale unless row max grew > 8
//  - P -> A-frag via v_cvt_pk_bf16_f32 + 8 bpermute (no P LDS buffer)
//  - LDS = 40960 B -> 4 blocks/CU
// Grid (S/64, NH). Block 256 = 4 waves, wave w owns q rows [q0+16w, +16).
// ---------------------------------------------------------------------------
__global__ __launch_bounds__(256) void attn(const unsigned short* __restrict__ Qb,
                                            const unsigned short* __restrict__ Kb,
                                            const unsigned short* __restrict__ Vt,
                                            unsigned short* __restrict__ O) {
  __shared__ unsigned short Kl[2][6144];    // [32 t][192 d], chunk-swizzled
  __shared__ unsigned short Vl[2][4096];    // [128 d][32 t], linear
  const int tid = threadIdx.x;
  const int w = tid >> 6, lane = tid & 63;
  const int lr = lane & 15, lh = lane >> 4;
  const int h = blockIdx.y;
  const int q0 = (gridDim.x - 1 - blockIdx.x) * 64;  // heavy blocks first
  const int qw = q0 + w * 16;
  const int qv = qw + lr;                   // this lane's softmax q row

  bf16x8 qf[6];
#pragma unroll
  for (int c = 0; c < 6; c++)
    qf[c] = *(const bf16x8*)(Qb + (size_t)(qw + lr) * 6144 + h * 192 + c * 32 + lh * 8);

  const unsigned short* Kbase = Kb + h * 192;
  const unsigned short* Vbase = Vt + (size_t)h * 128 * 2048;
  size_t kga[3];
#pragma unroll
  for (int j = 0; j < 3; j++) {
    int c = w * 192 + j * 64 + lane;        // chunk 0..767 (16 B each)
    int r = c / 24, p = c - r * 24;
    int ch = p ^ (r & 7);
    kga[j] = (size_t)r * 6144 + ch * 8;
  }
  size_t vga[2];
#pragma unroll
  for (int j = 0; j < 2; j++) {
    int c = w * 128 + j * 64 + lane;
    int d = c >> 2, p = c & 3;
    vga[j] = (size_t)d * 2048 + p * 8;
  }

#define STAGE(T0, B)                                                           \
  {                                                                            \
    _Pragma("unroll") for (int j = 0; j < 3; j++)                              \
        GLOAD16(Kbase + (size_t)(T0) * 6144 + kga[j],                          \
                &Kl[B][(w * 192 + j * 64) * 8]);                               \
    _Pragma("unroll") for (int j = 0; j < 2; j++)                              \
        GLOAD16(Vbase + vga[j] + (T0), &Vl[B][(w * 128 + j * 64) * 8]);        \
  }

  f32x4 acc[8];
  const f32x4 z = {0.f, 0.f, 0.f, 0.f};
#pragma unroll
  for (int n = 0; n < 8; n++) acc[n] = z;
  float mrow = -1e30f, lrow = 0.f;          // per-lane (q = qv)
  const float scale = 0.07216878364870322f; // 192^-0.5
  const int swz = (lr & 7) * 8;
  const int sA = lr + 32 * (lh & 1), sB = sA + 16;

  const int nt = (q0 + 64) >> 5;
  STAGE(0, 0);
  __syncthreads();
  for (int it = 0; it < nt; ++it) {
    const int t0 = it << 5;
    const int cur = it & 1;
    if (it + 1 < nt) STAGE(t0 + 32, cur ^ 1);
    if (t0 <= qw + 15) {
      f32x4 s0 = z, s1 = z;
#pragma unroll
      for (int c = 0; c < 6; c++) {
        int col = ((c * 4 + lh) * 8) ^ swz;
        bf16x8 k0 = *(const bf16x8*)(&Kl[cur][lr * 192 + col]);
        bf16x8 k1 = *(const bf16x8*)(&Kl[cur][(16 + lr) * 192 + col]);
        s0 = __builtin_amdgcn_mfma_f32_16x16x32_bf16(k0, qf[c], s0, 0, 0, 0);  // S[t][q]
        s1 = __builtin_amdgcn_mfma_f32_16x16x32_bf16(k1, qf[c], s1, 0, 0, 0);
      }
      // lane holds S[t0 + lh*4 + r][qv] (s0) and S[t0+16+lh*4+r][qv] (s1)
      const int tb = t0 + lh * 4;
      float a0[4], a1[4];
      float mx = -1e30f;
#pragma unroll
      for (int r = 0; r < 4; r++) {
        a0[r] = (tb + r > qv)      ? -1e30f : s0[r] * scale;
        a1[r] = (tb + 16 + r > qv) ? -1e30f : s1[r] * scale;
        mx = fmaxf(mx, fmaxf(a0[r], a1[r]));
      }
      mx = fmaxf(mx, __shfl_xor(mx, 16, 64));
      mx = fmaxf(mx, __shfl_xor(mx, 32, 64));
      float ro = 1.f;
      bool resc = (mx - mrow) > 8.f;        // T13 defer-rescale
      if (resc) { ro = __expf(mrow - mx); mrow = mx; }
      float p0[4], p1[4], ls = 0.f;
#pragma unroll
      for (int r = 0; r < 4; r++) {
        p0[r] = __expf(a0[r] - mrow);
        p1[r] = __expf(a1[r] - mrow);
        ls += p0[r] + p1[r];
      }
      lrow = lrow * ro + ls;
      if (__any(resc)) {
        float rs[4];
#pragma unroll
        for (int r = 0; r < 4; r++) rs[r] = __shfl(ro, lh * 4 + r, 16);
#pragma unroll
        for (int n = 0; n < 8; n++)
#pragma unroll
          for (int r = 0; r < 4; r++) acc[n][r] *= rs[r];
      }
      // pack P to bf16 pairs and relayout to PV A-fragment via bpermute
      unsigned pk0 = cvtpk(p0[0], p0[1]), pk1 = cvtpk(p0[2], p0[3]);
      unsigned pk2 = cvtpk(p1[0], p1[1]), pk3 = cvtpk(p1[2], p1[3]);
      unsigned A0 = __shfl(pk0, sA, 64), A1 = __shfl(pk1, sA, 64);
      unsigned B0 = __shfl(pk0, sB, 64), B1 = __shfl(pk1, sB, 64);
      unsigned C0 = __shfl(pk2, sA, 64), C1 = __shfl(pk3, sA, 64);
      unsigned D0 = __shfl(pk2, sB, 64), D1 = __shfl(pk3, sB, 64);
      u32x4 pw;
      pw[0] = (lh < 2) ? A0 : C0;
      pw[1] = (lh < 2) ? A1 : C1;
      pw[2] = (lh < 2) ? B0 : D0;
      pw[3] = (lh < 2) ? B1 : D1;
      bf16x8 pa = __builtin_bit_cast(bf16x8, pw);
#pragma unroll
      for (int n = 0; n < 8; n++) {
        bf16x8 vb = *(const bf16x8*)(&Vl[cur][(n * 16 + lr) * 32 + lh * 8]);
        acc[n] = __builtin_amdgcn_mfma_f32_16x16x32_bf16(pa, vb, acc[n], 0, 0, 0);
      }
    }
    __syncthreads();
  }
#undef STAGE
  lrow += __shfl_xor(lrow, 16, 64);
  lrow += __shfl_xor(lrow, 32, 64);
  float invL = 1.f / lrow;
  float inv[4];
#pragma unroll
  for (int r = 0; r < 4; r++) inv[r] = __shfl(invL, lh * 4 + r, 16);
#pragma unroll
  for (int n = 0; n < 8; n++)
#pragma unroll
    for (int r = 0; r < 4; r++) {
      int q = qw + lh * 4 + r;
      O[(size_t)q * 4096 + h * 128 + n * 16 + lr] = f2b(acc[n][r] * inv[r]);
    }
}

// ---------------------------------------------------------------------------
extern "C" void kernel_launch(void* const* d_in, const int* in_sizes, int n_in,
                              void* d_out, int out_size, void* d_ws, size_t ws_size,
                              hipStream_t stream) {
  const float* hs      = (const float*)d_in[0];
  const float* q_a_w   = (const float*)d_in[1];
  const float* q_a_ln  = (const float*)d_in[2];
  const float* q_b_w   = (const float*)d_in[3];
  const float* kv_a_w  = (const float*)d_in[4];
  const float* kv_a_ln = (const float*)d_in[5];
  const float* kv_b_w  = (const float*)d_in[6];
  const float* o_w     = (const float*)d_in[7];
  float* out = (float*)d_out;

  char* ws = (char*)d_ws;
  size_t off = 0;
  auto alloc = [&](size_t bytes) {
    void* p = ws + off;
    off += (bytes + 255) & ~(size_t)255;
    return p;
  };
  unsigned short* q_a_wT  = (unsigned short*)alloc(1536UL * 2048 * 2);
  unsigned short* q_b_wT  = (unsigned short*)alloc(6144UL * 1536 * 2);
  unsigned short* kv_a_wT = (unsigned short*)alloc(640UL * 2048 * 2);
  unsigned short* kv_b_wT = (unsigned short*)alloc(8192UL * 512 * 2);
  unsigned short* o_wT    = (unsigned short*)alloc(2048UL * 4096 * 2);
  unsigned short* hs_b    = (unsigned short*)alloc(2048UL * 2048 * 2);
  unsigned short* q_a_n   = (unsigned short*)alloc(2048UL * 1536 * 2);
  unsigned short* Qb      = (unsigned short*)alloc(2048UL * 6144 * 2);
  float*          ckv_raw = (float*)alloc(2048UL * 640 * 4);
  unsigned short* ckv_n   = (unsigned short*)alloc(2048UL * 512 * 2);
  unsigned short* Kb      = (unsigned short*)alloc(2048UL * 6144 * 2);
  unsigned short* Vt      = (unsigned short*)alloc(32UL * 128 * 2048 * 2);
  // Big transient region, time-shared: q_a_raw -> kv_raw -> attn_out
  float* big = (float*)alloc(2048UL * 8192 * 4);
  float* q_a_raw = big;
  float* kv_raw  = big;
  unsigned short* attn_out = (unsigned short*)big;
  (void)ws_size; (void)in_sizes; (void)n_in; (void)out_size;

  dim3 b256(256), b328(32, 8);
  castb<<<4096, b256, 0, stream>>>(hs, hs_b, 1048576);
  tcast<<<dim3(64, 48), b328, 0, stream>>>(q_a_w, q_a_wT, 2048, 1536, 1536);
  tcast<<<dim3(48, 192), b328, 0, stream>>>(q_b_w, q_b_wT, 1536, 6144, 6144);
  tcast<<<dim3(64, 20), b328, 0, stream>>>(kv_a_w, kv_a_wT, 2048, 576, 640);
  tcast<<<dim3(16, 256), b328, 0, stream>>>(kv_b_w, kv_b_wT, 512, 8192, 8192);
  tcast<<<dim3(128, 64), b328, 0, stream>>>(o_w, o_wT, 4096, 2048, 2048);
  // q path
  gemm_bt<0><<<dim3(12, 16), b256, 0, stream>>>(hs_b, q_a_wT, q_a_raw, 2048, 1536, 2048);
  rmsnorm<<<2048, b256, 0, stream>>>(q_a_raw, q_a_ln, q_a_n, 1536, 1536);
  gemm_bt<1><<<dim3(48, 16), b256, 0, stream>>>(q_a_n, q_b_wT, Qb, 2048, 6144, 1536);
  // kv path
  gemm_bt<0><<<dim3(5, 16), b256, 0, stream>>>(hs_b, kv_a_wT, ckv_raw, 2048, 640, 2048);
  rmsnorm<<<2048, b256, 0, stream>>>(ckv_raw, kv_a_ln, ckv_n, 512, 640);
  krot<<<2048, b256, 0, stream>>>(ckv_raw, Kb);
  gemm_bt<0><<<dim3(64, 16), b256, 0, stream>>>(ckv_n, kv_b_wT, kv_raw, 2048, 8192, 512);
  kvpass<<<2048, b256, 0, stream>>>(kv_raw, Kb);
  vtrans<<<dim3(64, 4, 32), b328, 0, stream>>>(kv_raw, Vt);
  // attention + output projection
  attn<<<dim3(32, 32), b256, 0, stream>>>(Qb, Kb, Vt, attn_out);
  gemm_bt<0><<<dim3(16, 16), b256, 0, stream>>>(attn_out, o_wT, out, 2048, 2048, 4096);
}

// Round 6
// 422.478 us; speedup vs baseline: 1.7970x; 1.2659x over previous
//
#include <hip/hip_runtime.h>

// ---------------------------------------------------------------------------
// MLA forward (B=1, S=2048, HID=2048, NH=32, DQK=192(128+64 rope), DV=128)
// Round 6: attn -> 8-wave blocks (128 q/block, K/V staged once per 128 q);
// q_a+kv_a GEMMs fused (N=2176); kv_b GEMM bf16 out; kvpass vectorized.
// ---------------------------------------------------------------------------

typedef __bf16 bf16x8 __attribute__((ext_vector_type(8)));
typedef float  f32x4  __attribute__((ext_vector_type(4)));
typedef unsigned u32x4 __attribute__((ext_vector_type(4)));

#define GLOAD16(g, l)                                                          \
  __builtin_amdgcn_global_load_lds(                                            \
      (const __attribute__((address_space(1))) unsigned int*)(g),              \
      (__attribute__((address_space(3))) unsigned int*)(l), 16, 0, 0)

__device__ __forceinline__ unsigned short f2b(float f) {
  unsigned u = __builtin_bit_cast(unsigned, f);
  u += 0x7fffu + ((u >> 16) & 1u);   // round-to-nearest-even
  return (unsigned short)(u >> 16);
}

__device__ __forceinline__ unsigned cvtpk(float lo, float hi) {
  unsigned r;
  asm("v_cvt_pk_bf16_f32 %0, %1, %2" : "=v"(r) : "v"(lo), "v"(hi));
  return r;
}

// ---------------- elementwise cast fp32 -> bf16 (vectorized) ----------------
__global__ __launch_bounds__(256) void castb(const float* __restrict__ s,
                                             unsigned short* __restrict__ d, int n4) {
  int i = blockIdx.x * 256 + threadIdx.x;
  if (i < n4) {
    float4 v = ((const float4*)s)[i];
    ushort4 o;
    o.x = f2b(v.x); o.y = f2b(v.y); o.z = f2b(v.z); o.w = f2b(v.w);
    ((ushort4*)d)[i] = o;
  }
}

// ------------- transpose-cast: src[R][C] f32 -> dst[Cpad][R] bf16 -----------
__global__ __launch_bounds__(256) void tcast(const float* __restrict__ src,
                                             unsigned short* __restrict__ dst,
                                             int R, int C, int Cpad) {
  __shared__ float t[32][33];
  int tx = threadIdx.x, ty = threadIdx.y;
  int r0 = blockIdx.x * 32, c0 = blockIdx.y * 32;
#pragma unroll
  for (int j = 0; j < 4; j++) {
    int c = c0 + tx;
    t[ty + j * 8][tx] = (c < C) ? src[(size_t)(r0 + ty + j * 8) * C + c] : 0.f;
  }
  __syncthreads();
#pragma unroll
  for (int j = 0; j < 4; j++)
    dst[(size_t)(c0 + ty + j * 8) * R + r0 + tx] = f2b(t[tx][ty + j * 8]);
}

// ---------------- RMSNorm row kernel: fp32 in -> bf16 out -------------------
__global__ __launch_bounds__(256) void rmsnorm(const float* __restrict__ x,
                                               const float* __restrict__ w,
                                               unsigned short* __restrict__ o,
                                               int C, int stride) {
  int row = blockIdx.x, tid = threadIdx.x;
  const float* xr = x + (size_t)row * stride;
  float ss = 0.f;
  for (int c = tid; c < C; c += 256) { float v = xr[c]; ss += v * v; }
#pragma unroll
  for (int off = 1; off < 64; off <<= 1) ss += __shfl_xor(ss, off, 64);
  __shared__ float red[4];
  if ((tid & 63) == 0) red[tid >> 6] = ss;
  __syncthreads();
  ss = red[0] + red[1] + red[2] + red[3];
  float r = rsqrtf(ss / C + 1e-6f);
  unsigned short* orow = o + (size_t)row * C;
  for (int c = tid; c < C; c += 256) orow[c] = f2b(xr[c] * r * w[c]);
}

// -------- k_rot rope + broadcast into Kb[t][h*192 + 128..192] ---------------
// reads fused raw buffer Craw[t][2176], k_rot at cols 2048..2111
__global__ __launch_bounds__(256) void krot(const float* __restrict__ craw,
                                            unsigned short* __restrict__ Kb) {
  int t = blockIdx.x, tid = threadIdx.x;
  __shared__ unsigned short rot[64];
  if (tid < 32) {
    float x1 = craw[(size_t)t * 2176 + 2048 + tid];
    float x2 = craw[(size_t)t * 2176 + 2080 + tid];
    float a = (float)t * exp2f(-(float)tid * 0.4152410118609203f);
    float cs = __cosf(a), sn = __sinf(a);
    rot[tid]      = f2b(x1 * cs - x2 * sn);
    rot[tid + 32] = f2b(x1 * sn + x2 * cs);
  }
  __syncthreads();
  for (int idx = tid; idx < 2048; idx += 256) {
    int h = idx >> 6, d = idx & 63;
    Kb[(size_t)t * 6144 + h * 192 + 128 + d] = rot[d];
  }
}

// -------- k_pass split: kvb[t][h*256+d] bf16 -> Kb[t][h*192+d], d<128 -------
__global__ __launch_bounds__(256) void kvpass(const unsigned short* __restrict__ kvb,
                                              unsigned short* __restrict__ Kb) {
  int t = blockIdx.x, tid = threadIdx.x;
  const ushort4* src = (const ushort4*)(kvb + (size_t)t * 8192);
#pragma unroll
  for (int j = 0; j < 4; j++) {
    int idx = tid + j * 256;               // 0..1023 ushort4 chunks (h,d<128)
    int h = idx >> 5, c = idx & 31;
    *(ushort4*)(Kb + (size_t)t * 6144 + h * 192 + c * 4) = src[h * 64 + c];
  }
}

// -------- V transpose: kvb[t][h*256+128+d] bf16 -> Vt[h*128+d][t] -----------
__global__ __launch_bounds__(256) void vtrans(const unsigned short* __restrict__ kvb,
                                              unsigned short* __restrict__ Vt) {
  __shared__ unsigned short t[32][34];
  int tx = threadIdx.x, ty = threadIdx.y;
  int t0 = blockIdx.x * 32, d0 = blockIdx.y * 32, h = blockIdx.z;
#pragma unroll
  for (int j = 0; j < 4; j++)
    t[ty + j * 8][tx] = kvb[(size_t)(t0 + ty + j * 8) * 8192 + h * 256 + 128 + d0 + tx];
  __syncthreads();
#pragma unroll
  for (int j = 0; j < 4; j++)
    Vt[(size_t)(h * 128 + d0 + ty + j * 8) * 2048 + t0 + tx] = t[tx][ty + j * 8];
}

// ---------------------------------------------------------------------------
// GEMM: C[M][N] = A[M][K] bf16 * Bt[N][K] bf16.
// EPI=0: f32 out. EPI=1: bf16 out + fused q-RoPE (N=6144). EPI=2: bf16 out.
// ---------------------------------------------------------------------------
template <int EPI>
__global__ __launch_bounds__(256) void gemm_bt(const unsigned short* __restrict__ A,
                                               const unsigned short* __restrict__ Bt,
                                               void* __restrict__ Cout,
                                               int M, int N, int K) {
  __shared__ unsigned short As[4096];
  __shared__ unsigned short Bs[4096];
  const int tid = threadIdx.x;
  const int w = tid >> 6, lane = tid & 63;
  const int lr = lane & 15, lh = lane >> 4;
  const int m0 = blockIdx.y * 128, n0 = blockIdx.x * 128;
  const int wm = w >> 1, wn = w & 1;
  const int srow = lane >> 2;
  const int schunk = (lane & 3) ^ ((lane >> 3) & 3);
  const int swzr = (lr >> 1) & 3;

  f32x4 acc[4][4];
  const f32x4 z = {0.f, 0.f, 0.f, 0.f};
#pragma unroll
  for (int i = 0; i < 4; i++)
#pragma unroll
    for (int j = 0; j < 4; j++) acc[i][j] = z;

  for (int k0 = 0; k0 < K; k0 += 32) {
#pragma unroll
    for (int c = 0; c < 2; c++) {
      GLOAD16(A + (size_t)(m0 + c * 64 + w * 16 + srow) * K + k0 + schunk * 8,
              As + c * 2048 + w * 512);
      GLOAD16(Bt + (size_t)(n0 + c * 64 + w * 16 + srow) * K + k0 + schunk * 8,
              Bs + c * 2048 + w * 512);
    }
    __syncthreads();
    bf16x8 a[4], b[4];
#pragma unroll
    for (int m = 0; m < 4; m++) {
      int row = wm * 64 + m * 16 + lr;
      a[m] = *(const bf16x8*)(As + row * 32 + ((lh ^ swzr) * 8));
    }
#pragma unroll
    for (int n = 0; n < 4; n++) {
      int row = wn * 64 + n * 16 + lr;
      b[n] = *(const bf16x8*)(Bs + row * 32 + ((lh ^ swzr) * 8));
    }
#pragma unroll
    for (int m = 0; m < 4; m++)
#pragma unroll
      for (int n = 0; n < 4; n++)
        acc[m][n] = __builtin_amdgcn_mfma_f32_16x16x32_bf16(a[m], b[n], acc[m][n], 0, 0, 0);
    __syncthreads();
  }
  if (EPI == 0) {
    float* C = (float*)Cout;
#pragma unroll
    for (int m = 0; m < 4; m++)
#pragma unroll
      for (int n = 0; n < 4; n++)
#pragma unroll
        for (int r = 0; r < 4; r++) {
          int row = m0 + wm * 64 + m * 16 + lh * 4 + r;
          int col = n0 + wn * 64 + n * 16 + lr;
          C[(size_t)row * N + col] = acc[m][n][r];
        }
  } else if (EPI == 2) {
    unsigned short* C = (unsigned short*)Cout;
#pragma unroll
    for (int m = 0; m < 4; m++)
#pragma unroll
      for (int n = 0; n < 4; n++)
#pragma unroll
        for (int r = 0; r < 4; r++) {
          int row = m0 + wm * 64 + m * 16 + lh * 4 + r;
          int col = n0 + wn * 64 + n * 16 + lr;
          C[(size_t)row * N + col] = f2b(acc[m][n][r]);
        }
  } else {
    unsigned short* C = (unsigned short*)Cout;
#pragma unroll
    for (int m = 0; m < 4; m++)
#pragma unroll
      for (int n = 0; n < 4; n++) {
        int colb = n0 + wn * 64 + n * 16;          // 16-col span, category-uniform
        int sb = colb % 192;
        bool isrope = sb >= 128;
        bool first  = sb < 160;                    // i < 32 half
        int col = colb + lr;
#pragma unroll
        for (int r = 0; r < 4; r++) {
          int row = m0 + wm * 64 + m * 16 + lh * 4 + r;
          float v = acc[m][n][r], o;
          if (!isrope) {
            o = v;
          } else {
            int ii = (col - 128) & 31;
            float ang = (float)row * exp2f(-(float)ii * 0.4152410118609203f);
            float cs = __cosf(ang), sn = __sinf(ang);
            float pa_ = acc[m][(n + 2) & 3][r];    // partner when first
            float pb_ = acc[m][(n + 6) & 3][r];    // partner when !first
            float partner = first ? pa_ : pb_;
            o = first ? (v * cs - partner * sn) : (partner * sn + v * cs);
          }
          C[(size_t)row * N + col] = f2b(o);
        }
      }
  }
}

// ---------------------------------------------------------------------------
// Causal MLA attention, round-6 structure: 8 waves (512 thr), 128 q/block.
// K/V staged ONCE per 128 q-rows (was per 64). Per-wave core = round 5:
// swapped QK^T -> S[t][q], in-register softmax, T13 defer-rescale,
// cvt_pk + bpermute P relayout, global_load_lds double-buffered staging.
// Grid (S/128, NH), reversed bx (heavy first).
// ---------------------------------------------------------------------------
__global__ __launch_bounds__(512) void attn(const unsigned short* __restrict__ Qb,
                                            const unsigned short* __restrict__ Kb,
                                            const unsigned short* __restrict__ Vt,
                                            unsigned short* __restrict__ O) {
  __shared__ unsigned short Kl[2][6144];    // [32 t][192 d], chunk-swizzled
  __shared__ unsigned short Vl[2][4096];    // [128 d][32 t], linear
  const int tid = threadIdx.x;
  const int w = tid >> 6, lane = tid & 63;
  const int lr = lane & 15, lh = lane >> 4;
  const int h = blockIdx.y;
  const int q0 = (gridDim.x - 1 - blockIdx.x) * 128;  // heavy blocks first
  const int qw = q0 + w * 16;
  const int qv = qw + lr;                   // this lane's softmax q row

  bf16x8 qf[6];
#pragma unroll
  for (int c = 0; c < 6; c++)
    qf[c] = *(const bf16x8*)(Qb + (size_t)(qw + lr) * 6144 + h * 192 + c * 32 + lh * 8);

  const unsigned short* Kbase = Kb + h * 192;
  const unsigned short* Vbase = Vt + (size_t)h * 128 * 2048;
  // K: 768 16B-chunks. wave w stages chunks [w*64, w*64+64); waves 0-3 also
  // [512+w*64, ...). V: 512 chunks, wave w stages [w*64, ...).
  size_t kga0, kga1 = 0;
  {
    int c = w * 64 + lane;
    int r = c / 24, p = c - r * 24;
    kga0 = (size_t)r * 6144 + (p ^ (r & 7)) * 8;
  }
  if (w < 4) {
    int c = 512 + w * 64 + lane;
    int r = c / 24, p = c - r * 24;
    kga1 = (size_t)r * 6144 + (p ^ (r & 7)) * 8;
  }
  size_t vga;
  {
    int c = w * 64 + lane;
    vga = (size_t)(c >> 2) * 2048 + (c & 3) * 8;
  }

#define STAGE(T0, B)                                                           \
  {                                                                            \
    GLOAD16(Kbase + (size_t)(T0) * 6144 + kga0, &Kl[B][w * 512]);              \
    if (w < 4)                                                                 \
      GLOAD16(Kbase + (size_t)(T0) * 6144 + kga1, &Kl[B][4096 + w * 512]);     \
    GLOAD16(Vbase + vga + (T0), &Vl[B][w * 512]);                              \
  }

  f32x4 acc[8];
  const f32x4 z = {0.f, 0.f, 0.f, 0.f};
#pragma unroll
  for (int n = 0; n < 8; n++) acc[n] = z;
  float mrow = -1e30f, lrow = 0.f;          // per-lane (q = qv)
  const float scale = 0.07216878364870322f; // 192^-0.5
  const int swz = (lr & 7) * 8;
  const int sA = lr + 32 * (lh & 1), sB = sA + 16;

  const int nt = (q0 + 128) >> 5;
  STAGE(0, 0);
  __syncthreads();
  for (int it = 0; it < nt; ++it) {
    const int t0 = it << 5;
    const int cur = it & 1;
    if (it + 1 < nt) STAGE(t0 + 32, cur ^ 1);
    if (t0 <= qw + 15) {
      f32x4 s0 = z, s1 = z;
#pragma unroll
      for (int c = 0; c < 6; c++) {
        int col = ((c * 4 + lh) * 8) ^ swz;
        bf16x8 k0 = *(const bf16x8*)(&Kl[cur][lr * 192 + col]);
        bf16x8 k1 = *(const bf16x8*)(&Kl[cur][(16 + lr) * 192 + col]);
        s0 = __builtin_amdgcn_mfma_f32_16x16x32_bf16(k0, qf[c], s0, 0, 0, 0);  // S[t][q]
        s1 = __builtin_amdgcn_mfma_f32_16x16x32_bf16(k1, qf[c], s1, 0, 0, 0);
      }
      const int tb = t0 + lh * 4;
      float a0[4], a1[4];
      float mx = -1e30f;
#pragma unroll
      for (int r = 0; r < 4; r++) {
        a0[r] = (tb + r > qv)      ? -1e30f : s0[r] * scale;
        a1[r] = (tb + 16 + r > qv) ? -1e30f : s1[r] * scale;
        mx = fmaxf(mx, fmaxf(a0[r], a1[r]));
      }
      mx = fmaxf(mx, __shfl_xor(mx, 16, 64));
      mx = fmaxf(mx, __shfl_xor(mx, 32, 64));
      float ro = 1.f;
      bool resc = (mx - mrow) > 8.f;        // T13 defer-rescale
      if (resc) { ro = __expf(mrow - mx); mrow = mx; }
      float p0[4], p1[4], ls = 0.f;
#pragma unroll
      for (int r = 0; r < 4; r++) {
        p0[r] = __expf(a0[r] - mrow);
        p1[r] = __expf(a1[r] - mrow);
        ls += p0[r] + p1[r];
      }
      lrow = lrow * ro + ls;
      if (__any(resc)) {
        float rs[4];
#pragma unroll
        for (int r = 0; r < 4; r++) rs[r] = __shfl(ro, lh * 4 + r, 16);
#pragma unroll
        for (int n = 0; n < 8; n++)
#pragma unroll
          for (int r = 0; r < 4; r++) acc[n][r] *= rs[r];
      }
      unsigned pk0 = cvtpk(p0[0], p0[1]), pk1 = cvtpk(p0[2], p0[3]);
      unsigned pk2 = cvtpk(p1[0], p1[1]), pk3 = cvtpk(p1[2], p1[3]);
      unsigned A0 = __shfl(pk0, sA, 64), A1 = __shfl(pk1, sA, 64);
      unsigned B0 = __shfl(pk0, sB, 64), B1 = __shfl(pk1, sB, 64);
      unsigned C0 = __shfl(pk2, sA, 64), C1 = __shfl(pk3, sA, 64);
      unsigned D0 = __shfl(pk2, sB, 64), D1 = __shfl(pk3, sB, 64);
      u32x4 pw;
      pw[0] = (lh < 2) ? A0 : C0;
      pw[1] = (lh < 2) ? A1 : C1;
      pw[2] = (lh < 2) ? B0 : D0;
      pw[3] = (lh < 2) ? B1 : D1;
      bf16x8 pa = __builtin_bit_cast(bf16x8, pw);
#pragma unroll
      for (int n = 0; n < 8; n++) {
        bf16x8 vb = *(const bf16x8*)(&Vl[cur][(n * 16 + lr) * 32 + lh * 8]);
        acc[n] = __builtin_amdgcn_mfma_f32_16x16x32_bf16(pa, vb, acc[n], 0, 0, 0);
      }
    }
    __syncthreads();
  }
#undef STAGE
  lrow += __shfl_xor(lrow, 16, 64);
  lrow += __shfl_xor(lrow, 32, 64);
  float invL = 1.f / lrow;
  float inv[4];
#pragma unroll
  for (int r = 0; r < 4; r++) inv[r] = __shfl(invL, lh * 4 + r, 16);
#pragma unroll
  for (int n = 0; n < 8; n++)
#pragma unroll
    for (int r = 0; r < 4; r++) {
      int q = qw + lh * 4 + r;
      O[(size_t)q * 4096 + h * 128 + n * 16 + lr] = f2b(acc[n][r] * inv[r]);
    }
}

// ---------------------------------------------------------------------------
extern "C" void kernel_launch(void* const* d_in, const int* in_sizes, int n_in,
                              void* d_out, int out_size, void* d_ws, size_t ws_size,
                              hipStream_t stream) {
  const float* hs      = (const float*)d_in[0];
  const float* q_a_w   = (const float*)d_in[1];
  const float* q_a_ln  = (const float*)d_in[2];
  const float* q_b_w   = (const float*)d_in[3];
  const float* kv_a_w  = (const float*)d_in[4];
  const float* kv_a_ln = (const float*)d_in[5];
  const float* kv_b_w  = (const float*)d_in[6];
  const float* o_w     = (const float*)d_in[7];
  float* out = (float*)d_out;

  char* ws = (char*)d_ws;
  size_t off = 0;
  auto alloc = [&](size_t bytes) {
    void* p = ws + off;
    off += (bytes + 255) & ~(size_t)255;
    return p;
  };
  unsigned short* wcat    = (unsigned short*)alloc(2176UL * 2048 * 2);  // [q_a | kv_a]
  unsigned short* q_b_wT  = (unsigned short*)alloc(6144UL * 1536 * 2);
  unsigned short* kv_b_wT = (unsigned short*)alloc(8192UL * 512 * 2);
  unsigned short* o_wT    = (unsigned short*)alloc(2048UL * 4096 * 2);
  unsigned short* hs_b    = (unsigned short*)alloc(2048UL * 2048 * 2);
  unsigned short* q_a_n   = (unsigned short*)alloc(2048UL * 1536 * 2);
  unsigned short* Qb      = (unsigned short*)alloc(2048UL * 6144 * 2);
  unsigned short* ckv_n   = (unsigned short*)alloc(2048UL * 512 * 2);
  unsigned short* Kb      = (unsigned short*)alloc(2048UL * 6144 * 2);
  unsigned short* Vt      = (unsigned short*)alloc(32UL * 128 * 2048 * 2);
  // Big transient region (64 MB), time-shared:
  //   [0, 32MB):  Craw f32 [2048][2176] (17.8MB)  ->  attn_out bf16 (16.8MB)
  //   [32,64MB):  kvb bf16 [2048][8192] (32MB)
  char* big = (char*)alloc(2048UL * 8192 * 4);
  float*          Craw     = (float*)big;
  unsigned short* attn_out = (unsigned short*)big;
  unsigned short* kvb      = (unsigned short*)(big + 33554432);
  (void)ws_size; (void)in_sizes; (void)n_in; (void)out_size;

  dim3 b256(256), b328(32, 8);
  // prep
  castb<<<4096, b256, 0, stream>>>(hs, hs_b, 1048576);
  tcast<<<dim3(64, 48), b328, 0, stream>>>(q_a_w, wcat, 2048, 1536, 1536);
  tcast<<<dim3(64, 20), b328, 0, stream>>>(kv_a_w, wcat + 1536UL * 2048, 2048, 576, 640);
  tcast<<<dim3(48, 192), b328, 0, stream>>>(q_b_w, q_b_wT, 1536, 6144, 6144);
  tcast<<<dim3(16, 256), b328, 0, stream>>>(kv_b_w, kv_b_wT, 512, 8192, 8192);
  tcast<<<dim3(128, 64), b328, 0, stream>>>(o_w, o_wT, 4096, 2048, 2048);
  // fused q_a + kv_a projection
  gemm_bt<0><<<dim3(17, 16), b256, 0, stream>>>(hs_b, wcat, Craw, 2048, 2176, 2048);
  rmsnorm<<<2048, b256, 0, stream>>>(Craw, q_a_ln, q_a_n, 1536, 2176);
  rmsnorm<<<2048, b256, 0, stream>>>(Craw + 1536, kv_a_ln, ckv_n, 512, 2176);
  krot<<<2048, b256, 0, stream>>>(Craw, Kb);
  // q path (rope fused in epilogue)
  gemm_bt<1><<<dim3(48, 16), b256, 0, stream>>>(q_a_n, q_b_wT, Qb, 2048, 6144, 1536);
  // kv path (bf16 out)
  gemm_bt<2><<<dim3(64, 16), b256, 0, stream>>>(ckv_n, kv_b_wT, kvb, 2048, 8192, 512);
  kvpass<<<2048, b256, 0, stream>>>(kvb, Kb);
  vtrans<<<dim3(64, 4, 32), b328, 0, stream>>>(kvb, Vt);
  // attention + output projection
  attn<<<dim3(16, 32), dim3(512), 0, stream>>>(Qb, Kb, Vt, attn_out);
  gemm_bt<0><<<dim3(16, 16), b256, 0, stream>>>(attn_out, o_wT, out, 2048, 2048, 4096);
}

// Round 7
// 402.752 us; speedup vs baseline: 1.8850x; 1.0490x over previous
//
#include <hip/hip_runtime.h>

// ---------------------------------------------------------------------------
// MLA forward (B=1, S=2048, HID=2048, NH=32, DQK=192(128+64 rope), DV=128)
// Round 7: 256^2 8-phase counted-vmcnt GEMM (T3+T4+T5) for q_b & kv_b;
// attn V-tile conflict-free swizzle + setprio around MFMA clusters.
// ---------------------------------------------------------------------------

typedef __bf16 bf16x8 __attribute__((ext_vector_type(8)));
typedef float  f32x4  __attribute__((ext_vector_type(4)));
typedef unsigned u32x4 __attribute__((ext_vector_type(4)));

#define GLOAD16(g, l)                                                          \
  __builtin_amdgcn_global_load_lds(                                            \
      (const __attribute__((address_space(1))) unsigned int*)(g),              \
      (__attribute__((address_space(3))) unsigned int*)(l), 16, 0, 0)

__device__ __forceinline__ unsigned short f2b(float f) {
  unsigned u = __builtin_bit_cast(unsigned, f);
  u += 0x7fffu + ((u >> 16) & 1u);   // round-to-nearest-even
  return (unsigned short)(u >> 16);
}

__device__ __forceinline__ unsigned cvtpk(float lo, float hi) {
  unsigned r;
  asm("v_cvt_pk_bf16_f32 %0, %1, %2" : "=v"(r) : "v"(lo), "v"(hi));
  return r;
}

// ---------------- elementwise cast fp32 -> bf16 (vectorized) ----------------
__global__ __launch_bounds__(256) void castb(const float* __restrict__ s,
                                             unsigned short* __restrict__ d, int n4) {
  int i = blockIdx.x * 256 + threadIdx.x;
  if (i < n4) {
    float4 v = ((const float4*)s)[i];
    ushort4 o;
    o.x = f2b(v.x); o.y = f2b(v.y); o.z = f2b(v.z); o.w = f2b(v.w);
    ((ushort4*)d)[i] = o;
  }
}

// ------------- transpose-cast: src[R][C] f32 -> dst[Cpad][R] bf16 -----------
__global__ __launch_bounds__(256) void tcast(const float* __restrict__ src,
                                             unsigned short* __restrict__ dst,
                                             int R, int C, int Cpad) {
  __shared__ float t[32][33];
  int tx = threadIdx.x, ty = threadIdx.y;
  int r0 = blockIdx.x * 32, c0 = blockIdx.y * 32;
#pragma unroll
  for (int j = 0; j < 4; j++) {
    int c = c0 + tx;
    t[ty + j * 8][tx] = (c < C) ? src[(size_t)(r0 + ty + j * 8) * C + c] : 0.f;
  }
  __syncthreads();
#pragma unroll
  for (int j = 0; j < 4; j++)
    dst[(size_t)(c0 + ty + j * 8) * R + r0 + tx] = f2b(t[tx][ty + j * 8]);
}

// ---------------- RMSNorm row kernel: fp32 in -> bf16 out -------------------
__global__ __launch_bounds__(256) void rmsnorm(const float* __restrict__ x,
                                               const float* __restrict__ w,
                                               unsigned short* __restrict__ o,
                                               int C, int stride) {
  int row = blockIdx.x, tid = threadIdx.x;
  const float* xr = x + (size_t)row * stride;
  float ss = 0.f;
  for (int c = tid; c < C; c += 256) { float v = xr[c]; ss += v * v; }
#pragma unroll
  for (int off = 1; off < 64; off <<= 1) ss += __shfl_xor(ss, off, 64);
  __shared__ float red[4];
  if ((tid & 63) == 0) red[tid >> 6] = ss;
  __syncthreads();
  ss = red[0] + red[1] + red[2] + red[3];
  float r = rsqrtf(ss / C + 1e-6f);
  unsigned short* orow = o + (size_t)row * C;
  for (int c = tid; c < C; c += 256) orow[c] = f2b(xr[c] * r * w[c]);
}

// -------- k_rot rope + broadcast into Kb[t][h*192 + 128..192] ---------------
__global__ __launch_bounds__(256) void krot(const float* __restrict__ craw,
                                            unsigned short* __restrict__ Kb) {
  int t = blockIdx.x, tid = threadIdx.x;
  __shared__ unsigned short rot[64];
  if (tid < 32) {
    float x1 = craw[(size_t)t * 2176 + 2048 + tid];
    float x2 = craw[(size_t)t * 2176 + 2080 + tid];
    float a = (float)t * exp2f(-(float)tid * 0.4152410118609203f);
    float cs = __cosf(a), sn = __sinf(a);
    rot[tid]      = f2b(x1 * cs - x2 * sn);
    rot[tid + 32] = f2b(x1 * sn + x2 * cs);
  }
  __syncthreads();
  for (int idx = tid; idx < 2048; idx += 256) {
    int h = idx >> 6, d = idx & 63;
    Kb[(size_t)t * 6144 + h * 192 + 128 + d] = rot[d];
  }
}

// -------- k_pass split: kvb[t][h*256+d] bf16 -> Kb[t][h*192+d], d<128 -------
__global__ __launch_bounds__(256) void kvpass(const unsigned short* __restrict__ kvb,
                                              unsigned short* __restrict__ Kb) {
  int t = blockIdx.x, tid = threadIdx.x;
  const ushort4* src = (const ushort4*)(kvb + (size_t)t * 8192);
#pragma unroll
  for (int j = 0; j < 4; j++) {
    int idx = tid + j * 256;
    int h = idx >> 5, c = idx & 31;
    *(ushort4*)(Kb + (size_t)t * 6144 + h * 192 + c * 4) = src[h * 64 + c];
  }
}

// -------- V transpose: kvb[t][h*256+128+d] bf16 -> Vt[h*128+d][t] -----------
__global__ __launch_bounds__(256) void vtrans(const unsigned short* __restrict__ kvb,
                                              unsigned short* __restrict__ Vt) {
  __shared__ unsigned short t[32][34];
  int tx = threadIdx.x, ty = threadIdx.y;
  int t0 = blockIdx.x * 32, d0 = blockIdx.y * 32, h = blockIdx.z;
#pragma unroll
  for (int j = 0; j < 4; j++)
    t[ty + j * 8][tx] = kvb[(size_t)(t0 + ty + j * 8) * 8192 + h * 256 + 128 + d0 + tx];
  __syncthreads();
#pragma unroll
  for (int j = 0; j < 4; j++)
    Vt[(size_t)(h * 128 + d0 + ty + j * 8) * 2048 + t0 + tx] = t[tx][ty + j * 8];
}

// ---------------------------------------------------------------------------
// 128^2 GEMM (m97 structure) — kept for fused-a (N=2176) and o-proj (N=2048).
// EPI=0: f32 out. EPI=2: bf16 out.
// ---------------------------------------------------------------------------
template <int EPI>
__global__ __launch_bounds__(256) void gemm_bt(const unsigned short* __restrict__ A,
                                               const unsigned short* __restrict__ Bt,
                                               void* __restrict__ Cout,
                                               int M, int N, int K) {
  __shared__ unsigned short As[4096];
  __shared__ unsigned short Bs[4096];
  const int tid = threadIdx.x;
  const int w = tid >> 6, lane = tid & 63;
  const int lr = lane & 15, lh = lane >> 4;
  const int m0 = blockIdx.y * 128, n0 = blockIdx.x * 128;
  const int wm = w >> 1, wn = w & 1;
  const int srow = lane >> 2;
  const int schunk = (lane & 3) ^ ((lane >> 3) & 3);
  const int swzr = (lr >> 1) & 3;

  f32x4 acc[4][4];
  const f32x4 z = {0.f, 0.f, 0.f, 0.f};
#pragma unroll
  for (int i = 0; i < 4; i++)
#pragma unroll
    for (int j = 0; j < 4; j++) acc[i][j] = z;

  for (int k0 = 0; k0 < K; k0 += 32) {
#pragma unroll
    for (int c = 0; c < 2; c++) {
      GLOAD16(A + (size_t)(m0 + c * 64 + w * 16 + srow) * K + k0 + schunk * 8,
              As + c * 2048 + w * 512);
      GLOAD16(Bt + (size_t)(n0 + c * 64 + w * 16 + srow) * K + k0 + schunk * 8,
              Bs + c * 2048 + w * 512);
    }
    __syncthreads();
    bf16x8 a[4], b[4];
#pragma unroll
    for (int m = 0; m < 4; m++) {
      int row = wm * 64 + m * 16 + lr;
      a[m] = *(const bf16x8*)(As + row * 32 + ((lh ^ swzr) * 8));
    }
#pragma unroll
    for (int n = 0; n < 4; n++) {
      int row = wn * 64 + n * 16 + lr;
      b[n] = *(const bf16x8*)(Bs + row * 32 + ((lh ^ swzr) * 8));
    }
#pragma unroll
    for (int m = 0; m < 4; m++)
#pragma unroll
      for (int n = 0; n < 4; n++)
        acc[m][n] = __builtin_amdgcn_mfma_f32_16x16x32_bf16(a[m], b[n], acc[m][n], 0, 0, 0);
    __syncthreads();
  }
  if (EPI == 0) {
    float* C = (float*)Cout;
#pragma unroll
    for (int m = 0; m < 4; m++)
#pragma unroll
      for (int n = 0; n < 4; n++)
#pragma unroll
        for (int r = 0; r < 4; r++) {
          int row = m0 + wm * 64 + m * 16 + lh * 4 + r;
          int col = n0 + wn * 64 + n * 16 + lr;
          C[(size_t)row * N + col] = acc[m][n][r];
        }
  } else {
    unsigned short* C = (unsigned short*)Cout;
#pragma unroll
    for (int m = 0; m < 4; m++)
#pragma unroll
      for (int n = 0; n < 4; n++)
#pragma unroll
        for (int r = 0; r < 4; r++) {
          int row = m0 + wm * 64 + m * 16 + lh * 4 + r;
          int col = n0 + wn * 64 + n * 16 + lr;
          C[(size_t)row * N + col] = f2b(acc[m][n][r]);
        }
  }
}

// ---------------------------------------------------------------------------
// 256^2 8-phase GEMM (T3+T4+T5). BM=BN=256, BK=64, 8 waves (2Mx4N), 512 thr,
// LDS 128 KiB double-buffered. Per K-tile: 4 phases, each {ds_read subtile ||
// half-tile stage -> s_barrier -> setprio(1) -> 16 MFMA -> setprio(0) ->
// s_barrier}; one vmcnt(0) per K-tile (all next-tile loads issued in ph0/ph1).
// Chunk swizzle chunk^=(row&7) on stage-source AND read (conflict-free b128).
// EPI=1: bf16 out + fused q-RoPE. EPI=2: bf16 out.
// ---------------------------------------------------------------------------
template <int EPI>
__global__ __launch_bounds__(512) void gemm256(const unsigned short* __restrict__ A,
                                               const unsigned short* __restrict__ Bt,
                                               void* __restrict__ Cout,
                                               int M, int N, int K) {
  __shared__ unsigned short lds[2][2][16384];   // [buf][op A/B][256*64] = 128 KiB
  const int tid = threadIdx.x;
  const int w = tid >> 6, lane = tid & 63;
  const int lr = lane & 15, lh = lane >> 4;
  const int wr = w >> 2, wc = w & 3;            // 2 x 4 waves
  const int m0 = blockIdx.y * 256, n0 = blockIdx.x * 256;

  // staging decomposition: half-tile = [128 rows][64 k] = 1024 x 16B chunks;
  // thread stages chunks tid and 512+tid; source chunk pre-swizzled.
  int soff[2];
#pragma unroll
  for (int j = 0; j < 2; j++) {
    int c = j * 512 + tid;
    int row = c >> 3, p = c & 7;
    soff[j] = row * K + (p ^ (row & 7)) * 8;
  }
  const unsigned short* Abase = A + (size_t)m0 * K;
  const unsigned short* Bbase = Bt + (size_t)n0 * K;
  const int rswz = lr & 7;                      // read-side swizzle key

#define STAGEOP(op, Base, kt, buf)                                             \
  {                                                                            \
    _Pragma("unroll") for (int h = 0; h < 2; h++)                              \
    _Pragma("unroll") for (int j = 0; j < 2; j++)                              \
      GLOAD16(Base + (size_t)(h * 128) * K + soff[j] + (kt) * 64,              \
              &lds[buf][op][(h * 1024 + j * 512 + w * 64) * 8]);               \
  }
#define READA(mh, buf)                                                         \
  {                                                                            \
    _Pragma("unroll") for (int mi = 0; mi < 4; mi++)                           \
    _Pragma("unroll") for (int ks = 0; ks < 2; ks++)                           \
      af[mi][ks] = *(const bf16x8*)&lds[buf][0][                               \
          (wr * 128 + ((mh) * 4 + mi) * 16 + lr) * 64 +                        \
          (((ks * 4 + lh) ^ rswz) * 8)];                                       \
  }
#define READB(n, buf)                                                          \
  {                                                                            \
    _Pragma("unroll") for (int ks = 0; ks < 2; ks++)                           \
      bfr[n][ks] = *(const bf16x8*)&lds[buf][1][                               \
          (wc * 64 + (n) * 16 + lr) * 64 + (((ks * 4 + lh) ^ rswz) * 8)];      \
  }
#define MFMAQ(mh, nh)                                                          \
  {                                                                            \
    __builtin_amdgcn_s_setprio(1);                                             \
    _Pragma("unroll") for (int mi = 0; mi < 4; mi++)                           \
    _Pragma("unroll") for (int ni = 0; ni < 2; ni++)                           \
    _Pragma("unroll") for (int ks = 0; ks < 2; ks++)                           \
      acc[(mh) * 4 + mi][(nh) * 2 + ni] =                                      \
          __builtin_amdgcn_mfma_f32_16x16x32_bf16(                             \
              af[mi][ks], bfr[(nh) * 2 + ni][ks],                              \
              acc[(mh) * 4 + mi][(nh) * 2 + ni], 0, 0, 0);                     \
    __builtin_amdgcn_s_setprio(0);                                             \
  }

  f32x4 acc[8][4];
  const f32x4 z = {0.f, 0.f, 0.f, 0.f};
#pragma unroll
  for (int i = 0; i < 8; i++)
#pragma unroll
    for (int j = 0; j < 4; j++) acc[i][j] = z;

  // prologue: stage K-tile 0 into buf 0, drain, sync
  STAGEOP(0, Abase, 0, 0);
  STAGEOP(1, Bbase, 0, 0);
  asm volatile("s_waitcnt vmcnt(0)" ::: "memory");
  __builtin_amdgcn_s_barrier();

  const int KT = K >> 6;
  for (int kt = 0; kt < KT; ++kt) {
    const int buf = kt & 1;
    const bool more = (kt + 1 < KT);
    bf16x8 af[4][2], bfr[4][2];
    // phase 0: A(mh=0) + B(n0,n1) reads; stage next A; MFMA Q(0,0)
    READA(0, buf);
    READB(0, buf); READB(1, buf);
    if (more) STAGEOP(0, Abase, kt + 1, buf ^ 1);
    __builtin_amdgcn_s_barrier();
    MFMAQ(0, 0);
    __builtin_amdgcn_s_barrier();
    // phase 1: B(n2,n3) reads; stage next B; MFMA Q(0,1)
    READB(2, buf); READB(3, buf);
    if (more) STAGEOP(1, Bbase, kt + 1, buf ^ 1);
    __builtin_amdgcn_s_barrier();
    MFMAQ(0, 1);
    __builtin_amdgcn_s_barrier();
    // phase 2: A(mh=1) reads; MFMA Q(1,1)
    READA(1, buf);
    __builtin_amdgcn_s_barrier();
    MFMAQ(1, 1);
    __builtin_amdgcn_s_barrier();
    // phase 3: MFMA Q(1,0); counted drain of next-tile stages; flip
    MFMAQ(1, 0);
    if (more) asm volatile("s_waitcnt vmcnt(0)" ::: "memory");
    __builtin_amdgcn_s_barrier();
  }
#undef STAGEOP
#undef READA
#undef READB
#undef MFMAQ

  unsigned short* C = (unsigned short*)Cout;
  if (EPI == 2) {
#pragma unroll
    for (int m = 0; m < 8; m++)
#pragma unroll
      for (int n = 0; n < 4; n++)
#pragma unroll
        for (int r = 0; r < 4; r++) {
          int row = m0 + wr * 128 + m * 16 + lh * 4 + r;
          int col = n0 + wc * 64 + n * 16 + lr;
          C[(size_t)row * N + col] = f2b(acc[m][n][r]);
        }
  } else {  // EPI == 1: fused q-RoPE
#pragma unroll
    for (int m = 0; m < 8; m++)
#pragma unroll
      for (int n = 0; n < 4; n++) {
        int colb = n0 + wc * 64 + n * 16;       // 16-col span, category-uniform
        int sb = colb % 192;
        bool isrope = sb >= 128;
        bool first  = sb < 160;
        int col = colb + lr;
#pragma unroll
        for (int r = 0; r < 4; r++) {
          int row = m0 + wr * 128 + m * 16 + lh * 4 + r;
          float v = acc[m][n][r], o;
          if (!isrope) {
            o = v;
          } else {
            int ii = (col - 128) & 31;
            float ang = (float)row * exp2f(-(float)ii * 0.4152410118609203f);
            float cs = __cosf(ang), sn = __sinf(ang);
            float pa_ = acc[m][(n + 2) & 3][r];
            float pb_ = acc[m][(n + 6) & 3][r];
            float partner = first ? pa_ : pb_;
            o = first ? (v * cs - partner * sn) : (partner * sn + v * cs);
          }
          C[(size_t)row * N + col] = f2b(o);
        }
      }
  }
}

// ---------------------------------------------------------------------------
// Causal MLA attention (round-6 structure) + V-tile conflict-free swizzle
// (chunk ^= (d>>1)&3 on stage-source and read) + setprio around MFMA clusters.
// Grid (S/128, NH) reversed; 8 waves (512 thr), 128 q/block.
// ---------------------------------------------------------------------------
__global__ __launch_bounds__(512) void attn(const unsigned short* __restrict__ Qb,
                                            const unsigned short* __restrict__ Kb,
                                            const unsigned short* __restrict__ Vt,
                                            unsigned short* __restrict__ O) {
  __shared__ unsigned short Kl[2][6144];    // [32 t][192 d], chunk-swizzled
  __shared__ unsigned short Vl[2][4096];    // [128 d][32 t], chunk-swizzled
  const int tid = threadIdx.x;
  const int w = tid >> 6, lane = tid & 63;
  const int lr = lane & 15, lh = lane >> 4;
  const int h = blockIdx.y;
  const int q0 = (gridDim.x - 1 - blockIdx.x) * 128;  // heavy blocks first
  const int qw = q0 + w * 16;
  const int qv = qw + lr;

  bf16x8 qf[6];
#pragma unroll
  for (int c = 0; c < 6; c++)
    qf[c] = *(const bf16x8*)(Qb + (size_t)(qw + lr) * 6144 + h * 192 + c * 32 + lh * 8);

  const unsigned short* Kbase = Kb + h * 192;
  const unsigned short* Vbase = Vt + (size_t)h * 128 * 2048;
  size_t kga0, kga1 = 0;
  {
    int c = w * 64 + lane;
    int r = c / 24, p = c - r * 24;
    kga0 = (size_t)r * 6144 + (p ^ (r & 7)) * 8;
  }
  if (w < 4) {
    int c = 512 + w * 64 + lane;
    int r = c / 24, p = c - r * 24;
    kga1 = (size_t)r * 6144 + (p ^ (r & 7)) * 8;
  }
  size_t vga;
  {
    int c = w * 64 + lane;
    int d = c >> 2, p = c & 3;
    vga = (size_t)d * 2048 + (p ^ ((d >> 1) & 3)) * 8;   // pre-swizzled source
  }

#define STAGE(T0, B)                                                           \
  {                                                                            \
    GLOAD16(Kbase + (size_t)(T0) * 6144 + kga0, &Kl[B][w * 512]);              \
    if (w < 4)                                                                 \
      GLOAD16(Kbase + (size_t)(T0) * 6144 + kga1, &Kl[B][4096 + w * 512]);     \
    GLOAD16(Vbase + vga + (T0), &Vl[B][w * 512]);                              \
  }

  f32x4 acc[8];
  const f32x4 z = {0.f, 0.f, 0.f, 0.f};
#pragma unroll
  for (int n = 0; n < 8; n++) acc[n] = z;
  float mrow = -1e30f, lrow = 0.f;
  const float scale = 0.07216878364870322f;  // 192^-0.5
  const int swz = (lr & 7) * 8;
  const int vsw = (lh ^ ((lr >> 1) & 3)) * 8;            // V read swizzle
  const int sA = lr + 32 * (lh & 1), sB = sA + 16;

  const int nt = (q0 + 128) >> 5;
  STAGE(0, 0);
  __syncthreads();
  for (int it = 0; it < nt; ++it) {
    const int t0 = it << 5;
    const int cur = it & 1;
    if (it + 1 < nt) STAGE(t0 + 32, cur ^ 1);
    if (t0 <= qw + 15) {
      f32x4 s0 = z, s1 = z;
      __builtin_amdgcn_s_setprio(1);
#pragma unroll
      for (int c = 0; c < 6; c++) {
        int col = ((c * 4 + lh) * 8) ^ swz;
        bf16x8 k0 = *(const bf16x8*)(&Kl[cur][lr * 192 + col]);
        bf16x8 k1 = *(const bf16x8*)(&Kl[cur][(16 + lr) * 192 + col]);
        s0 = __builtin_amdgcn_mfma_f32_16x16x32_bf16(k0, qf[c], s0, 0, 0, 0);  // S[t][q]
        s1 = __builtin_amdgcn_mfma_f32_16x16x32_bf16(k1, qf[c], s1, 0, 0, 0);
      }
      __builtin_amdgcn_s_setprio(0);
      const int tb = t0 + lh * 4;
      float a0[4], a1[4];
      float mx = -1e30f;
#pragma unroll
      for (int r = 0; r < 4; r++) {
        a0[r] = (tb + r > qv)      ? -1e30f : s0[r] * scale;
        a1[r] = (tb + 16 + r > qv) ? -1e30f : s1[r] * scale;
        mx = fmaxf(mx, fmaxf(a0[r], a1[r]));
      }
      mx = fmaxf(mx, __shfl_xor(mx, 16, 64));
      mx = fmaxf(mx, __shfl_xor(mx, 32, 64));
      float ro = 1.f;
      bool resc = (mx - mrow) > 8.f;        // T13 defer-rescale
      if (resc) { ro = __expf(mrow - mx); mrow = mx; }
      float p0[4], p1[4], ls = 0.f;
#pragma unroll
      for (int r = 0; r < 4; r++) {
        p0[r] = __expf(a0[r] - mrow);
        p1[r] = __expf(a1[r] - mrow);
        ls += p0[r] + p1[r];
      }
      lrow = lrow * ro + ls;
      if (__any(resc)) {
        float rs[4];
#pragma unroll
        for (int r = 0; r < 4; r++) rs[r] = __shfl(ro, lh * 4 + r, 16);
#pragma unroll
        for (int n = 0; n < 8; n++)
#pragma unroll
          for (int r = 0; r < 4; r++) acc[n][r] *= rs[r];
      }
      unsigned pk0 = cvtpk(p0[0], p0[1]), pk1 = cvtpk(p0[2], p0[3]);
      unsigned pk2 = cvtpk(p1[0], p1[1]), pk3 = cvtpk(p1[2], p1[3]);
      unsigned A0 = __shfl(pk0, sA, 64), A1 = __shfl(pk1, sA, 64);
      unsigned B0 = __shfl(pk0, sB, 64), B1 = __shfl(pk1, sB, 64);
      unsigned C0 = __shfl(pk2, sA, 64), C1 = __shfl(pk3, sA, 64);
      unsigned D0 = __shfl(pk2, sB, 64), D1 = __shfl(pk3, sB, 64);
      u32x4 pw;
      pw[0] = (lh < 2) ? A0 : C0;
      pw[1] = (lh < 2) ? A1 : C1;
      pw[2] = (lh < 2) ? B0 : D0;
      pw[3] = (lh < 2) ? B1 : D1;
      bf16x8 pa = __builtin_bit_cast(bf16x8, pw);
      __builtin_amdgcn_s_setprio(1);
#pragma unroll
      for (int n = 0; n < 8; n++) {
        bf16x8 vb = *(const bf16x8*)(&Vl[cur][(n * 16 + lr) * 32 + vsw]);
        acc[n] = __builtin_amdgcn_mfma_f32_16x16x32_bf16(pa, vb, acc[n], 0, 0, 0);
      }
      __builtin_amdgcn_s_setprio(0);
    }
    __syncthreads();
  }
#undef STAGE
  lrow += __shfl_xor(lrow, 16, 64);
  lrow += __shfl_xor(lrow, 32, 64);
  float invL = 1.f / lrow;
  float inv[4];
#pragma unroll
  for (int r = 0; r < 4; r++) inv[r] = __shfl(invL, lh * 4 + r, 16);
#pragma unroll
  for (int n = 0; n < 8; n++)
#pragma unroll
    for (int r = 0; r < 4; r++) {
      int q = qw + lh * 4 + r;
      O[(size_t)q * 4096 + h * 128 + n * 16 + lr] = f2b(acc[n][r] * inv[r]);
    }
}

// ---------------------------------------------------------------------------
extern "C" void kernel_launch(void* const* d_in, const int* in_sizes, int n_in,
                              void* d_out, int out_size, void* d_ws, size_t ws_size,
                              hipStream_t stream) {
  const float* hs      = (const float*)d_in[0];
  const float* q_a_w   = (const float*)d_in[1];
  const float* q_a_ln  = (const float*)d_in[2];
  const float* q_b_w   = (const float*)d_in[3];
  const float* kv_a_w  = (const float*)d_in[4];
  const float* kv_a_ln = (const float*)d_in[5];
  const float* kv_b_w  = (const float*)d_in[6];
  const float* o_w     = (const float*)d_in[7];
  float* out = (float*)d_out;

  char* ws = (char*)d_ws;
  size_t off = 0;
  auto alloc = [&](size_t bytes) {
    void* p = ws + off;
    off += (bytes + 255) & ~(size_t)255;
    return p;
  };
  unsigned short* wcat    = (unsigned short*)alloc(2176UL * 2048 * 2);  // [q_a | kv_a]
  unsigned short* q_b_wT  = (unsigned short*)alloc(6144UL * 1536 * 2);
  unsigned short* kv_b_wT = (unsigned short*)alloc(8192UL * 512 * 2);
  unsigned short* o_wT    = (unsigned short*)alloc(2048UL * 4096 * 2);
  unsigned short* hs_b    = (unsigned short*)alloc(2048UL * 2048 * 2);
  unsigned short* q_a_n   = (unsigned short*)alloc(2048UL * 1536 * 2);
  unsigned short* Qb      = (unsigned short*)alloc(2048UL * 6144 * 2);
  unsigned short* ckv_n   = (unsigned short*)alloc(2048UL * 512 * 2);
  unsigned short* Kb      = (unsigned short*)alloc(2048UL * 6144 * 2);
  unsigned short* Vt      = (unsigned short*)alloc(32UL * 128 * 2048 * 2);
  char* big = (char*)alloc(2048UL * 8192 * 4);
  float*          Craw     = (float*)big;
  unsigned short* attn_out = (unsigned short*)big;
  unsigned short* kvb      = (unsigned short*)(big + 33554432);
  (void)ws_size; (void)in_sizes; (void)n_in; (void)out_size;

  dim3 b256(256), b328(32, 8), b512(512);
  // prep
  castb<<<4096, b256, 0, stream>>>(hs, hs_b, 1048576);
  tcast<<<dim3(64, 48), b328, 0, stream>>>(q_a_w, wcat, 2048, 1536, 1536);
  tcast<<<dim3(64, 20), b328, 0, stream>>>(kv_a_w, wcat + 1536UL * 2048, 2048, 576, 640);
  tcast<<<dim3(48, 192), b328, 0, stream>>>(q_b_w, q_b_wT, 1536, 6144, 6144);
  tcast<<<dim3(16, 256), b328, 0, stream>>>(kv_b_w, kv_b_wT, 512, 8192, 8192);
  tcast<<<dim3(128, 64), b328, 0, stream>>>(o_w, o_wT, 4096, 2048, 2048);
  // fused q_a + kv_a projection
  gemm_bt<0><<<dim3(17, 16), b256, 0, stream>>>(hs_b, wcat, Craw, 2048, 2176, 2048);
  rmsnorm<<<2048, b256, 0, stream>>>(Craw, q_a_ln, q_a_n, 1536, 2176);
  rmsnorm<<<2048, b256, 0, stream>>>(Craw + 1536, kv_a_ln, ckv_n, 512, 2176);
  krot<<<2048, b256, 0, stream>>>(Craw, Kb);
  // q path: 256^2 8-phase GEMM with fused rope epilogue
  gemm256<1><<<dim3(24, 8), b512, 0, stream>>>(q_a_n, q_b_wT, Qb, 2048, 6144, 1536);
  // kv path: 256^2 8-phase GEMM, bf16 out
  gemm256<2><<<dim3(32, 8), b512, 0, stream>>>(ckv_n, kv_b_wT, kvb, 2048, 8192, 512);
  kvpass<<<2048, b256, 0, stream>>>(kvb, Kb);
  vtrans<<<dim3(64, 4, 32), b328, 0, stream>>>(kvb, Vt);
  // attention + output projection
  attn<<<dim3(16, 32), b512, 0, stream>>>(Qb, Kb, Vt, attn_out);
  gemm_bt<0><<<dim3(16, 16), b256, 0, stream>>>(attn_out, o_wT, out, 2048, 2048, 4096);
}

// Round 8
// 374.080 us; speedup vs baseline: 2.0295x; 1.0766x over previous
//
#include <hip/hip_runtime.h>

// ---------------------------------------------------------------------------
// MLA forward (B=1, S=2048, HID=2048, NH=32, DQK=192(128+64 rope), DV=128)
// Round 8: attn triple-buffer + counted vmcnt + raw s_barrier (T4);
// kv_b GEMM epilogue writes Kb/Vt directly (kvpass+vtrans+kvb dropped);
// all casts merged into one prep kernel; krot folded into ckv rmsnorm.
// ---------------------------------------------------------------------------

typedef __bf16 bf16x8 __attribute__((ext_vector_type(8)));
typedef float  f32x4  __attribute__((ext_vector_type(4)));
typedef unsigned u32x4 __attribute__((ext_vector_type(4)));

#define GLOAD16(g, l)                                                          \
  __builtin_amdgcn_global_load_lds(                                            \
      (const __attribute__((address_space(1))) unsigned int*)(g),              \
      (__attribute__((address_space(3))) unsigned int*)(l), 16, 0, 0)

__device__ __forceinline__ unsigned short f2b(float f) {
  unsigned u = __builtin_bit_cast(unsigned, f);
  u += 0x7fffu + ((u >> 16) & 1u);   // round-to-nearest-even
  return (unsigned short)(u >> 16);
}

__device__ __forceinline__ unsigned cvtpk(float lo, float hi) {
  unsigned r;
  asm("v_cvt_pk_bf16_f32 %0, %1, %2" : "=v"(r) : "v"(lo), "v"(hi));
  return r;
}

// ---------------------------------------------------------------------------
// prep: all fp32->bf16 weight transpose-casts + hs cast, one launch.
// block ranges: [0,4096) hs castb; then tcast jobs (see table in launch).
// ---------------------------------------------------------------------------
__device__ __forceinline__ void tc_body(const float* __restrict__ src,
                                        unsigned short* __restrict__ dst,
                                        int R, int C, int bx, int by,
                                        int tx, int ty) {
  __shared__ float t[32][33];
  int r0 = bx * 32, c0 = by * 32;
#pragma unroll
  for (int j = 0; j < 4; j++) {
    int c = c0 + tx;
    t[ty + j * 8][tx] = (c < C) ? src[(size_t)(r0 + ty + j * 8) * C + c] : 0.f;
  }
  __syncthreads();
#pragma unroll
  for (int j = 0; j < 4; j++)
    dst[(size_t)(c0 + ty + j * 8) * R + r0 + tx] = f2b(t[tx][ty + j * 8]);
}

__global__ __launch_bounds__(256) void prep(
    const float* __restrict__ hs, unsigned short* __restrict__ hs_b,
    const float* __restrict__ qaw, const float* __restrict__ kvaw,
    unsigned short* __restrict__ wcat,
    const float* __restrict__ qbw, unsigned short* __restrict__ qbT,
    const float* __restrict__ kvbw, unsigned short* __restrict__ kvbT,
    const float* __restrict__ ow, unsigned short* __restrict__ owT) {
  int b = blockIdx.x;
  int tid = threadIdx.x;
  if (b < 4096) {                                  // hs cast, 4 floats/thread
    int i = b * 256 + tid;
    float4 v = ((const float4*)hs)[i];
    ushort4 o;
    o.x = f2b(v.x); o.y = f2b(v.y); o.z = f2b(v.z); o.w = f2b(v.w);
    ((ushort4*)hs_b)[i] = o;
    return;
  }
  b -= 4096;
  int tx = tid & 31, ty = tid >> 5;
  if (b < 3072)       { tc_body(qaw,  wcat,               2048, 1536, b & 63,  b >> 6, tx, ty); return; }
  b -= 3072;
  if (b < 1280)       { tc_body(kvaw, wcat + 1536UL*2048, 2048, 576,  b & 63,  b >> 6, tx, ty); return; }
  b -= 1280;
  if (b < 9216)       { tc_body(qbw,  qbT,                1536, 6144, b % 48,  b / 48, tx, ty); return; }
  b -= 9216;
  if (b < 4096)       { tc_body(kvbw, kvbT,               512,  8192, b & 15,  b >> 4, tx, ty); return; }
  b -= 4096;
  tc_body(ow, owT, 4096, 2048, b & 127, b >> 7, tx, ty);
}

// ---------------- RMSNorm row kernel: fp32 in -> bf16 out -------------------
__global__ __launch_bounds__(256) void rmsnorm(const float* __restrict__ x,
                                               const float* __restrict__ w,
                                               unsigned short* __restrict__ o,
                                               int C, int stride) {
  int row = blockIdx.x, tid = threadIdx.x;
  const float* xr = x + (size_t)row * stride;
  float ss = 0.f;
  for (int c = tid; c < C; c += 256) { float v = xr[c]; ss += v * v; }
#pragma unroll
  for (int off = 1; off < 64; off <<= 1) ss += __shfl_xor(ss, off, 64);
  __shared__ float red[4];
  if ((tid & 63) == 0) red[tid >> 6] = ss;
  __syncthreads();
  ss = red[0] + red[1] + red[2] + red[3];
  float r = rsqrtf(ss / C + 1e-6f);
  unsigned short* orow = o + (size_t)row * C;
  for (int c = tid; c < C; c += 256) orow[c] = f2b(xr[c] * r * w[c]);
}

// ------- ckv RMSNorm (cols 1536..2048 of Craw) + k_rot rope broadcast -------
__global__ __launch_bounds__(256) void rmsnorm_krot(const float* __restrict__ craw,
                                                    const float* __restrict__ w,
                                                    unsigned short* __restrict__ ckv_n,
                                                    unsigned short* __restrict__ Kb) {
  int t = blockIdx.x, tid = threadIdx.x;
  const float* xr = craw + (size_t)t * 2176 + 1536;
  float ss = 0.f;
  for (int c = tid; c < 512; c += 256) { float v = xr[c]; ss += v * v; }
#pragma unroll
  for (int off = 1; off < 64; off <<= 1) ss += __shfl_xor(ss, off, 64);
  __shared__ float red[4];
  __shared__ unsigned short rot[64];
  if ((tid & 63) == 0) red[tid >> 6] = ss;
  __syncthreads();
  ss = red[0] + red[1] + red[2] + red[3];
  float r = rsqrtf(ss / 512.f + 1e-6f);
  unsigned short* orow = ckv_n + (size_t)t * 512;
  for (int c = tid; c < 512; c += 256) orow[c] = f2b(xr[c] * r * w[c]);
  if (tid < 32) {
    float x1 = craw[(size_t)t * 2176 + 2048 + tid];
    float x2 = craw[(size_t)t * 2176 + 2080 + tid];
    float a = (float)t * exp2f(-(float)tid * 0.4152410118609203f);
    float cs = __cosf(a), sn = __sinf(a);
    rot[tid]      = f2b(x1 * cs - x2 * sn);
    rot[tid + 32] = f2b(x1 * sn + x2 * cs);
  }
  __syncthreads();
  for (int idx = tid; idx < 2048; idx += 256) {
    int h = idx >> 6, d = idx & 63;
    Kb[(size_t)t * 6144 + h * 192 + 128 + d] = rot[d];
  }
}

// ---------------------------------------------------------------------------
// 128^2 GEMM (m97 structure) — fused-a (N=2176) and o-proj (f32 out).
// ---------------------------------------------------------------------------
__global__ __launch_bounds__(256) void gemm_bt(const unsigned short* __restrict__ A,
                                               const unsigned short* __restrict__ Bt,
                                               float* __restrict__ C,
                                               int M, int N, int K) {
  __shared__ unsigned short As[4096];
  __shared__ unsigned short Bs[4096];
  const int tid = threadIdx.x;
  const int w = tid >> 6, lane = tid & 63;
  const int lr = lane & 15, lh = lane >> 4;
  const int m0 = blockIdx.y * 128, n0 = blockIdx.x * 128;
  const int wm = w >> 1, wn = w & 1;
  const int srow = lane >> 2;
  const int schunk = (lane & 3) ^ ((lane >> 3) & 3);
  const int swzr = (lr >> 1) & 3;

  f32x4 acc[4][4];
  const f32x4 z = {0.f, 0.f, 0.f, 0.f};
#pragma unroll
  for (int i = 0; i < 4; i++)
#pragma unroll
    for (int j = 0; j < 4; j++) acc[i][j] = z;

  for (int k0 = 0; k0 < K; k0 += 32) {
#pragma unroll
    for (int c = 0; c < 2; c++) {
      GLOAD16(A + (size_t)(m0 + c * 64 + w * 16 + srow) * K + k0 + schunk * 8,
              As + c * 2048 + w * 512);
      GLOAD16(Bt + (size_t)(n0 + c * 64 + w * 16 + srow) * K + k0 + schunk * 8,
              Bs + c * 2048 + w * 512);
    }
    __syncthreads();
    bf16x8 a[4], b[4];
#pragma unroll
    for (int m = 0; m < 4; m++) {
      int row = wm * 64 + m * 16 + lr;
      a[m] = *(const bf16x8*)(As + row * 32 + ((lh ^ swzr) * 8));
    }
#pragma unroll
    for (int n = 0; n < 4; n++) {
      int row = wn * 64 + n * 16 + lr;
      b[n] = *(const bf16x8*)(Bs + row * 32 + ((lh ^ swzr) * 8));
    }
#pragma unroll
    for (int m = 0; m < 4; m++)
#pragma unroll
      for (int n = 0; n < 4; n++)
        acc[m][n] = __builtin_amdgcn_mfma_f32_16x16x32_bf16(a[m], b[n], acc[m][n], 0, 0, 0);
    __syncthreads();
  }
#pragma unroll
  for (int m = 0; m < 4; m++)
#pragma unroll
    for (int n = 0; n < 4; n++)
#pragma unroll
      for (int r = 0; r < 4; r++) {
        int row = m0 + wm * 64 + m * 16 + lh * 4 + r;
        int col = n0 + wn * 64 + n * 16 + lr;
        C[(size_t)row * N + col] = acc[m][n][r];
      }
}

// ---------------------------------------------------------------------------
// 256^2 8-phase GEMM (T3+T4+T5), as round 7.
// EPI=1: bf16 out + fused q-RoPE (Cout). EPI=3: MLA kv epilogue — K-part
// direct to Kb, V-part via padded-LDS transpose to Vt (Cout unused).
// ---------------------------------------------------------------------------
template <int EPI>
__global__ __launch_bounds__(512) void gemm256(const unsigned short* __restrict__ A,
                                               const unsigned short* __restrict__ Bt,
                                               void* __restrict__ Cout,
                                               unsigned short* __restrict__ Kb,
                                               unsigned short* __restrict__ Vt,
                                               int M, int N, int K) {
  __shared__ unsigned short lds[2][2][16384];   // [buf][op A/B][256*64] = 128 KiB
  const int tid = threadIdx.x;
  const int w = tid >> 6, lane = tid & 63;
  const int lr = lane & 15, lh = lane >> 4;
  const int wr = w >> 2, wc = w & 3;            // 2 x 4 waves
  const int m0 = blockIdx.y * 256, n0 = blockIdx.x * 256;

  int soff[2];
#pragma unroll
  for (int j = 0; j < 2; j++) {
    int c = j * 512 + tid;
    int row = c >> 3, p = c & 7;
    soff[j] = row * K + (p ^ (row & 7)) * 8;
  }
  const unsigned short* Abase = A + (size_t)m0 * K;
  const unsigned short* Bbase = Bt + (size_t)n0 * K;
  const int rswz = lr & 7;

#define STAGEOP(op, Base, kt, buf)                                             \
  {                                                                            \
    _Pragma("unroll") for (int hh = 0; hh < 2; hh++)                           \
    _Pragma("unroll") for (int j = 0; j < 2; j++)                              \
      GLOAD16(Base + (size_t)(hh * 128) * K + soff[j] + (kt) * 64,             \
              &lds[buf][op][(hh * 1024 + j * 512 + w * 64) * 8]);              \
  }
#define READA(mh, buf)                                                         \
  {                                                                            \
    _Pragma("unroll") for (int mi = 0; mi < 4; mi++)                           \
    _Pragma("unroll") for (int ks = 0; ks < 2; ks++)                           \
      af[mi][ks] = *(const bf16x8*)&lds[buf][0][                               \
          (wr * 128 + ((mh) * 4 + mi) * 16 + lr) * 64 +                        \
          (((ks * 4 + lh) ^ rswz) * 8)];                                       \
  }
#define READB(n, buf)                                                          \
  {                                                                            \
    _Pragma("unroll") for (int ks = 0; ks < 2; ks++)                           \
      bfr[n][ks] = *(const bf16x8*)&lds[buf][1][                               \
          (wc * 64 + (n) * 16 + lr) * 64 + (((ks * 4 + lh) ^ rswz) * 8)];      \
  }
#define MFMAQ(mh, nh)                                                          \
  {                                                                            \
    __builtin_amdgcn_s_setprio(1);                                             \
    _Pragma("unroll") for (int mi = 0; mi < 4; mi++)                           \
    _Pragma("unroll") for (int ni = 0; ni < 2; ni++)                           \
    _Pragma("unroll") for (int ks = 0; ks < 2; ks++)                           \
      acc[(mh) * 4 + mi][(nh) * 2 + ni] =                                      \
          __builtin_amdgcn_mfma_f32_16x16x32_bf16(                             \
              af[mi][ks], bfr[(nh) * 2 + ni][ks],                              \
              acc[(mh) * 4 + mi][(nh) * 2 + ni], 0, 0, 0);                     \
    __builtin_amdgcn_s_setprio(0);                                             \
  }

  f32x4 acc[8][4];
  const f32x4 z = {0.f, 0.f, 0.f, 0.f};
#pragma unroll
  for (int i = 0; i < 8; i++)
#pragma unroll
    for (int j = 0; j < 4; j++) acc[i][j] = z;

  STAGEOP(0, Abase, 0, 0);
  STAGEOP(1, Bbase, 0, 0);
  asm volatile("s_waitcnt vmcnt(0)" ::: "memory");
  __builtin_amdgcn_s_barrier();

  const int KT = K >> 6;
  for (int kt = 0; kt < KT; ++kt) {
    const int buf = kt & 1;
    const bool more = (kt + 1 < KT);
    bf16x8 af[4][2], bfr[4][2];
    READA(0, buf);
    READB(0, buf); READB(1, buf);
    if (more) STAGEOP(0, Abase, kt + 1, buf ^ 1);
    __builtin_amdgcn_s_barrier();
    MFMAQ(0, 0);
    __builtin_amdgcn_s_barrier();
    READB(2, buf); READB(3, buf);
    if (more) STAGEOP(1, Bbase, kt + 1, buf ^ 1);
    __builtin_amdgcn_s_barrier();
    MFMAQ(0, 1);
    __builtin_amdgcn_s_barrier();
    READA(1, buf);
    __builtin_amdgcn_s_barrier();
    MFMAQ(1, 1);
    __builtin_amdgcn_s_barrier();
    MFMAQ(1, 0);
    if (more) asm volatile("s_waitcnt vmcnt(0)" ::: "memory");
    __builtin_amdgcn_s_barrier();
  }
#undef STAGEOP
#undef READA
#undef READB
#undef MFMAQ

  if (EPI == 1) {                                  // bf16 out + fused q-RoPE
    unsigned short* C = (unsigned short*)Cout;
#pragma unroll
    for (int m = 0; m < 8; m++)
#pragma unroll
      for (int n = 0; n < 4; n++) {
        int colb = n0 + wc * 64 + n * 16;
        int sb = colb % 192;
        bool isrope = sb >= 128;
        bool first  = sb < 160;
        int col = colb + lr;
#pragma unroll
        for (int r = 0; r < 4; r++) {
          int row = m0 + wr * 128 + m * 16 + lh * 4 + r;
          float v = acc[m][n][r], o;
          if (!isrope) {
            o = v;
          } else {
            int ii = (col - 128) & 31;
            float ang = (float)row * exp2f(-(float)ii * 0.4152410118609203f);
            float cs = __cosf(ang), sn = __sinf(ang);
            float pa_ = acc[m][(n + 2) & 3][r];
            float pb_ = acc[m][(n + 6) & 3][r];
            float partner = first ? pa_ : pb_;
            o = first ? (v * cs - partner * sn) : (partner * sn + v * cs);
          }
          C[(size_t)row * N + col] = f2b(o);
        }
      }
  } else {                                         // EPI == 3: MLA kv epilogue
    const int h = blockIdx.x;                      // one head per n-block
    unsigned short* Vlds = (unsigned short*)lds;   // [128][264] padded
    if (wc < 2) {                                  // k_pass -> Kb direct
#pragma unroll
      for (int m = 0; m < 8; m++)
#pragma unroll
        for (int n = 0; n < 4; n++) {
          int dd = wc * 64 + n * 16 + lr;
          int rowb = m0 + wr * 128 + m * 16 + lh * 4;
#pragma unroll
          for (int r = 0; r < 4; r++)
            Kb[(size_t)(rowb + r) * 6144 + h * 192 + dd] = f2b(acc[m][n][r]);
        }
    } else {                                       // V -> LDS (padded rows)
#pragma unroll
      for (int m = 0; m < 8; m++)
#pragma unroll
        for (int n = 0; n < 4; n++) {
          int dd = (wc - 2) * 64 + n * 16 + lr;
          int tl = wr * 128 + m * 16 + lh * 4;
          ushort4 pk;
          pk.x = f2b(acc[m][n][0]); pk.y = f2b(acc[m][n][1]);
          pk.z = f2b(acc[m][n][2]); pk.w = f2b(acc[m][n][3]);
          *(ushort4*)(Vlds + dd * 264 + tl) = pk;
        }
    }
    __syncthreads();
    {                                              // coalesced Vt writeout
      int r = tid >> 2, seg = tid & 3;
      const unsigned short* srcp = Vlds + r * 264 + seg * 64;
      unsigned short* dstp = Vt + (size_t)(h * 128 + r) * 2048 + m0 + seg * 64;
#pragma unroll
      for (int j = 0; j < 8; j++)
        *(int4*)(dstp + j * 8) = *(const int4*)(srcp + j * 8);
    }
  }
}

// ---------------------------------------------------------------------------
// Causal MLA attention, round-8: triple-buffered global_load_lds staging with
// per-wave counted vmcnt + raw s_barrier (stage latency hides under 2 compute
// phases; barrier never drains the prefetch). Core otherwise as round 7.
// Grid (S/128, NH) reversed; 8 waves (512 thr), 128 q/block.
// ---------------------------------------------------------------------------
__global__ __launch_bounds__(512) void attn(const unsigned short* __restrict__ Qb,
                                            const unsigned short* __restrict__ Kb,
                                            const unsigned short* __restrict__ Vt,
                                            unsigned short* __restrict__ O) {
  __shared__ unsigned short Kl[3][6144];    // [32 t][192 d], chunk-swizzled
  __shared__ unsigned short Vl[3][4096];    // [128 d][32 t], chunk-swizzled
  const int tid = threadIdx.x;
  const int w = tid >> 6, lane = tid & 63;
  const int lr = lane & 15, lh = lane >> 4;
  const int h = blockIdx.y;
  const int q0 = (gridDim.x - 1 - blockIdx.x) * 128;  // heavy blocks first
  const int qw = q0 + w * 16;
  const int qv = qw + lr;

  bf16x8 qf[6];
#pragma unroll
  for (int c = 0; c < 6; c++)
    qf[c] = *(const bf16x8*)(Qb + (size_t)(qw + lr) * 6144 + h * 192 + c * 32 + lh * 8);

  const unsigned short* Kbase = Kb + h * 192;
  const unsigned short* Vbase = Vt + (size_t)h * 128 * 2048;
  size_t kga0, kga1 = 0;
  {
    int c = w * 64 + lane;
    int r = c / 24, p = c - r * 24;
    kga0 = (size_t)r * 6144 + (p ^ (r & 7)) * 8;
  }
  if (w < 4) {
    int c = 512 + w * 64 + lane;
    int r = c / 24, p = c - r * 24;
    kga1 = (size_t)r * 6144 + (p ^ (r & 7)) * 8;
  }
  size_t vga;
  {
    int c = w * 64 + lane;
    int d = c >> 2, p = c & 3;
    vga = (size_t)d * 2048 + (p ^ ((d >> 1) & 3)) * 8;   // pre-swizzled source
  }

#define STAGE(T0, B)                                                           \
  {                                                                            \
    GLOAD16(Kbase + (size_t)(T0) * 6144 + kga0, &Kl[B][w * 512]);              \
    if (w < 4)                                                                 \
      GLOAD16(Kbase + (size_t)(T0) * 6144 + kga1, &Kl[B][4096 + w * 512]);     \
    GLOAD16(Vbase + vga + (T0), &Vl[B][w * 512]);                              \
  }

  f32x4 acc[8];
  const f32x4 z = {0.f, 0.f, 0.f, 0.f};
#pragma unroll
  for (int n = 0; n < 8; n++) acc[n] = z;
  float mrow = -1e30f, lrow = 0.f;
  const float scale = 0.07216878364870322f;  // 192^-0.5
  const int swz = (lr & 7) * 8;
  const int vsw = (lh ^ ((lr >> 1) & 3)) * 8;
  const int sA = lr + 32 * (lh & 1), sB = sA + 16;

  const int nt = (q0 + 128) >> 5;            // >= 4 always
  STAGE(0, 0);
  STAGE(32, 1);
  int cur = 0;
  for (int it = 0; it < nt; ++it) {
    const int t0 = it << 5;
    // wait for own stage(it); keep stage(it+1) in flight (counted, per-wave)
    if (it + 1 < nt) {
      if (w < 4) asm volatile("s_waitcnt vmcnt(3)" ::: "memory");
      else       asm volatile("s_waitcnt vmcnt(2)" ::: "memory");
    } else {
      asm volatile("s_waitcnt vmcnt(0)" ::: "memory");
    }
    __builtin_amdgcn_s_barrier();            // all waves' stage(it) now visible
    if (it + 2 < nt) {
      int nb = cur + 2; if (nb >= 3) nb -= 3;
      STAGE(t0 + 64, nb);                    // overwrites buf last read at it-1
    }
    if (t0 <= qw + 15) {
      f32x4 s0 = z, s1 = z;
      __builtin_amdgcn_s_setprio(1);
#pragma unroll
      for (int c = 0; c < 6; c++) {
        int col = ((c * 4 + lh) * 8) ^ swz;
        bf16x8 k0 = *(const bf16x8*)(&Kl[cur][lr * 192 + col]);
        bf16x8 k1 = *(const bf16x8*)(&Kl[cur][(16 + lr) * 192 + col]);
        s0 = __builtin_amdgcn_mfma_f32_16x16x32_bf16(k0, qf[c], s0, 0, 0, 0);  // S[t][q]
        s1 = __builtin_amdgcn_mfma_f32_16x16x32_bf16(k1, qf[c], s1, 0, 0, 0);
      }
      __builtin_amdgcn_s_setprio(0);
      const int tb = t0 + lh * 4;
      float a0[4], a1[4];
      float mx = -1e30f;
#pragma unroll
      for (int r = 0; r < 4; r++) {
        a0[r] = (tb + r > qv)      ? -1e30f : s0[r] * scale;
        a1[r] = (tb + 16 + r > qv) ? -1e30f : s1[r] * scale;
        mx = fmaxf(mx, fmaxf(a0[r], a1[r]));
      }
      mx = fmaxf(mx, __shfl_xor(mx, 16, 64));
      mx = fmaxf(mx, __shfl_xor(mx, 32, 64));
      float ro = 1.f;
      bool resc = (mx - mrow) > 8.f;        // T13 defer-rescale
      if (resc) { ro = __expf(mrow - mx); mrow = mx; }
      float p0[4], p1[4], ls = 0.f;
#pragma unroll
      for (int r = 0; r < 4; r++) {
        p0[r] = __expf(a0[r] - mrow);
        p1[r] = __expf(a1[r] - mrow);
        ls += p0[r] + p1[r];
      }
      lrow = lrow * ro + ls;
      if (__any(resc)) {
        float rs[4];
#pragma unroll
        for (int r = 0; r < 4; r++) rs[r] = __shfl(ro, lh * 4 + r, 16);
#pragma unroll
        for (int n = 0; n < 8; n++)
#pragma unroll
          for (int r = 0; r < 4; r++) acc[n][r] *= rs[r];
      }
      unsigned pk0 = cvtpk(p0[0], p0[1]), pk1 = cvtpk(p0[2], p0[3]);
      unsigned pk2 = cvtpk(p1[0], p1[1]), pk3 = cvtpk(p1[2], p1[3]);
      unsigned A0 = __shfl(pk0, sA, 64), A1 = __shfl(pk1, sA, 64);
      unsigned B0 = __shfl(pk0, sB, 64), B1 = __shfl(pk1, sB, 64);
      unsigned C0 = __shfl(pk2, sA, 64), C1 = __shfl(pk3, sA, 64);
      unsigned D0 = __shfl(pk2, sB, 64), D1 = __shfl(pk3, sB, 64);
      u32x4 pw;
      pw[0] = (lh < 2) ? A0 : C0;
      pw[1] = (lh < 2) ? A1 : C1;
      pw[2] = (lh < 2) ? B0 : D0;
      pw[3] = (lh < 2) ? B1 : D1;
      bf16x8 pa = __builtin_bit_cast(bf16x8, pw);
      __builtin_amdgcn_s_setprio(1);
#pragma unroll
      for (int n = 0; n < 8; n++) {
        bf16x8 vb = *(const bf16x8*)(&Vl[cur][(n * 16 + lr) * 32 + vsw]);
        acc[n] = __builtin_amdgcn_mfma_f32_16x16x32_bf16(pa, vb, acc[n], 0, 0, 0);
      }
      __builtin_amdgcn_s_setprio(0);
    }
    cur = (cur == 2) ? 0 : cur + 1;
  }
#undef STAGE
  lrow += __shfl_xor(lrow, 16, 64);
  lrow += __shfl_xor(lrow, 32, 64);
  float invL = 1.f / lrow;
  float inv[4];
#pragma unroll
  for (int r = 0; r < 4; r++) inv[r] = __shfl(invL, lh * 4 + r, 16);
#pragma unroll
  for (int n = 0; n < 8; n++)
#pragma unroll
    for (int r = 0; r < 4; r++) {
      int q = qw + lh * 4 + r;
      O[(size_t)q * 4096 + h * 128 + n * 16 + lr] = f2b(acc[n][r] * inv[r]);
    }
}

// ---------------------------------------------------------------------------
extern "C" void kernel_launch(void* const* d_in, const int* in_sizes, int n_in,
                              void* d_out, int out_size, void* d_ws, size_t ws_size,
                              hipStream_t stream) {
  const float* hs      = (const float*)d_in[0];
  const float* q_a_w   = (const float*)d_in[1];
  const float* q_a_ln  = (const float*)d_in[2];
  const float* q_b_w   = (const float*)d_in[3];
  const float* kv_a_w  = (const float*)d_in[4];
  const float* kv_a_ln = (const float*)d_in[5];
  const float* kv_b_w  = (const float*)d_in[6];
  const float* o_w     = (const float*)d_in[7];
  float* out = (float*)d_out;

  char* ws = (char*)d_ws;
  size_t off = 0;
  auto alloc = [&](size_t bytes) {
    void* p = ws + off;
    off += (bytes + 255) & ~(size_t)255;
    return p;
  };
  unsigned short* wcat    = (unsigned short*)alloc(2176UL * 2048 * 2);  // [q_a | kv_a]
  unsigned short* q_b_wT  = (unsigned short*)alloc(6144UL * 1536 * 2);
  unsigned short* kv_b_wT = (unsigned short*)alloc(8192UL * 512 * 2);
  unsigned short* o_wT    = (unsigned short*)alloc(2048UL * 4096 * 2);
  unsigned short* hs_b    = (unsigned short*)alloc(2048UL * 2048 * 2);
  unsigned short* q_a_n   = (unsigned short*)alloc(2048UL * 1536 * 2);
  unsigned short* Qb      = (unsigned short*)alloc(2048UL * 6144 * 2);
  unsigned short* ckv_n   = (unsigned short*)alloc(2048UL * 512 * 2);
  unsigned short* Kb      = (unsigned short*)alloc(2048UL * 6144 * 2);
  unsigned short* Vt      = (unsigned short*)alloc(32UL * 128 * 2048 * 2);
  // transient: Craw f32 [2048][2176] -> attn_out bf16 [2048][4096]
  char* big = (char*)alloc(2048UL * 2176 * 4);
  float*          Craw     = (float*)big;
  unsigned short* attn_out = (unsigned short*)big;
  (void)ws_size; (void)in_sizes; (void)n_in; (void)out_size;

  dim3 b256(256), b512(512);
  // all casts in one launch
  prep<<<29952, b256, 0, stream>>>(hs, hs_b, q_a_w, kv_a_w, wcat,
                                   q_b_w, q_b_wT, kv_b_w, kv_b_wT, o_w, o_wT);
  // fused q_a + kv_a projection
  gemm_bt<<<dim3(17, 16), b256, 0, stream>>>(hs_b, wcat, Craw, 2048, 2176, 2048);
  rmsnorm<<<2048, b256, 0, stream>>>(Craw, q_a_ln, q_a_n, 1536, 2176);
  rmsnorm_krot<<<2048, b256, 0, stream>>>(Craw, kv_a_ln, ckv_n, Kb);
  // q path: 256^2 8-phase GEMM with fused rope epilogue
  gemm256<1><<<dim3(24, 8), b512, 0, stream>>>(q_a_n, q_b_wT, Qb, nullptr, nullptr,
                                               2048, 6144, 1536);
  // kv path: 256^2 8-phase GEMM writing Kb (k_pass) and Vt (transposed V)
  gemm256<3><<<dim3(32, 8), b512, 0, stream>>>(ckv_n, kv_b_wT, nullptr, Kb, Vt,
                                               2048, 8192, 512);
  // attention + output projection
  attn<<<dim3(16, 32), b512, 0, stream>>>(Qb, Kb, Vt, attn_out);
  gemm_bt<<<dim3(16, 16), b256, 0, stream>>>(attn_out, o_wT, out, 2048, 2048, 4096);
}

// Round 9
// 368.477 us; speedup vs baseline: 2.0604x; 1.0152x over previous
//
#include <hip/hip_runtime.h>

// ---------------------------------------------------------------------------
// MLA forward (B=1, S=2048, HID=2048, NH=32, DQK=192(128+64 rope), DV=128)
// Round 9: attn KVBLK=64 (double-buffer, 80KiB LDS, same 2 blocks/CU),
// Q pre-scaled by scale*log2e in rope epilogue (exp2 softmax, no muls),
// interior-tile fast path (mask only on diagonal tiles); gemm_bt gets
// XCD-chunked block swizzle (T1).
// ---------------------------------------------------------------------------

typedef __bf16 bf16x8 __attribute__((ext_vector_type(8)));
typedef float  f32x4  __attribute__((ext_vector_type(4)));
typedef unsigned u32x4 __attribute__((ext_vector_type(4)));

#define GLOAD16(g, l)                                                          \
  __builtin_amdgcn_global_load_lds(                                            \
      (const __attribute__((address_space(1))) unsigned int*)(g),              \
      (__attribute__((address_space(3))) unsigned int*)(l), 16, 0, 0)

__device__ __forceinline__ unsigned short f2b(float f) {
  unsigned u = __builtin_bit_cast(unsigned, f);
  u += 0x7fffu + ((u >> 16) & 1u);   // round-to-nearest-even
  return (unsigned short)(u >> 16);
}

__device__ __forceinline__ unsigned cvtpk(float lo, float hi) {
  unsigned r;
  asm("v_cvt_pk_bf16_f32 %0, %1, %2" : "=v"(r) : "v"(lo), "v"(hi));
  return r;
}

// ---------------------------------------------------------------------------
// prep: all fp32->bf16 weight transpose-casts + hs cast, one launch.
// ---------------------------------------------------------------------------
__device__ __forceinline__ void tc_body(const float* __restrict__ src,
                                        unsigned short* __restrict__ dst,
                                        int R, int C, int bx, int by,
                                        int tx, int ty) {
  __shared__ float t[32][33];
  int r0 = bx * 32, c0 = by * 32;
#pragma unroll
  for (int j = 0; j < 4; j++) {
    int c = c0 + tx;
    t[ty + j * 8][tx] = (c < C) ? src[(size_t)(r0 + ty + j * 8) * C + c] : 0.f;
  }
  __syncthreads();
#pragma unroll
  for (int j = 0; j < 4; j++)
    dst[(size_t)(c0 + ty + j * 8) * R + r0 + tx] = f2b(t[tx][ty + j * 8]);
}

__global__ __launch_bounds__(256) void prep(
    const float* __restrict__ hs, unsigned short* __restrict__ hs_b,
    const float* __restrict__ qaw, const float* __restrict__ kvaw,
    unsigned short* __restrict__ wcat,
    const float* __restrict__ qbw, unsigned short* __restrict__ qbT,
    const float* __restrict__ kvbw, unsigned short* __restrict__ kvbT,
    const float* __restrict__ ow, unsigned short* __restrict__ owT) {
  int b = blockIdx.x;
  int tid = threadIdx.x;
  if (b < 4096) {
    int i = b * 256 + tid;
    float4 v = ((const float4*)hs)[i];
    ushort4 o;
    o.x = f2b(v.x); o.y = f2b(v.y); o.z = f2b(v.z); o.w = f2b(v.w);
    ((ushort4*)hs_b)[i] = o;
    return;
  }
  b -= 4096;
  int tx = tid & 31, ty = tid >> 5;
  if (b < 3072)       { tc_body(qaw,  wcat,               2048, 1536, b & 63,  b >> 6, tx, ty); return; }
  b -= 3072;
  if (b < 1280)       { tc_body(kvaw, wcat + 1536UL*2048, 2048, 576,  b & 63,  b >> 6, tx, ty); return; }
  b -= 1280;
  if (b < 9216)       { tc_body(qbw,  qbT,                1536, 6144, b % 48,  b / 48, tx, ty); return; }
  b -= 9216;
  if (b < 4096)       { tc_body(kvbw, kvbT,               512,  8192, b & 15,  b >> 4, tx, ty); return; }
  b -= 4096;
  tc_body(ow, owT, 4096, 2048, b & 127, b >> 7, tx, ty);
}

// ---------------- RMSNorm row kernel: fp32 in -> bf16 out -------------------
__global__ __launch_bounds__(256) void rmsnorm(const float* __restrict__ x,
                                               const float* __restrict__ w,
                                               unsigned short* __restrict__ o,
                                               int C, int stride) {
  int row = blockIdx.x, tid = threadIdx.x;
  const float* xr = x + (size_t)row * stride;
  float ss = 0.f;
  for (int c = tid; c < C; c += 256) { float v = xr[c]; ss += v * v; }
#pragma unroll
  for (int off = 1; off < 64; off <<= 1) ss += __shfl_xor(ss, off, 64);
  __shared__ float red[4];
  if ((tid & 63) == 0) red[tid >> 6] = ss;
  __syncthreads();
  ss = red[0] + red[1] + red[2] + red[3];
  float r = rsqrtf(ss / C + 1e-6f);
  unsigned short* orow = o + (size_t)row * C;
  for (int c = tid; c < C; c += 256) orow[c] = f2b(xr[c] * r * w[c]);
}

// ------- ckv RMSNorm (cols 1536..2048 of Craw) + k_rot rope broadcast -------
__global__ __launch_bounds__(256) void rmsnorm_krot(const float* __restrict__ craw,
                                                    const float* __restrict__ w,
                                                    unsigned short* __restrict__ ckv_n,
                                                    unsigned short* __restrict__ Kb) {
  int t = blockIdx.x, tid = threadIdx.x;
  const float* xr = craw + (size_t)t * 2176 + 1536;
  float ss = 0.f;
  for (int c = tid; c < 512; c += 256) { float v = xr[c]; ss += v * v; }
#pragma unroll
  for (int off = 1; off < 64; off <<= 1) ss += __shfl_xor(ss, off, 64);
  __shared__ float red[4];
  __shared__ unsigned short rot[64];
  if ((tid & 63) == 0) red[tid >> 6] = ss;
  __syncthreads();
  ss = red[0] + red[1] + red[2] + red[3];
  float r = rsqrtf(ss / 512.f + 1e-6f);
  unsigned short* orow = ckv_n + (size_t)t * 512;
  for (int c = tid; c < 512; c += 256) orow[c] = f2b(xr[c] * r * w[c]);
  if (tid < 32) {
    float x1 = craw[(size_t)t * 2176 + 2048 + tid];
    float x2 = craw[(size_t)t * 2176 + 2080 + tid];
    float a = (float)t * exp2f(-(float)tid * 0.4152410118609203f);
    float cs = __cosf(a), sn = __sinf(a);
    rot[tid]      = f2b(x1 * cs - x2 * sn);
    rot[tid + 32] = f2b(x1 * sn + x2 * cs);
  }
  __syncthreads();
  for (int idx = tid; idx < 2048; idx += 256) {
    int h = idx >> 6, d = idx & 63;
    Kb[(size_t)t * 6144 + h * 192 + 128 + d] = rot[d];
  }
}

// ---------------------------------------------------------------------------
// 128^2 GEMM (m97 structure) with XCD-chunked block swizzle (T1).
// 1D grid nwg = GX*GY (multiple of 8); f32 out.
// ---------------------------------------------------------------------------
__global__ __launch_bounds__(256) void gemm_bt(const unsigned short* __restrict__ A,
                                               const unsigned short* __restrict__ Bt,
                                               float* __restrict__ C,
                                               int M, int N, int K, int GX) {
  __shared__ unsigned short As[4096];
  __shared__ unsigned short Bs[4096];
  const int tid = threadIdx.x;
  const int w = tid >> 6, lane = tid & 63;
  const int lr = lane & 15, lh = lane >> 4;
  const int lin = blockIdx.x, cpx = gridDim.x >> 3;
  const int sid = (lin & 7) * cpx + (lin >> 3);        // chunked XCD transform
  const int m0 = (sid / GX) * 128, n0 = (sid % GX) * 128;
  const int wm = w >> 1, wn = w & 1;
  const int srow = lane >> 2;
  const int schunk = (lane & 3) ^ ((lane >> 3) & 3);
  const int swzr = (lr >> 1) & 3;

  f32x4 acc[4][4];
  const f32x4 z = {0.f, 0.f, 0.f, 0.f};
#pragma unroll
  for (int i = 0; i < 4; i++)
#pragma unroll
    for (int j = 0; j < 4; j++) acc[i][j] = z;

  for (int k0 = 0; k0 < K; k0 += 32) {
#pragma unroll
    for (int c = 0; c < 2; c++) {
      GLOAD16(A + (size_t)(m0 + c * 64 + w * 16 + srow) * K + k0 + schunk * 8,
              As + c * 2048 + w * 512);
      GLOAD16(Bt + (size_t)(n0 + c * 64 + w * 16 + srow) * K + k0 + schunk * 8,
              Bs + c * 2048 + w * 512);
    }
    __syncthreads();
    bf16x8 a[4], b[4];
#pragma unroll
    for (int m = 0; m < 4; m++) {
      int row = wm * 64 + m * 16 + lr;
      a[m] = *(const bf16x8*)(As + row * 32 + ((lh ^ swzr) * 8));
    }
#pragma unroll
    for (int n = 0; n < 4; n++) {
      int row = wn * 64 + n * 16 + lr;
      b[n] = *(const bf16x8*)(Bs + row * 32 + ((lh ^ swzr) * 8));
    }
#pragma unroll
    for (int m = 0; m < 4; m++)
#pragma unroll
      for (int n = 0; n < 4; n++)
        acc[m][n] = __builtin_amdgcn_mfma_f32_16x16x32_bf16(a[m], b[n], acc[m][n], 0, 0, 0);
    __syncthreads();
  }
#pragma unroll
  for (int m = 0; m < 4; m++)
#pragma unroll
    for (int n = 0; n < 4; n++)
#pragma unroll
      for (int r = 0; r < 4; r++) {
        int row = m0 + wm * 64 + m * 16 + lh * 4 + r;
        int col = n0 + wn * 64 + n * 16 + lr;
        C[(size_t)row * N + col] = acc[m][n][r];
      }
}

// ---------------------------------------------------------------------------
// 256^2 8-phase GEMM (T3+T4+T5), as round 8.
// EPI=1: bf16 out + fused q-RoPE, PRE-SCALED by scale*log2e (softmax uses
// exp2 directly). EPI=3: MLA kv epilogue (K->Kb, V->Vt via LDS transpose).
// ---------------------------------------------------------------------------
template <int EPI>
__global__ __launch_bounds__(512) void gemm256(const unsigned short* __restrict__ A,
                                               const unsigned short* __restrict__ Bt,
                                               void* __restrict__ Cout,
                                               unsigned short* __restrict__ Kb,
                                               unsigned short* __restrict__ Vt,
                                               int M, int N, int K) {
  __shared__ unsigned short lds[2][2][16384];   // 128 KiB
  const int tid = threadIdx.x;
  const int w = tid >> 6, lane = tid & 63;
  const int lr = lane & 15, lh = lane >> 4;
  const int wr = w >> 2, wc = w & 3;
  const int m0 = blockIdx.y * 256, n0 = blockIdx.x * 256;

  int soff[2];
#pragma unroll
  for (int j = 0; j < 2; j++) {
    int c = j * 512 + tid;
    int row = c >> 3, p = c & 7;
    soff[j] = row * K + (p ^ (row & 7)) * 8;
  }
  const unsigned short* Abase = A + (size_t)m0 * K;
  const unsigned short* Bbase = Bt + (size_t)n0 * K;
  const int rswz = lr & 7;

#define STAGEOP(op, Base, kt, buf)                                             \
  {                                                                            \
    _Pragma("unroll") for (int hh = 0; hh < 2; hh++)                           \
    _Pragma("unroll") for (int j = 0; j < 2; j++)                              \
      GLOAD16(Base + (size_t)(hh * 128) * K + soff[j] + (kt) * 64,             \
              &lds[buf][op][(hh * 1024 + j * 512 + w * 64) * 8]);              \
  }
#define READA(mh, buf)                                                         \
  {                                                                            \
    _Pragma("unroll") for (int mi = 0; mi < 4; mi++)                           \
    _Pragma("unroll") for (int ks = 0; ks < 2; ks++)                           \
      af[mi][ks] = *(const bf16x8*)&lds[buf][0][                               \
          (wr * 128 + ((mh) * 4 + mi) * 16 + lr) * 64 +                        \
          (((ks * 4 + lh) ^ rswz) * 8)];                                       \
  }
#define READB(n, buf)                                                          \
  {                                                                            \
    _Pragma("unroll") for (int ks = 0; ks < 2; ks++)                           \
      bfr[n][ks] = *(const bf16x8*)&lds[buf][1][                               \
          (wc * 64 + (n) * 16 + lr) * 64 + (((ks * 4 + lh) ^ rswz) * 8)];      \
  }
#define MFMAQ(mh, nh)                                                          \
  {                                                                            \
    __builtin_amdgcn_s_setprio(1);                                             \
    _Pragma("unroll") for (int mi = 0; mi < 4; mi++)                           \
    _Pragma("unroll") for (int ni = 0; ni < 2; ni++)                           \
    _Pragma("unroll") for (int ks = 0; ks < 2; ks++)                           \
      acc[(mh) * 4 + mi][(nh) * 2 + ni] =                                      \
          __builtin_amdgcn_mfma_f32_16x16x32_bf16(                             \
              af[mi][ks], bfr[(nh) * 2 + ni][ks],                              \
              acc[(mh) * 4 + mi][(nh) * 2 + ni], 0, 0, 0);                     \
    __builtin_amdgcn_s_setprio(0);                                             \
  }

  f32x4 acc[8][4];
  const f32x4 z = {0.f, 0.f, 0.f, 0.f};
#pragma unroll
  for (int i = 0; i < 8; i++)
#pragma unroll
    for (int j = 0; j < 4; j++) acc[i][j] = z;

  STAGEOP(0, Abase, 0, 0);
  STAGEOP(1, Bbase, 0, 0);
  asm volatile("s_waitcnt vmcnt(0)" ::: "memory");
  __builtin_amdgcn_s_barrier();

  const int KT = K >> 6;
  for (int kt = 0; kt < KT; ++kt) {
    const int buf = kt & 1;
    const bool more = (kt + 1 < KT);
    bf16x8 af[4][2], bfr[4][2];
    READA(0, buf);
    READB(0, buf); READB(1, buf);
    if (more) STAGEOP(0, Abase, kt + 1, buf ^ 1);
    __builtin_amdgcn_s_barrier();
    MFMAQ(0, 0);
    __builtin_amdgcn_s_barrier();
    READB(2, buf); READB(3, buf);
    if (more) STAGEOP(1, Bbase, kt + 1, buf ^ 1);
    __builtin_amdgcn_s_barrier();
    MFMAQ(0, 1);
    __builtin_amdgcn_s_barrier();
    READA(1, buf);
    __builtin_amdgcn_s_barrier();
    MFMAQ(1, 1);
    __builtin_amdgcn_s_barrier();
    MFMAQ(1, 0);
    if (more) asm volatile("s_waitcnt vmcnt(0)" ::: "memory");
    __builtin_amdgcn_s_barrier();
  }
#undef STAGEOP
#undef READA
#undef READB
#undef MFMAQ

  if (EPI == 1) {                                  // bf16 + fused q-RoPE, pre-scaled
    const float kSc = 0.104126984f;                // 192^-0.5 * log2(e)
    unsigned short* C = (unsigned short*)Cout;
#pragma unroll
    for (int m = 0; m < 8; m++)
#pragma unroll
      for (int n = 0; n < 4; n++) {
        int colb = n0 + wc * 64 + n * 16;
        int sb = colb % 192;
        bool isrope = sb >= 128;
        bool first  = sb < 160;
        int col = colb + lr;
#pragma unroll
        for (int r = 0; r < 4; r++) {
          int row = m0 + wr * 128 + m * 16 + lh * 4 + r;
          float v = acc[m][n][r], o;
          if (!isrope) {
            o = v;
          } else {
            int ii = (col - 128) & 31;
            float ang = (float)row * exp2f(-(float)ii * 0.4152410118609203f);
            float cs = __cosf(ang), sn = __sinf(ang);
            float pa_ = acc[m][(n + 2) & 3][r];
            float pb_ = acc[m][(n + 6) & 3][r];
            float partner = first ? pa_ : pb_;
            o = first ? (v * cs - partner * sn) : (partner * sn + v * cs);
          }
          C[(size_t)row * N + col] = f2b(o * kSc);
        }
      }
  } else {                                         // EPI == 3: MLA kv epilogue
    const int h = blockIdx.x;
    unsigned short* Vlds = (unsigned short*)lds;   // [128][264] padded
    if (wc < 2) {
#pragma unroll
      for (int m = 0; m < 8; m++)
#pragma unroll
        for (int n = 0; n < 4; n++) {
          int dd = wc * 64 + n * 16 + lr;
          int rowb = m0 + wr * 128 + m * 16 + lh * 4;
#pragma unroll
          for (int r = 0; r < 4; r++)
            Kb[(size_t)(rowb + r) * 6144 + h * 192 + dd] = f2b(acc[m][n][r]);
        }
    } else {
#pragma unroll
      for (int m = 0; m < 8; m++)
#pragma unroll
        for (int n = 0; n < 4; n++) {
          int dd = (wc - 2) * 64 + n * 16 + lr;
          int tl = wr * 128 + m * 16 + lh * 4;
          ushort4 pk;
          pk.x = f2b(acc[m][n][0]); pk.y = f2b(acc[m][n][1]);
          pk.z = f2b(acc[m][n][2]); pk.w = f2b(acc[m][n][3]);
          *(ushort4*)(Vlds + dd * 264 + tl) = pk;
        }
    }
    __syncthreads();
    {
      int r = tid >> 2, seg = tid & 3;
      const unsigned short* srcp = Vlds + r * 264 + seg * 64;
      unsigned short* dstp = Vt + (size_t)(h * 128 + r) * 2048 + m0 + seg * 64;
#pragma unroll
      for (int j = 0; j < 8; j++)
        *(int4*)(dstp + j * 8) = *(const int4*)(srcp + j * 8);
    }
  }
}

// ---------------------------------------------------------------------------
// Causal MLA attention, round-9: KVBLK=64, double-buffered (80 KiB LDS,
// 2 blocks/CU). Q pre-scaled (exp2 softmax). Interior tiles skip masking.
// Grid (S/128, NH) reversed; 8 waves (512 thr), 128 q/block.
// ---------------------------------------------------------------------------
__global__ __launch_bounds__(512) void attn(const unsigned short* __restrict__ Qb,
                                            const unsigned short* __restrict__ Kb,
                                            const unsigned short* __restrict__ Vt,
                                            unsigned short* __restrict__ O) {
  __shared__ unsigned short Kl[2][12288];   // [64 t][192 d], chunk-swizzled
  __shared__ unsigned short Vl[2][8192];    // [128 d][64 t], chunk-swizzled
  const int tid = threadIdx.x;
  const int w = tid >> 6, lane = tid & 63;
  const int lr = lane & 15, lh = lane >> 4;
  const int h = blockIdx.y;
  const int q0 = (gridDim.x - 1 - blockIdx.x) * 128;  // heavy blocks first
  const int qw = q0 + w * 16;
  const int qv = qw + lr;

  bf16x8 qf[6];
#pragma unroll
  for (int c = 0; c < 6; c++)
    qf[c] = *(const bf16x8*)(Qb + (size_t)(qw + lr) * 6144 + h * 192 + c * 32 + lh * 8);

  const unsigned short* Kbase = Kb + h * 192;
  const unsigned short* Vbase = Vt + (size_t)h * 128 * 2048;
  // K tile: 64 rows x 24 chunks = 1536; thread stages 3. V: 128 x 8 = 1024; 2.
  size_t ka[3];
#pragma unroll
  for (int j = 0; j < 3; j++) {
    int c = tid + j * 512;
    int r = c / 24, p = c - r * 24;
    ka[j] = (size_t)r * 6144 + (p ^ (r & 7)) * 8;
  }
  size_t va[2];
#pragma unroll
  for (int j = 0; j < 2; j++) {
    int c = tid + j * 512;
    int d = c >> 3, p = c & 7;
    va[j] = (size_t)d * 2048 + (p ^ (d & 7)) * 8;
  }

#define STAGE(T0, B)                                                           \
  {                                                                            \
    _Pragma("unroll") for (int j = 0; j < 3; j++)                              \
        GLOAD16(Kbase + (size_t)(T0) * 6144 + ka[j], &Kl[B][(tid + j * 512) * 8]); \
    _Pragma("unroll") for (int j = 0; j < 2; j++)                              \
        GLOAD16(Vbase + va[j] + (T0), &Vl[B][(tid + j * 512) * 8]);            \
  }

  f32x4 acc[8];
  const f32x4 z = {0.f, 0.f, 0.f, 0.f};
#pragma unroll
  for (int n = 0; n < 8; n++) acc[n] = z;
  float mrow = -1e30f, lrow = 0.f;
  const int swz = (lr & 7) * 8;
  const int cv0 = ((lh ^ (lr & 7)) * 8);            // V chunk, t-half 0
  const int cv1 = (((4 + lh) ^ (lr & 7)) * 8);      // V chunk, t-half 1
  const int sA = lr + 32 * (lh & 1), sB = sA + 16;

  const int nt = (q0 + 128) >> 6;                   // 2..32
  STAGE(0, 0);
  __syncthreads();
  for (int it = 0; it < nt; ++it) {
    const int t0 = it << 6;
    const int cur = it & 1;
    if (it + 1 < nt) STAGE(t0 + 64, cur ^ 1);
    if (t0 <= qw + 15) {
      f32x4 s0 = z, s1 = z, s2 = z, s3 = z;
      __builtin_amdgcn_s_setprio(1);
#pragma unroll
      for (int c = 0; c < 6; c++) {
        int col = ((c * 4 + lh) * 8) ^ swz;
        bf16x8 k0 = *(const bf16x8*)(&Kl[cur][(lr)      * 192 + col]);
        bf16x8 k1 = *(const bf16x8*)(&Kl[cur][(16 + lr) * 192 + col]);
        bf16x8 k2 = *(const bf16x8*)(&Kl[cur][(32 + lr) * 192 + col]);
        bf16x8 k3 = *(const bf16x8*)(&Kl[cur][(48 + lr) * 192 + col]);
        s0 = __builtin_amdgcn_mfma_f32_16x16x32_bf16(k0, qf[c], s0, 0, 0, 0);
        s1 = __builtin_amdgcn_mfma_f32_16x16x32_bf16(k1, qf[c], s1, 0, 0, 0);
        s2 = __builtin_amdgcn_mfma_f32_16x16x32_bf16(k2, qf[c], s2, 0, 0, 0);
        s3 = __builtin_amdgcn_mfma_f32_16x16x32_bf16(k3, qf[c], s3, 0, 0, 0);
      }
      __builtin_amdgcn_s_setprio(0);
      // S (already in log2 domain via pre-scaled Q); lane owns q-row qv.
      const int tb = t0 + lh * 4;
      if (t0 + 63 > qw) {                           // diagonal: mask needed
#pragma unroll
        for (int r = 0; r < 4; r++) {
          s0[r] = (tb + r > qv)      ? -1e30f : s0[r];
          s1[r] = (tb + 16 + r > qv) ? -1e30f : s1[r];
          s2[r] = (tb + 32 + r > qv) ? -1e30f : s2[r];
          s3[r] = (tb + 48 + r > qv) ? -1e30f : s3[r];
        }
      }
      float mx = -1e30f;
#pragma unroll
      for (int r = 0; r < 4; r++)
        mx = fmaxf(mx, fmaxf(fmaxf(s0[r], s1[r]), fmaxf(s2[r], s3[r])));
      mx = fmaxf(mx, __shfl_xor(mx, 16, 64));
      mx = fmaxf(mx, __shfl_xor(mx, 32, 64));
      float ro = 1.f;
      bool resc = (mx - mrow) > 11.5f;              // defer-rescale (log2)
      if (resc) { ro = exp2f(mrow - mx); mrow = mx; }
      float p0[4], p1[4], p2[4], p3[4], ls = 0.f;
#pragma unroll
      for (int r = 0; r < 4; r++) {
        p0[r] = exp2f(s0[r] - mrow);
        p1[r] = exp2f(s1[r] - mrow);
        p2[r] = exp2f(s2[r] - mrow);
        p3[r] = exp2f(s3[r] - mrow);
        ls += (p0[r] + p1[r]) + (p2[r] + p3[r]);
      }
      lrow = lrow * ro + ls;
      if (__any(resc)) {
        float rs[4];
#pragma unroll
        for (int r = 0; r < 4; r++) rs[r] = __shfl(ro, lh * 4 + r, 16);
#pragma unroll
        for (int n = 0; n < 8; n++)
#pragma unroll
          for (int r = 0; r < 4; r++) acc[n][r] *= rs[r];
      }
      // P -> two A-fragments (t halves) via cvt_pk + shfl
      unsigned k0p = cvtpk(p0[0], p0[1]), k1p = cvtpk(p0[2], p0[3]);
      unsigned k2p = cvtpk(p1[0], p1[1]), k3p = cvtpk(p1[2], p1[3]);
      unsigned k4p = cvtpk(p2[0], p2[1]), k5p = cvtpk(p2[2], p2[3]);
      unsigned k6p = cvtpk(p3[0], p3[1]), k7p = cvtpk(p3[2], p3[3]);
      u32x4 w0, w1;
      {
        unsigned A0 = __shfl(k0p, sA, 64), A1 = __shfl(k1p, sA, 64);
        unsigned B0 = __shfl(k0p, sB, 64), B1 = __shfl(k1p, sB, 64);
        unsigned C0 = __shfl(k2p, sA, 64), C1 = __shfl(k3p, sA, 64);
        unsigned D0 = __shfl(k2p, sB, 64), D1 = __shfl(k3p, sB, 64);
        w0[0] = (lh < 2) ? A0 : C0;
        w0[1] = (lh < 2) ? A1 : C1;
        w0[2] = (lh < 2) ? B0 : D0;
        w0[3] = (lh < 2) ? B1 : D1;
      }
      {
        unsigned A0 = __shfl(k4p, sA, 64), A1 = __shfl(k5p, sA, 64);
        unsigned B0 = __shfl(k4p, sB, 64), B1 = __shfl(k5p, sB, 64);
        unsigned C0 = __shfl(k6p, sA, 64), C1 = __shfl(k7p, sA, 64);
        unsigned D0 = __shfl(k6p, sB, 64), D1 = __shfl(k7p, sB, 64);
        w1[0] = (lh < 2) ? A0 : C0;
        w1[1] = (lh < 2) ? A1 : C1;
        w1[2] = (lh < 2) ? B0 : D0;
        w1[3] = (lh < 2) ? B1 : D1;
      }
      bf16x8 pa0 = __builtin_bit_cast(bf16x8, w0);
      bf16x8 pa1 = __builtin_bit_cast(bf16x8, w1);
      __builtin_amdgcn_s_setprio(1);
#pragma unroll
      for (int n = 0; n < 8; n++) {
        bf16x8 vb0 = *(const bf16x8*)(&Vl[cur][(n * 16 + lr) * 64 + cv0]);
        bf16x8 vb1 = *(const bf16x8*)(&Vl[cur][(n * 16 + lr) * 64 + cv1]);
        acc[n] = __builtin_amdgcn_mfma_f32_16x16x32_bf16(pa0, vb0, acc[n], 0, 0, 0);
        acc[n] = __builtin_amdgcn_mfma_f32_16x16x32_bf16(pa1, vb1, acc[n], 0, 0, 0);
      }
      __builtin_amdgcn_s_setprio(0);
    }
    __syncthreads();
  }
#undef STAGE
  lrow += __shfl_xor(lrow, 16, 64);
  lrow += __shfl_xor(lrow, 32, 64);
  float invL = 1.f / lrow;
  float inv[4];
#pragma unroll
  for (int r = 0; r < 4; r++) inv[r] = __shfl(invL, lh * 4 + r, 16);
#pragma unroll
  for (int n = 0; n < 8; n++)
#pragma unroll
    for (int r = 0; r < 4; r++) {
      int q = qw + lh * 4 + r;
      O[(size_t)q * 4096 + h * 128 + n * 16 + lr] = f2b(acc[n][r] * inv[r]);
    }
}

// ---------------------------------------------------------------------------
extern "C" void kernel_launch(void* const* d_in, const int* in_sizes, int n_in,
                              void* d_out, int out_size, void* d_ws, size_t ws_size,
                              hipStream_t stream) {
  const float* hs      = (const float*)d_in[0];
  const float* q_a_w   = (const float*)d_in[1];
  const float* q_a_ln  = (const float*)d_in[2];
  const float* q_b_w   = (const float*)d_in[3];
  const float* kv_a_w  = (const float*)d_in[4];
  const float* kv_a_ln = (const float*)d_in[5];
  const float* kv_b_w  = (const float*)d_in[6];
  const float* o_w     = (const float*)d_in[7];
  float* out = (float*)d_out;

  char* ws = (char*)d_ws;
  size_t off = 0;
  auto alloc = [&](size_t bytes) {
    void* p = ws + off;
    off += (bytes + 255) & ~(size_t)255;
    return p;
  };
  unsigned short* wcat    = (unsigned short*)alloc(2176UL * 2048 * 2);
  unsigned short* q_b_wT  = (unsigned short*)alloc(6144UL * 1536 * 2);
  unsigned short* kv_b_wT = (unsigned short*)alloc(8192UL * 512 * 2);
  unsigned short* o_wT    = (unsigned short*)alloc(2048UL * 4096 * 2);
  unsigned short* hs_b    = (unsigned short*)alloc(2048UL * 2048 * 2);
  unsigned short* q_a_n   = (unsigned short*)alloc(2048UL * 1536 * 2);
  unsigned short* Qb      = (unsigned short*)alloc(2048UL * 6144 * 2);
  unsigned short* ckv_n   = (unsigned short*)alloc(2048UL * 512 * 2);
  unsigned short* Kb      = (unsigned short*)alloc(2048UL * 6144 * 2);
  unsigned short* Vt      = (unsigned short*)alloc(32UL * 128 * 2048 * 2);
  char* big = (char*)alloc(2048UL * 2176 * 4);
  float*          Craw     = (float*)big;
  unsigned short* attn_out = (unsigned short*)big;
  (void)ws_size; (void)in_sizes; (void)n_in; (void)out_size;

  dim3 b256(256), b512(512);
  prep<<<29952, b256, 0, stream>>>(hs, hs_b, q_a_w, kv_a_w, wcat,
                                   q_b_w, q_b_wT, kv_b_w, kv_b_wT, o_w, o_wT);
  // fused q_a + kv_a projection (1D grid, XCD-chunked swizzle)
  gemm_bt<<<272, b256, 0, stream>>>(hs_b, wcat, Craw, 2048, 2176, 2048, 17);
  rmsnorm<<<2048, b256, 0, stream>>>(Craw, q_a_ln, q_a_n, 1536, 2176);
  rmsnorm_krot<<<2048, b256, 0, stream>>>(Craw, kv_a_ln, ckv_n, Kb);
  // q path: 256^2 8-phase GEMM, fused rope + pre-scale epilogue
  gemm256<1><<<dim3(24, 8), b512, 0, stream>>>(q_a_n, q_b_wT, Qb, nullptr, nullptr,
                                               2048, 6144, 1536);
  // kv path: 256^2 8-phase GEMM writing Kb (k_pass) and Vt (transposed V)
  gemm256<3><<<dim3(32, 8), b512, 0, stream>>>(ckv_n, kv_b_wT, nullptr, Kb, Vt,
                                               2048, 8192, 512);
  // attention + output projection
  attn<<<dim3(16, 32), b512, 0, stream>>>(Qb, Kb, Vt, attn_out);
  gemm_bt<<<256, b256, 0, stream>>>(attn_out, o_wT, out, 2048, 2048, 4096, 16);
}

// Round 10
// 298.207 us; speedup vs baseline: 2.5459x; 1.2356x over previous
//
#include <hip/hip_runtime.h>

// ---------------------------------------------------------------------------
// MLA forward (B=1, S=2048, HID=2048, NH=32, DQK=192(128+64 rope), DV=128)
// Round 10: attn balanced+XCD-local block remap; split-K=2 on both 128^2
// GEMMs (2 blocks/CU) with partial-sum fused into rms2 / addout; q_b & kv_b
// 256^2 GEMMs merged into one dispatch.
// ---------------------------------------------------------------------------

typedef __bf16 bf16x8 __attribute__((ext_vector_type(8)));
typedef float  f32x4  __attribute__((ext_vector_type(4)));
typedef unsigned u32x4 __attribute__((ext_vector_type(4)));

#define GLOAD16(g, l)                                                          \
  __builtin_amdgcn_global_load_lds(                                            \
      (const __attribute__((address_space(1))) unsigned int*)(g),              \
      (__attribute__((address_space(3))) unsigned int*)(l), 16, 0, 0)

__device__ __forceinline__ unsigned short f2b(float f) {
  unsigned u = __builtin_bit_cast(unsigned, f);
  u += 0x7fffu + ((u >> 16) & 1u);   // round-to-nearest-even
  return (unsigned short)(u >> 16);
}

__device__ __forceinline__ unsigned cvtpk(float lo, float hi) {
  unsigned r;
  asm("v_cvt_pk_bf16_f32 %0, %1, %2" : "=v"(r) : "v"(lo), "v"(hi));
  return r;
}

// ---------------------------------------------------------------------------
// prep: all fp32->bf16 weight transpose-casts + hs cast, one launch.
// ---------------------------------------------------------------------------
__device__ __forceinline__ void tc_body(const float* __restrict__ src,
                                        unsigned short* __restrict__ dst,
                                        int R, int C, int bx, int by,
                                        int tx, int ty) {
  __shared__ float t[32][33];
  int r0 = bx * 32, c0 = by * 32;
#pragma unroll
  for (int j = 0; j < 4; j++) {
    int c = c0 + tx;
    t[ty + j * 8][tx] = (c < C) ? src[(size_t)(r0 + ty + j * 8) * C + c] : 0.f;
  }
  __syncthreads();
#pragma unroll
  for (int j = 0; j < 4; j++)
    dst[(size_t)(c0 + ty + j * 8) * R + r0 + tx] = f2b(t[tx][ty + j * 8]);
}

__global__ __launch_bounds__(256) void prep(
    const float* __restrict__ hs, unsigned short* __restrict__ hs_b,
    const float* __restrict__ qaw, const float* __restrict__ kvaw,
    unsigned short* __restrict__ wcat,
    const float* __restrict__ qbw, unsigned short* __restrict__ qbT,
    const float* __restrict__ kvbw, unsigned short* __restrict__ kvbT,
    const float* __restrict__ ow, unsigned short* __restrict__ owT) {
  int b = blockIdx.x;
  int tid = threadIdx.x;
  if (b < 4096) {
    int i = b * 256 + tid;
    float4 v = ((const float4*)hs)[i];
    ushort4 o;
    o.x = f2b(v.x); o.y = f2b(v.y); o.z = f2b(v.z); o.w = f2b(v.w);
    ((ushort4*)hs_b)[i] = o;
    return;
  }
  b -= 4096;
  int tx = tid & 31, ty = tid >> 5;
  if (b < 3072)       { tc_body(qaw,  wcat,               2048, 1536, b & 63,  b >> 6, tx, ty); return; }
  b -= 3072;
  if (b < 1280)       { tc_body(kvaw, wcat + 1536UL*2048, 2048, 576,  b & 63,  b >> 6, tx, ty); return; }
  b -= 1280;
  if (b < 9216)       { tc_body(qbw,  qbT,                1536, 6144, b % 48,  b / 48, tx, ty); return; }
  b -= 9216;
  if (b < 4096)       { tc_body(kvbw, kvbT,               512,  8192, b & 15,  b >> 4, tx, ty); return; }
  b -= 4096;
  tc_body(ow, owT, 4096, 2048, b & 127, b >> 7, tx, ty);
}

// ---------------------------------------------------------------------------
// rms2: fused RMSNorms over split-K partial sums of Craw (c0+c1).
// b<2048: q_a rows (C=1536). b>=2048: ckv rows (C=512) + k_rot rope broadcast.
// ---------------------------------------------------------------------------
__global__ __launch_bounds__(256) void rms2(const float* __restrict__ c0,
                                            const float* __restrict__ c1,
                                            const float* __restrict__ qw,
                                            const float* __restrict__ kvw,
                                            unsigned short* __restrict__ qan,
                                            unsigned short* __restrict__ ckvn,
                                            unsigned short* __restrict__ Kb) {
  int b = blockIdx.x, tid = threadIdx.x;
  __shared__ float red[4];
  if (b < 2048) {
    const float* x0 = c0 + (size_t)b * 2176;
    const float* x1 = c1 + (size_t)b * 2176;
    float vb[6], ss = 0.f;
#pragma unroll
    for (int j = 0; j < 6; j++) {
      float v = x0[tid + j * 256] + x1[tid + j * 256];
      vb[j] = v; ss += v * v;
    }
#pragma unroll
    for (int off = 1; off < 64; off <<= 1) ss += __shfl_xor(ss, off, 64);
    if ((tid & 63) == 0) red[tid >> 6] = ss;
    __syncthreads();
    ss = red[0] + red[1] + red[2] + red[3];
    float r = rsqrtf(ss / 1536.f + 1e-6f);
    unsigned short* orow = qan + (size_t)b * 1536;
#pragma unroll
    for (int j = 0; j < 6; j++)
      orow[tid + j * 256] = f2b(vb[j] * r * qw[tid + j * 256]);
  } else {
    int t = b - 2048;
    const float* x0 = c0 + (size_t)t * 2176 + 1536;
    const float* x1 = c1 + (size_t)t * 2176 + 1536;
    float vb[2], ss = 0.f;
#pragma unroll
    for (int j = 0; j < 2; j++) {
      float v = x0[tid + j * 256] + x1[tid + j * 256];
      vb[j] = v; ss += v * v;
    }
#pragma unroll
    for (int off = 1; off < 64; off <<= 1) ss += __shfl_xor(ss, off, 64);
    __shared__ unsigned short rot[64];
    if ((tid & 63) == 0) red[tid >> 6] = ss;
    __syncthreads();
    ss = red[0] + red[1] + red[2] + red[3];
    float r = rsqrtf(ss / 512.f + 1e-6f);
    unsigned short* orow = ckvn + (size_t)t * 512;
#pragma unroll
    for (int j = 0; j < 2; j++)
      orow[tid + j * 256] = f2b(vb[j] * r * kvw[tid + j * 256]);
    if (tid < 32) {
      float x1v = c0[(size_t)t * 2176 + 2048 + tid] + c1[(size_t)t * 2176 + 2048 + tid];
      float x2v = c0[(size_t)t * 2176 + 2080 + tid] + c1[(size_t)t * 2176 + 2080 + tid];
      float a = (float)t * exp2f(-(float)tid * 0.4152410118609203f);
      float cs = __cosf(a), sn = __sinf(a);
      rot[tid]      = f2b(x1v * cs - x2v * sn);
      rot[tid + 32] = f2b(x1v * sn + x2v * cs);
    }
    __syncthreads();
    for (int idx = tid; idx < 2048; idx += 256) {
      int h = idx >> 6, d = idx & 63;
      Kb[(size_t)t * 6144 + h * 192 + 128 + d] = rot[d];
    }
  }
}

// ---------------- addout: out = p0 + p1 (o-proj split-K combine) ------------
__global__ __launch_bounds__(256) void addout(const float4* __restrict__ p,
                                              float4* __restrict__ o) {
  int i = blockIdx.x * 256 + threadIdx.x;
  float4 a = p[i], b = p[i + 1048576];
  float4 r; r.x = a.x + b.x; r.y = a.y + b.y; r.z = a.z + b.z; r.w = a.w + b.w;
  o[i] = r;
}

// ---------------------------------------------------------------------------
// 128^2 GEMM (m97 structure), XCD-chunked swizzle, SPLIT-K=2.
// Grid = 2*total blocks; split s computes K-half, writes Cp + s*M*N (f32).
// ---------------------------------------------------------------------------
__global__ __launch_bounds__(256) void gemm_bt(const unsigned short* __restrict__ A,
                                               const unsigned short* __restrict__ Bt,
                                               float* __restrict__ Cp,
                                               int M, int N, int Ktot,
                                               int GX, int total) {
  __shared__ unsigned short As[4096];
  __shared__ unsigned short Bs[4096];
  const int tid = threadIdx.x;
  const int w = tid >> 6, lane = tid & 63;
  const int lr = lane & 15, lh = lane >> 4;
  const int lin = blockIdx.x, cpx = gridDim.x >> 3;
  int sid = (lin & 7) * cpx + (lin >> 3);              // chunked XCD transform
  const int s = (sid >= total);
  if (s) sid -= total;
  const int m0 = (sid / GX) * 128, n0 = (sid % GX) * 128;
  const int Kseg = Ktot >> 1;
  const unsigned short* Ab = A + (size_t)s * Kseg;
  const unsigned short* Bb = Bt + (size_t)s * Kseg;
  float* C = Cp + (size_t)s * M * N;
  const int wm = w >> 1, wn = w & 1;
  const int srow = lane >> 2;
  const int schunk = (lane & 3) ^ ((lane >> 3) & 3);
  const int swzr = (lr >> 1) & 3;

  f32x4 acc[4][4];
  const f32x4 z = {0.f, 0.f, 0.f, 0.f};
#pragma unroll
  for (int i = 0; i < 4; i++)
#pragma unroll
    for (int j = 0; j < 4; j++) acc[i][j] = z;

  for (int k0 = 0; k0 < Kseg; k0 += 32) {
#pragma unroll
    for (int c = 0; c < 2; c++) {
      GLOAD16(Ab + (size_t)(m0 + c * 64 + w * 16 + srow) * Ktot + k0 + schunk * 8,
              As + c * 2048 + w * 512);
      GLOAD16(Bb + (size_t)(n0 + c * 64 + w * 16 + srow) * Ktot + k0 + schunk * 8,
              Bs + c * 2048 + w * 512);
    }
    __syncthreads();
    bf16x8 a[4], b[4];
#pragma unroll
    for (int m = 0; m < 4; m++) {
      int row = wm * 64 + m * 16 + lr;
      a[m] = *(const bf16x8*)(As + row * 32 + ((lh ^ swzr) * 8));
    }
#pragma unroll
    for (int n = 0; n < 4; n++) {
      int row = wn * 64 + n * 16 + lr;
      b[n] = *(const bf16x8*)(Bs + row * 32 + ((lh ^ swzr) * 8));
    }
#pragma unroll
    for (int m = 0; m < 4; m++)
#pragma unroll
      for (int n = 0; n < 4; n++)
        acc[m][n] = __builtin_amdgcn_mfma_f32_16x16x32_bf16(a[m], b[n], acc[m][n], 0, 0, 0);
    __syncthreads();
  }
#pragma unroll
  for (int m = 0; m < 4; m++)
#pragma unroll
    for (int n = 0; n < 4; n++)
#pragma unroll
      for (int r = 0; r < 4; r++) {
        int row = m0 + wm * 64 + m * 16 + lh * 4 + r;
        int col = n0 + wn * 64 + n * 16 + lr;
        C[(size_t)row * N + col] = acc[m][n][r];
      }
}

// ---------------------------------------------------------------------------
// Merged 256^2 8-phase GEMM: blocks [0,192) = q_b (rope+prescale epilogue),
// blocks [192,448) = kv_b (Kb/Vt epilogue). One dispatch, better tail overlap.
// ---------------------------------------------------------------------------
__global__ __launch_bounds__(512) void gemm256m(
    const unsigned short* __restrict__ Aq, const unsigned short* __restrict__ Bq,
    unsigned short* __restrict__ Qb,
    const unsigned short* __restrict__ Akv, const unsigned short* __restrict__ Bkv,
    unsigned short* __restrict__ Kb, unsigned short* __restrict__ Vt) {
  __shared__ unsigned short lds[2][2][16384];   // 128 KiB
  const int tid = threadIdx.x;
  const int w = tid >> 6, lane = tid & 63;
  const int lr = lane & 15, lh = lane >> 4;
  const int wr = w >> 2, wc = w & 3;
  const int blk = blockIdx.x;
  const bool isq = blk < 192;
  const int bx = isq ? (blk % 24) : ((blk - 192) & 31);
  const int by = isq ? (blk / 24) : ((blk - 192) >> 5);
  const int K  = isq ? 1536 : 512;
  const int N  = isq ? 6144 : 8192;
  const unsigned short* A  = isq ? Aq : Akv;
  const unsigned short* Bt = isq ? Bq : Bkv;
  const int m0 = by * 256, n0 = bx * 256;

  int soff[2];
#pragma unroll
  for (int j = 0; j < 2; j++) {
    int c = j * 512 + tid;
    int row = c >> 3, p = c & 7;
    soff[j] = row * K + (p ^ (row & 7)) * 8;
  }
  const unsigned short* Abase = A + (size_t)m0 * K;
  const unsigned short* Bbase = Bt + (size_t)n0 * K;
  const int rswz = lr & 7;

#define STAGEOP(op, Base, kt, buf)                                             \
  {                                                                            \
    _Pragma("unroll") for (int hh = 0; hh < 2; hh++)                           \
    _Pragma("unroll") for (int j = 0; j < 2; j++)                              \
      GLOAD16(Base + (size_t)(hh * 128) * K + soff[j] + (kt) * 64,             \
              &lds[buf][op][(hh * 1024 + j * 512 + w * 64) * 8]);              \
  }
#define READA(mh, buf)                                                         \
  {                                                                            \
    _Pragma("unroll") for (int mi = 0; mi < 4; mi++)                           \
    _Pragma("unroll") for (int ks = 0; ks < 2; ks++)                           \
      af[mi][ks] = *(const bf16x8*)&lds[buf][0][                               \
          (wr * 128 + ((mh) * 4 + mi) * 16 + lr) * 64 +                        \
          (((ks * 4 + lh) ^ rswz) * 8)];                                       \
  }
#define READB(n, buf)                                                          \
  {                                                                            \
    _Pragma("unroll") for (int ks = 0; ks < 2; ks++)                           \
      bfr[n][ks] = *(const bf16x8*)&lds[buf][1][                               \
          (wc * 64 + (n) * 16 + lr) * 64 + (((ks * 4 + lh) ^ rswz) * 8)];      \
  }
#define MFMAQ(mh, nh)                                                          \
  {                                                                            \
    __builtin_amdgcn_s_setprio(1);                                             \
    _Pragma("unroll") for (int mi = 0; mi < 4; mi++)                           \
    _Pragma("unroll") for (int ni = 0; ni < 2; ni++)                           \
    _Pragma("unroll") for (int ks = 0; ks < 2; ks++)                           \
      acc[(mh) * 4 + mi][(nh) * 2 + ni] =                                      \
          __builtin_amdgcn_mfma_f32_16x16x32_bf16(                             \
              af[mi][ks], bfr[(nh) * 2 + ni][ks],                              \
              acc[(mh) * 4 + mi][(nh) * 2 + ni], 0, 0, 0);                     \
    __builtin_amdgcn_s_setprio(0);                                             \
  }

  f32x4 acc[8][4];
  const f32x4 z = {0.f, 0.f, 0.f, 0.f};
#pragma unroll
  for (int i = 0; i < 8; i++)
#pragma unroll
    for (int j = 0; j < 4; j++) acc[i][j] = z;

  STAGEOP(0, Abase, 0, 0);
  STAGEOP(1, Bbase, 0, 0);
  asm volatile("s_waitcnt vmcnt(0)" ::: "memory");
  __builtin_amdgcn_s_barrier();

  const int KT = K >> 6;
  for (int kt = 0; kt < KT; ++kt) {
    const int buf = kt & 1;
    const bool more = (kt + 1 < KT);
    bf16x8 af[4][2], bfr[4][2];
    READA(0, buf);
    READB(0, buf); READB(1, buf);
    if (more) STAGEOP(0, Abase, kt + 1, buf ^ 1);
    __builtin_amdgcn_s_barrier();
    MFMAQ(0, 0);
    __builtin_amdgcn_s_barrier();
    READB(2, buf); READB(3, buf);
    if (more) STAGEOP(1, Bbase, kt + 1, buf ^ 1);
    __builtin_amdgcn_s_barrier();
    MFMAQ(0, 1);
    __builtin_amdgcn_s_barrier();
    READA(1, buf);
    __builtin_amdgcn_s_barrier();
    MFMAQ(1, 1);
    __builtin_amdgcn_s_barrier();
    MFMAQ(1, 0);
    if (more) asm volatile("s_waitcnt vmcnt(0)" ::: "memory");
    __builtin_amdgcn_s_barrier();
  }
#undef STAGEOP
#undef READA
#undef READB
#undef MFMAQ

  if (isq) {                                       // q_b: bf16 + RoPE, pre-scaled
    const float kSc = 0.104126984f;                // 192^-0.5 * log2(e)
#pragma unroll
    for (int m = 0; m < 8; m++)
#pragma unroll
      for (int n = 0; n < 4; n++) {
        int colb = n0 + wc * 64 + n * 16;
        int sb = colb % 192;
        bool isrope = sb >= 128;
        bool first  = sb < 160;
        int col = colb + lr;
#pragma unroll
        for (int r = 0; r < 4; r++) {
          int row = m0 + wr * 128 + m * 16 + lh * 4 + r;
          float v = acc[m][n][r], o;
          if (!isrope) {
            o = v;
          } else {
            int ii = (col - 128) & 31;
            float ang = (float)row * exp2f(-(float)ii * 0.4152410118609203f);
            float cs = __cosf(ang), sn = __sinf(ang);
            float pa_ = acc[m][(n + 2) & 3][r];
            float pb_ = acc[m][(n + 6) & 3][r];
            float partner = first ? pa_ : pb_;
            o = first ? (v * cs - partner * sn) : (partner * sn + v * cs);
          }
          Qb[(size_t)row * 6144 + col] = f2b(o * kSc);
        }
      }
  } else {                                         // kv_b: K->Kb, V->Vt
    const int h = bx;
    unsigned short* Vlds = (unsigned short*)lds;   // [128][264] padded
    if (wc < 2) {
#pragma unroll
      for (int m = 0; m < 8; m++)
#pragma unroll
        for (int n = 0; n < 4; n++) {
          int dd = wc * 64 + n * 16 + lr;
          int rowb = m0 + wr * 128 + m * 16 + lh * 4;
#pragma unroll
          for (int r = 0; r < 4; r++)
            Kb[(size_t)(rowb + r) * 6144 + h * 192 + dd] = f2b(acc[m][n][r]);
        }
    } else {
#pragma unroll
      for (int m = 0; m < 8; m++)
#pragma unroll
        for (int n = 0; n < 4; n++) {
          int dd = (wc - 2) * 64 + n * 16 + lr;
          int tl = wr * 128 + m * 16 + lh * 4;
          ushort4 pk;
          pk.x = f2b(acc[m][n][0]); pk.y = f2b(acc[m][n][1]);
          pk.z = f2b(acc[m][n][2]); pk.w = f2b(acc[m][n][3]);
          *(ushort4*)(Vlds + dd * 264 + tl) = pk;
        }
    }
    __syncthreads();
    {
      int r = tid >> 2, seg = tid & 3;
      const unsigned short* srcp = Vlds + r * 264 + seg * 64;
      unsigned short* dstp = Vt + (size_t)(h * 128 + r) * 2048 + m0 + seg * 64;
#pragma unroll
      for (int j = 0; j < 8; j++)
        *(int4*)(dstp + j * 8) = *(const int4*)(srcp + j * 8);
    }
  }
}

// ---------------------------------------------------------------------------
// Causal MLA attention (round-9 core) with balanced + XCD-local block remap:
// b -> (h, i) such that (a) co-resident block pairs (k,k+1) and (k,k+32) have
// complementary work (sum = 17 tile-units), (b) each head's 16 blocks stay on
// one XCD (K/V L2 locality). Grid 512, 8 waves, 128 q/block, KVBLK=64.
// ---------------------------------------------------------------------------
__global__ __launch_bounds__(512) void attn(const unsigned short* __restrict__ Qb,
                                            const unsigned short* __restrict__ Kb,
                                            const unsigned short* __restrict__ Vt,
                                            unsigned short* __restrict__ O) {
  __shared__ unsigned short Kl[2][12288];   // [64 t][192 d], chunk-swizzled
  __shared__ unsigned short Vl[2][8192];    // [128 d][64 t], chunk-swizzled
  const int tid = threadIdx.x;
  const int w = tid >> 6, lane = tid & 63;
  const int lr = lane & 15, lh = lane >> 4;
  // balanced + XCD-local decode
  const int b = blockIdx.x;
  const int x = b & 7, k = b >> 3;
  const int h = x + 8 * (k >> 4);
  const int ii = k & 15;
  int qi = (ii & 1) ? (15 - 2 * (ii >> 1)) : (2 * (ii >> 1));
  if (k & 32) qi = 15 - qi;
  const int q0 = qi * 128;
  const int qw = q0 + w * 16;
  const int qv = qw + lr;

  bf16x8 qf[6];
#pragma unroll
  for (int c = 0; c < 6; c++)
    qf[c] = *(const bf16x8*)(Qb + (size_t)(qw + lr) * 6144 + h * 192 + c * 32 + lh * 8);

  const unsigned short* Kbase = Kb + h * 192;
  const unsigned short* Vbase = Vt + (size_t)h * 128 * 2048;
  size_t ka[3];
#pragma unroll
  for (int j = 0; j < 3; j++) {
    int c = tid + j * 512;
    int r = c / 24, p = c - r * 24;
    ka[j] = (size_t)r * 6144 + (p ^ (r & 7)) * 8;
  }
  size_t va[2];
#pragma unroll
  for (int j = 0; j < 2; j++) {
    int c = tid + j * 512;
    int d = c >> 3, p = c & 7;
    va[j] = (size_t)d * 2048 + (p ^ (d & 7)) * 8;
  }

#define STAGE(T0, B)                                                           \
  {                                                                            \
    _Pragma("unroll") for (int j = 0; j < 3; j++)                              \
        GLOAD16(Kbase + (size_t)(T0) * 6144 + ka[j], &Kl[B][(tid + j * 512) * 8]); \
    _Pragma("unroll") for (int j = 0; j < 2; j++)                              \
        GLOAD16(Vbase + va[j] + (T0), &Vl[B][(tid + j * 512) * 8]);            \
  }

  f32x4 acc[8];
  const f32x4 z = {0.f, 0.f, 0.f, 0.f};
#pragma unroll
  for (int n = 0; n < 8; n++) acc[n] = z;
  float mrow = -1e30f, lrow = 0.f;
  const int swz = (lr & 7) * 8;
  const int cv0 = ((lh ^ (lr & 7)) * 8);
  const int cv1 = (((4 + lh) ^ (lr & 7)) * 8);
  const int sA = lr + 32 * (lh & 1), sB = sA + 16;

  const int nt = (q0 + 128) >> 6;
  STAGE(0, 0);
  __syncthreads();
  for (int it = 0; it < nt; ++it) {
    const int t0 = it << 6;
    const int cur = it & 1;
    if (it + 1 < nt) STAGE(t0 + 64, cur ^ 1);
    if (t0 <= qw + 15) {
      f32x4 s0 = z, s1 = z, s2 = z, s3 = z;
      __builtin_amdgcn_s_setprio(1);
#pragma unroll
      for (int c = 0; c < 6; c++) {
        int col = ((c * 4 + lh) * 8) ^ swz;
        bf16x8 k0 = *(const bf16x8*)(&Kl[cur][(lr)      * 192 + col]);
        bf16x8 k1 = *(const bf16x8*)(&Kl[cur][(16 + lr) * 192 + col]);
        bf16x8 k2 = *(const bf16x8*)(&Kl[cur][(32 + lr) * 192 + col]);
        bf16x8 k3 = *(const bf16x8*)(&Kl[cur][(48 + lr) * 192 + col]);
        s0 = __builtin_amdgcn_mfma_f32_16x16x32_bf16(k0, qf[c], s0, 0, 0, 0);
        s1 = __builtin_amdgcn_mfma_f32_16x16x32_bf16(k1, qf[c], s1, 0, 0, 0);
        s2 = __builtin_amdgcn_mfma_f32_16x16x32_bf16(k2, qf[c], s2, 0, 0, 0);
        s3 = __builtin_amdgcn_mfma_f32_16x16x32_bf16(k3, qf[c], s3, 0, 0, 0);
      }
      __builtin_amdgcn_s_setprio(0);
      const int tb = t0 + lh * 4;
      if (t0 + 63 > qw) {
#pragma unroll
        for (int r = 0; r < 4; r++) {
          s0[r] = (tb + r > qv)      ? -1e30f : s0[r];
          s1[r] = (tb + 16 + r > qv) ? -1e30f : s1[r];
          s2[r] = (tb + 32 + r > qv) ? -1e30f : s2[r];
          s3[r] = (tb + 48 + r > qv) ? -1e30f : s3[r];
        }
      }
      float mx = -1e30f;
#pragma unroll
      for (int r = 0; r < 4; r++)
        mx = fmaxf(mx, fmaxf(fmaxf(s0[r], s1[r]), fmaxf(s2[r], s3[r])));
      mx = fmaxf(mx, __shfl_xor(mx, 16, 64));
      mx = fmaxf(mx, __shfl_xor(mx, 32, 64));
      float ro = 1.f;
      bool resc = (mx - mrow) > 11.5f;
      if (resc) { ro = exp2f(mrow - mx); mrow = mx; }
      float p0[4], p1[4], p2[4], p3[4], ls = 0.f;
#pragma unroll
      for (int r = 0; r < 4; r++) {
        p0[r] = exp2f(s0[r] - mrow);
        p1[r] = exp2f(s1[r] - mrow);
        p2[r] = exp2f(s2[r] - mrow);
        p3[r] = exp2f(s3[r] - mrow);
        ls += (p0[r] + p1[r]) + (p2[r] + p3[r]);
      }
      lrow = lrow * ro + ls;
      if (__any(resc)) {
        float rs[4];
#pragma unroll
        for (int r = 0; r < 4; r++) rs[r] = __shfl(ro, lh * 4 + r, 16);
#pragma unroll
        for (int n = 0; n < 8; n++)
#pragma unroll
          for (int r = 0; r < 4; r++) acc[n][r] *= rs[r];
      }
      unsigned k0p = cvtpk(p0[0], p0[1]), k1p = cvtpk(p0[2], p0[3]);
      unsigned k2p = cvtpk(p1[0], p1[1]), k3p = cvtpk(p1[2], p1[3]);
      unsigned k4p = cvtpk(p2[0], p2[1]), k5p = cvtpk(p2[2], p2[3]);
      unsigned k6p = cvtpk(p3[0], p3[1]), k7p = cvtpk(p3[2], p3[3]);
      u32x4 w0, w1;
      {
        unsigned A0 = __shfl(k0p, sA, 64), A1 = __shfl(k1p, sA, 64);
        unsigned B0 = __shfl(k0p, sB, 64), B1 = __shfl(k1p, sB, 64);
        unsigned C0 = __shfl(k2p, sA, 64), C1 = __shfl(k3p, sA, 64);
        unsigned D0 = __shfl(k2p, sB, 64), D1 = __shfl(k3p, sB, 64);
        w0[0] = (lh < 2) ? A0 : C0;
        w0[1] = (lh < 2) ? A1 : C1;
        w0[2] = (lh < 2) ? B0 : D0;
        w0[3] = (lh < 2) ? B1 : D1;
      }
      {
        unsigned A0 = __shfl(k4p, sA, 64), A1 = __shfl(k5p, sA, 64);
        unsigned B0 = __shfl(k4p, sB, 64), B1 = __shfl(k5p, sB, 64);
        unsigned C0 = __shfl(k6p, sA, 64), C1 = __shfl(k7p, sA, 64);
        unsigned D0 = __shfl(k6p, sB, 64), D1 = __shfl(k7p, sB, 64);
        w1[0] = (lh < 2) ? A0 : C0;
        w1[1] = (lh < 2) ? A1 : C1;
        w1[2] = (lh < 2) ? B0 : D0;
        w1[3] = (lh < 2) ? B1 : D1;
      }
      bf16x8 pa0 = __builtin_bit_cast(bf16x8, w0);
      bf16x8 pa1 = __builtin_bit_cast(bf16x8, w1);
      __builtin_amdgcn_s_setprio(1);
#pragma unroll
      for (int n = 0; n < 8; n++) {
        bf16x8 vb0 = *(const bf16x8*)(&Vl[cur][(n * 16 + lr) * 64 + cv0]);
        bf16x8 vb1 = *(const bf16x8*)(&Vl[cur][(n * 16 + lr) * 64 + cv1]);
        acc[n] = __builtin_amdgcn_mfma_f32_16x16x32_bf16(pa0, vb0, acc[n], 0, 0, 0);
        acc[n] = __builtin_amdgcn_mfma_f32_16x16x32_bf16(pa1, vb1, acc[n], 0, 0, 0);
      }
      __builtin_amdgcn_s_setprio(0);
    }
    __syncthreads();
  }
#undef STAGE
  lrow += __shfl_xor(lrow, 16, 64);
  lrow += __shfl_xor(lrow, 32, 64);
  float invL = 1.f / lrow;
  float inv[4];
#pragma unroll
  for (int r = 0; r < 4; r++) inv[r] = __shfl(invL, lh * 4 + r, 16);
#pragma unroll
  for (int n = 0; n < 8; n++)
#pragma unroll
    for (int r = 0; r < 4; r++) {
      int q = qw + lh * 4 + r;
      O[(size_t)q * 4096 + h * 128 + n * 16 + lr] = f2b(acc[n][r] * inv[r]);
    }
}

// ---------------------------------------------------------------------------
extern "C" void kernel_launch(void* const* d_in, const int* in_sizes, int n_in,
                              void* d_out, int out_size, void* d_ws, size_t ws_size,
                              hipStream_t stream) {
  const float* hs      = (const float*)d_in[0];
  const float* q_a_w   = (const float*)d_in[1];
  const float* q_a_ln  = (const float*)d_in[2];
  const float* q_b_w   = (const float*)d_in[3];
  const float* kv_a_w  = (const float*)d_in[4];
  const float* kv_a_ln = (const float*)d_in[5];
  const float* kv_b_w  = (const float*)d_in[6];
  const float* o_w     = (const float*)d_in[7];
  float* out = (float*)d_out;

  char* ws = (char*)d_ws;
  size_t off = 0;
  auto alloc = [&](size_t bytes) {
    void* p = ws + off;
    off += (bytes + 255) & ~(size_t)255;
    return p;
  };
  unsigned short* wcat    = (unsigned short*)alloc(2176UL * 2048 * 2);
  unsigned short* q_b_wT  = (unsigned short*)alloc(6144UL * 1536 * 2);
  unsigned short* kv_b_wT = (unsigned short*)alloc(8192UL * 512 * 2);
  unsigned short* o_wT    = (unsigned short*)alloc(2048UL * 4096 * 2);
  unsigned short* hs_b    = (unsigned short*)alloc(2048UL * 2048 * 2);
  unsigned short* q_a_n   = (unsigned short*)alloc(2048UL * 1536 * 2);
  unsigned short* Qb      = (unsigned short*)alloc(2048UL * 6144 * 2);
  unsigned short* ckv_n   = (unsigned short*)alloc(2048UL * 512 * 2);
  unsigned short* Kb      = (unsigned short*)alloc(2048UL * 6144 * 2);
  unsigned short* Vt      = (unsigned short*)alloc(32UL * 128 * 2048 * 2);
  // big transient region:
  //   [0, 35.7MB):  CrawP f32 [2][2048][2176]   (dead after rms2)
  //   [0, 16.8MB):  attn_out bf16 (time-shares CrawP[0])
  //   [36MB, +33.6MB): OutP f32 [2][2048][2048]
  char* big = (char*)alloc(37748736UL + 2UL * 2048 * 2048 * 4);
  float*          Craw0    = (float*)big;
  float*          Craw1    = (float*)(big + 2048UL * 2176 * 4);
  unsigned short* attn_out = (unsigned short*)big;
  float*          OutP     = (float*)(big + 37748736UL);
  (void)ws_size; (void)in_sizes; (void)n_in; (void)out_size;

  dim3 b256(256), b512(512);
  prep<<<29952, b256, 0, stream>>>(hs, hs_b, q_a_w, kv_a_w, wcat,
                                   q_b_w, q_b_wT, kv_b_w, kv_b_wT, o_w, o_wT);
  // fused q_a + kv_a projection, split-K=2 (544 blocks, 2/CU)
  gemm_bt<<<544, b256, 0, stream>>>(hs_b, wcat, Craw0, 2048, 2176, 2048, 17, 272);
  // both RMSNorms + krot over partial sums, one dispatch
  rms2<<<4096, b256, 0, stream>>>(Craw0, Craw1, q_a_ln, kv_a_ln, q_a_n, ckv_n, Kb);
  // q_b + kv_b 256^2 8-phase GEMMs, merged dispatch (448 blocks)
  gemm256m<<<448, b512, 0, stream>>>(q_a_n, q_b_wT, Qb, ckv_n, kv_b_wT, Kb, Vt);
  // attention (balanced + XCD-local remap)
  attn<<<512, b512, 0, stream>>>(Qb, Kb, Vt, attn_out);
  // output projection, split-K=2 (512 blocks, 2/CU) + combine
  gemm_bt<<<512, b256, 0, stream>>>(attn_out, o_wT, OutP, 2048, 2048, 4096, 16, 256);
  addout<<<4096, b256, 0, stream>>>((const float4*)OutP, (float4*)out);
}